// Round 11
// baseline (1973.715 us; speedup 1.0000x reference)
//
#include <hip/hip_runtime.h>

// 2-layer bidirectional LSTM, B=256 T=2048 D=64, H1=16/dir, H2=8/dir.
// R11 = R10 + 2-way sequence ILP in the scan waves.
// R10 proved: gx-precompute works (VGPR 28, no spills, 473us l1 scan). The
// scan is latency-bound (554cy/step vs ~250cy chain arithmetic; 1-2 waves/CU;
// VALUBusy 24%): the single dependence chain stalls on bpermute/exp latency
// with nothing else to issue. Fix: each wave processes TWO sequences of the
// SAME direction (batch 2p, 2p+1 -> shared u-weights); two independent
// chains interleave in the scheduler, covering each other's latency.
//  - LDS ring: 2 streams x 4 slots x 1KB = 8KB.
//  - vmcnt per group = 2 DMA + 2x stores; traced: l1 4/12/20,28;
//    l2 4/20/36,52.
//  - gemm + fallback kernels unchanged from R10 (proven).

constexpr int Bn = 256;
constexpr int Tn = 2048;

__device__ __forceinline__ float fast_rcp(float x) { return __builtin_amdgcn_rcpf(x); }
__device__ __forceinline__ float tanh_fast(float x) {
  return fmaf(2.0f, fast_rcp(1.0f + __expf(-2.0f * x)), -1.0f);
}

// DPP rotate-right by R within each 16-lane row: dst[l] = src[(l-R)&15].
template <int R>
__device__ __forceinline__ float rotr16(float v) {
  return __int_as_float(__builtin_amdgcn_mov_dpp(
      __float_as_int(v), 0x120 | R, 0xF, 0xF, true));
}

#define OPQ4(v) asm("" : "+v"(v.x), "+v"(v.y), "+v"(v.z), "+v"(v.w));
#define OPQ1(v) asm("" : "+v"(v));

#define GST(addr, val) \
  asm volatile("global_store_dword %0, %1, off" :: "v"(addr), "v"(val));

#define WAITV(N)                                              \
  do {                                                        \
    asm volatile("s_waitcnt vmcnt(" #N ")" ::: "memory");     \
    __builtin_amdgcn_sched_barrier(0);                        \
  } while (0)

#define DMA16(gsrc, ldst)                                         \
  __builtin_amdgcn_global_load_lds(                               \
      (const __attribute__((address_space(1))) float*)(gsrc),     \
      (__attribute__((address_space(3))) float*)(ldst), 16, 0, 0);

#define FMAU(ACC, I) { const float4 xv_ = x4[I];                    \
    ACC = fmaf(xv_.x, w##I.x, ACC); ACC = fmaf(xv_.y, w##I.y, ACC); \
    ACC = fmaf(xv_.z, w##I.z, ACC); ACC = fmaf(xv_.w, w##I.w, ACC); }

#define FMAQ(ACC, I) { float4 v_ = xq_[I];                          \
    ACC = fmaf(v_.x, w##I.x, ACC); ACC = fmaf(v_.y, w##I.y, ACC);   \
    ACC = fmaf(v_.z, w##I.z, ACC); ACC = fmaf(v_.w, w##I.w, ACC); }

// ==================== GEMM 1: gx1[bd][s][64] (scan order) ====================
__global__ __launch_bounds__(64, 4) void gemm_gx1(
    const float* __restrict__ x,
    const float* __restrict__ wf, const float* __restrict__ bif,
    const float* __restrict__ bhf,
    const float* __restrict__ wb, const float* __restrict__ bib,
    const float* __restrict__ bhb,
    float* __restrict__ gx1) {
  constexpr int TILES = 16, TT = Tn / TILES;
  const int lane = threadIdx.x;
  const int bd   = blockIdx.x / TILES;
  const int tile = blockIdx.x % TILES;
  const int dir  = bd & 1, b = bd >> 1;

  const float* W = dir ? wb : wf;  // [64][64]
  float bias = (dir ? bib : bif)[lane] + (dir ? bhb : bhf)[lane];

  const float4* wr = reinterpret_cast<const float4*>(W + lane * 64);
  float4 w0 = wr[0],  w1 = wr[1],  w2 = wr[2],  w3 = wr[3],
         w4 = wr[4],  w5 = wr[5],  w6 = wr[6],  w7 = wr[7],
         w8 = wr[8],  w9 = wr[9],  w10 = wr[10], w11 = wr[11],
         w12 = wr[12], w13 = wr[13], w14 = wr[14], w15 = wr[15];
  OPQ4(w0)  OPQ4(w1)  OPQ4(w2)  OPQ4(w3)  OPQ4(w4)  OPQ4(w5)
  OPQ4(w6)  OPQ4(w7)  OPQ4(w8)  OPQ4(w9)  OPQ4(w10) OPQ4(w11)
  OPQ4(w12) OPQ4(w13) OPQ4(w14) OPQ4(w15) OPQ1(bias)

  float* gout = gx1 + (size_t)bd * Tn * 64;
  for (int tt = 0; tt < TT; ++tt) {
    const int t = tile * TT + tt;
    const float4* x4 =
        reinterpret_cast<const float4*>(x + ((size_t)b * Tn + t) * 64);
    float a0 = bias, a1 = 0.f, a2 = 0.f, a3 = 0.f;
    FMAU(a0, 0)  FMAU(a1, 1)  FMAU(a2, 2)  FMAU(a3, 3)
    FMAU(a0, 4)  FMAU(a1, 5)  FMAU(a2, 6)  FMAU(a3, 7)
    FMAU(a0, 8)  FMAU(a1, 9)  FMAU(a2, 10) FMAU(a3, 11)
    FMAU(a0, 12) FMAU(a1, 13) FMAU(a2, 14) FMAU(a3, 15)
    const float acc = (a0 + a1) + (a2 + a3);
    const int s = dir ? (Tn - 1 - t) : t;
    gout[(size_t)s * 64 + lane] = acc;
  }
}

// ==================== GEMM 2: gx2[bd][s][32] (scan order) ====================
__global__ __launch_bounds__(64, 4) void gemm_gx2(
    const float* __restrict__ in,   // out1 [B][T][32]
    const float* __restrict__ wf, const float* __restrict__ bif,
    const float* __restrict__ bhf,
    const float* __restrict__ wb, const float* __restrict__ bib,
    const float* __restrict__ bhb,
    float* __restrict__ gx2) {
  constexpr int TILES = 16, TT = Tn / TILES;
  const int lane = threadIdx.x;
  const int g = lane & 31, half = lane >> 5;
  const int b = blockIdx.x / TILES, tile = blockIdx.x % TILES;

  const float* W = half ? wb : wf;  // [32][32]
  float bias = (half ? bib : bif)[g] + (half ? bhb : bhf)[g];

  const float4* wr = reinterpret_cast<const float4*>(W + g * 32);
  float4 w0 = wr[0], w1 = wr[1], w2 = wr[2], w3 = wr[3],
         w4 = wr[4], w5 = wr[5], w6 = wr[6], w7 = wr[7];
  OPQ4(w0) OPQ4(w1) OPQ4(w2) OPQ4(w3) OPQ4(w4) OPQ4(w5) OPQ4(w6) OPQ4(w7)
  OPQ1(bias)

  for (int tt = 0; tt < TT; ++tt) {
    const int t = tile * TT + tt;
    const float4* x4 =
        reinterpret_cast<const float4*>(in + ((size_t)b * Tn + t) * 32);
    float a0 = bias, a1 = 0.f, a2 = 0.f, a3 = 0.f;
    FMAU(a0, 0) FMAU(a1, 1) FMAU(a2, 2) FMAU(a3, 3)
    FMAU(a0, 4) FMAU(a1, 5) FMAU(a2, 6) FMAU(a3, 7)
    const float acc = (a0 + a1) + (a2 + a3);
    const int s = half ? (Tn - 1 - t) : t;
    gx2[((size_t)(b * 2 + half) * Tn + s) * 32 + g] = acc;
  }
}

// ==================== Scan 1, 2-stream: H=16 ====================
// grid = 256: dir = bid&1, p = bid>>1; streams A = batch 2p, B = batch 2p+1
// (same dir -> shared u registers). Chunk = 4 s-rows x 64 = 1KB per stream.
__global__ __launch_bounds__(64, 1) void l1_scan_gx2(
    const float* __restrict__ gx1,
    const float* __restrict__ whh_f, const float* __restrict__ whh_b,
    float* __restrict__ out1) {
  constexpr int NC = Tn / 4;
  const int lane = threadIdx.x;
  const int dir  = blockIdx.x & 1;
  const int p    = blockIdx.x >> 1;
  const int b0 = 2 * p, b1 = 2 * p + 1;

  __shared__ float xr[2 * 4 * 256];   // 8KB: [stream][slot][256]
  float* xrA = xr;
  float* xrB = xr + 1024;

  const float* gxA = gx1 + (size_t)(b0 * 2 + dir) * Tn * 64;
  const float* gxB = gx1 + (size_t)(b1 * 2 + dir) * Tn * 64;

  // Prologue: A0,B0,A1,B1,A2,B2.
#pragma unroll
  for (int q = 0; q < 3; ++q) {
    DMA16(gxA + (size_t)q * 256 + lane * 4, xrA + q * 256)
    DMA16(gxB + (size_t)q * 256 + lane * 4, xrB + q * 256)
  }

  const float* whh = dir ? whh_b : whh_f;  // [64][16]
  const int k = lane & 15, grp = lane >> 4;
  const float* whr = whh + lane * 16;
  float u0 = whr[k], u1 = whr[(k - 1) & 15], u2 = whr[(k - 2) & 15],
        u3 = whr[(k - 3) & 15], u4 = whr[(k - 4) & 15],
        u5 = whr[(k - 5) & 15], u6 = whr[(k - 6) & 15],
        u7 = whr[(k - 7) & 15], u8 = whr[(k - 8) & 15],
        u9 = whr[(k - 9) & 15], u10 = whr[(k - 10) & 15],
        u11 = whr[(k - 11) & 15], u12 = whr[(k - 12) & 15],
        u13 = whr[(k - 13) & 15], u14 = whr[(k - 14) & 15],
        u15 = whr[(k - 15) & 15];
  OPQ1(u0)  OPQ1(u1)  OPQ1(u2)  OPQ1(u3)  OPQ1(u4)  OPQ1(u5)
  OPQ1(u6)  OPQ1(u7)  OPQ1(u8)  OPQ1(u9)  OPQ1(u10) OPQ1(u11)
  OPQ1(u12) OPQ1(u13) OPQ1(u14) OPQ1(u15)

  const float gin  = (grp == 2) ? 2.0f : 1.0f;
  const float gout = (grp == 2) ? 2.0f : 1.0f;
  const float gsub = (grp == 2) ? -1.0f : 0.0f;

  const int ostep = dir ? -32 : 32;
  float* opA = out1 + (size_t)b0 * Tn * 32 + dir * 16 +
               (dir ? (size_t)(Tn - 1) * 32 : 0);
  float* opB = out1 + (size_t)b1 * Tn * 32 + dir * 16 +
               (dir ? (size_t)(Tn - 1) * 32 : 0);

  float hA = 0.0f, cA = 0.0f, hB = 0.0f, cB = 0.0f;

#define STEP1(HH, CC, OP, GX) {                                           \
    float m0 = fmaf(HH, u0, (GX)), m1 = 0.f, m2 = 0.f, m3 = 0.f;          \
    m1 = fmaf(rotr16<1>(HH),  u1,  m1);  m2 = fmaf(rotr16<2>(HH),  u2,  m2); \
    m3 = fmaf(rotr16<3>(HH),  u3,  m3);  m0 = fmaf(rotr16<4>(HH),  u4,  m0); \
    m1 = fmaf(rotr16<5>(HH),  u5,  m1);  m2 = fmaf(rotr16<6>(HH),  u6,  m2); \
    m3 = fmaf(rotr16<7>(HH),  u7,  m3);  m0 = fmaf(rotr16<8>(HH),  u8,  m0); \
    m1 = fmaf(rotr16<9>(HH),  u9,  m1);  m2 = fmaf(rotr16<10>(HH), u10, m2); \
    m3 = fmaf(rotr16<11>(HH), u11, m3);  m0 = fmaf(rotr16<12>(HH), u12, m0); \
    m1 = fmaf(rotr16<13>(HH), u13, m1);  m2 = fmaf(rotr16<14>(HH), u14, m2); \
    m3 = fmaf(rotr16<15>(HH), u15, m3);                                   \
    const float g_ = (m0 + m1) + (m2 + m3);                               \
    const float sg_  = fast_rcp(1.0f + __expf(-gin * g_));                \
    const float val_ = fmaf(gout, sg_, gsub);                             \
    const float e1_ = __shfl_xor(val_, 16, 64);                           \
    const float e2_ = __shfl_xor(val_, 32, 64);                           \
    const float e3_ = __shfl_xor(val_, 48, 64);                           \
    const float iv_ = (grp == 0) ? val_ : (grp == 1) ? e1_ : (grp == 2) ? e2_ : e3_; \
    const float fv_ = (grp == 1) ? val_ : (grp == 0) ? e1_ : (grp == 3) ? e2_ : e3_; \
    const float gv_ = (grp == 2) ? val_ : (grp == 3) ? e1_ : (grp == 0) ? e2_ : e3_; \
    const float ov_ = (grp == 3) ? val_ : (grp == 2) ? e1_ : (grp == 1) ? e2_ : e3_; \
    CC = fmaf(fv_, CC, iv_ * gv_);                                        \
    HH = ov_ * tanh_fast(CC);                                             \
    if (lane < 16) { GST(OP + lane, HH) }                                 \
    OP += ostep;                                                          \
  }

  // Per group: 2 DMA + 8 GST. Waits (traced): 4, 12, 20, then 28.
#define GROUP1(NW, G) {                                                   \
    WAITV(NW);                                                            \
    const float* sA_ = xrA + ((G) & 3) * 256;                             \
    const float* sB_ = xrB + ((G) & 3) * 256;                             \
    const float qA0_ = sA_[lane];        const float qB0_ = sB_[lane];    \
    const float qA1_ = sA_[64 + lane];   const float qB1_ = sB_[64 + lane];  \
    const float qA2_ = sA_[128 + lane];  const float qB2_ = sB_[128 + lane]; \
    const float qA3_ = sA_[192 + lane];  const float qB3_ = sB_[192 + lane]; \
    { const int mp_ = (G) + 3;                                            \
      const int mpc_ = (mp_ < NC) ? mp_ : NC - 1;                         \
      DMA16(gxA + (size_t)mpc_ * 256 + lane * 4, xrA + (mp_ & 3) * 256)   \
      DMA16(gxB + (size_t)mpc_ * 256 + lane * 4, xrB + (mp_ & 3) * 256) } \
    STEP1(hA, cA, opA, qA0_)  STEP1(hB, cB, opB, qB0_)                    \
    STEP1(hA, cA, opA, qA1_)  STEP1(hB, cB, opB, qB1_)                    \
    STEP1(hA, cA, opA, qA2_)  STEP1(hB, cB, opB, qB2_)                    \
    STEP1(hA, cA, opA, qA3_)  STEP1(hB, cB, opB, qB3_)                    \
  }

  GROUP1(4, 0)
  GROUP1(12, 1)
  GROUP1(20, 2)
#pragma unroll 1
  for (int g = 3; g < NC; ++g) {
    GROUP1(28, g)
  }
#undef GROUP1
#undef STEP1
}

// ==================== Scan 2, 2-stream: H=8 ====================
// grid = 256: dir = bid&1, p = bid>>1; A = batch 2p, B = batch 2p+1.
// Chunk = 8 s-rows x 32 = 1KB per stream.
__global__ __launch_bounds__(64, 1) void l2_scan_gx2(
    const float* __restrict__ gx2,
    const float* __restrict__ whh_f, const float* __restrict__ whh_b,
    float* __restrict__ out) {
  constexpr int NC = Tn / 8;
  const int lane = threadIdx.x;
  const int j    = lane & 31;
  const int dir  = blockIdx.x & 1;
  const int p    = blockIdx.x >> 1;
  const int b0 = 2 * p, b1 = 2 * p + 1;

  __shared__ float xr[2 * 4 * 256];
  float* xrA = xr;
  float* xrB = xr + 1024;

  const float* gxA = gx2 + (size_t)(b0 * 2 + dir) * Tn * 32;
  const float* gxB = gx2 + (size_t)(b1 * 2 + dir) * Tn * 32;

#pragma unroll
  for (int q = 0; q < 3; ++q) {
    DMA16(gxA + (size_t)q * 256 + lane * 4, xrA + q * 256)
    DMA16(gxB + (size_t)q * 256 + lane * 4, xrB + q * 256)
  }

  const float* whh = dir ? whh_b : whh_f;  // [32][8]
  const int k = j & 7, grp = j >> 3;
  const float* whr = whh + j * 8;
  float u0 = whr[k], u1 = whr[(k - 1) & 7], u2 = whr[(k - 2) & 7],
        u3 = whr[(k - 3) & 7], u4 = whr[(k - 4) & 7],
        u5 = whr[(k - 5) & 7], u6 = whr[(k - 6) & 7],
        u7 = whr[(k - 7) & 7];
  OPQ1(u0) OPQ1(u1) OPQ1(u2) OPQ1(u3) OPQ1(u4) OPQ1(u5) OPQ1(u6) OPQ1(u7)

  const float gin  = (grp == 2) ? 2.0f : 1.0f;
  const float gout = (grp == 2) ? 2.0f : 1.0f;
  const float gsub = (grp == 2) ? -1.0f : 0.0f;

  const int ostep = dir ? -16 : 16;
  float* opA = out + (size_t)b0 * Tn * 16 + dir * 8 +
               (dir ? (size_t)(Tn - 1) * 16 : 0);
  float* opB = out + (size_t)b1 * Tn * 16 + dir * 8 +
               (dir ? (size_t)(Tn - 1) * 16 : 0);

  float hA = 0.0f, cA = 0.0f, hB = 0.0f, cB = 0.0f;

#define STEP2(HH, CC, OP, GX) {                                           \
    float m0 = fmaf(HH, u0, (GX)), m1 = 0.f, m2 = 0.f, m3 = 0.f;          \
    m1 = fmaf(rotr16<1>(HH), u1, m1);  m2 = fmaf(rotr16<2>(HH), u2, m2);  \
    m3 = fmaf(rotr16<3>(HH), u3, m3);  m0 = fmaf(rotr16<4>(HH), u4, m0);  \
    m1 = fmaf(rotr16<5>(HH), u5, m1);  m2 = fmaf(rotr16<6>(HH), u6, m2);  \
    m3 = fmaf(rotr16<7>(HH), u7, m3);                                     \
    const float g_ = (m0 + m1) + (m2 + m3);                               \
    const float sg_  = fast_rcp(1.0f + __expf(-gin * g_));                \
    const float val_ = fmaf(gout, sg_, gsub);                             \
    const float e1_ = __shfl_xor(val_, 8, 64);                            \
    const float e2_ = __shfl_xor(val_, 16, 64);                           \
    const float e3_ = __shfl_xor(val_, 24, 64);                           \
    const float iv_ = (grp == 0) ? val_ : (grp == 1) ? e1_ : (grp == 2) ? e2_ : e3_; \
    const float fv_ = (grp == 1) ? val_ : (grp == 0) ? e1_ : (grp == 3) ? e2_ : e3_; \
    const float gv_ = (grp == 2) ? val_ : (grp == 3) ? e1_ : (grp == 0) ? e2_ : e3_; \
    const float ov_ = (grp == 3) ? val_ : (grp == 2) ? e1_ : (grp == 1) ? e2_ : e3_; \
    CC = fmaf(fv_, CC, iv_ * gv_);                                        \
    HH = ov_ * tanh_fast(CC);                                             \
    if (lane < 8) { GST(OP + j, HH) }                                     \
    OP += ostep;                                                          \
  }

  // Per group: 2 DMA + 16 GST. Waits (traced): 4, 20, 36, then 52.
#define GROUP2(NW, G) {                                                   \
    WAITV(NW);                                                            \
    const float* sA_ = xrA + ((G) & 3) * 256;                             \
    const float* sB_ = xrB + ((G) & 3) * 256;                             \
    const float qA0_ = sA_[j];         const float qB0_ = sB_[j];         \
    const float qA1_ = sA_[32 + j];    const float qB1_ = sB_[32 + j];    \
    const float qA2_ = sA_[64 + j];    const float qB2_ = sB_[64 + j];    \
    const float qA3_ = sA_[96 + j];    const float qB3_ = sB_[96 + j];    \
    const float qA4_ = sA_[128 + j];   const float qB4_ = sB_[128 + j];   \
    const float qA5_ = sA_[160 + j];   const float qB5_ = sB_[160 + j];   \
    const float qA6_ = sA_[192 + j];   const float qB6_ = sB_[192 + j];   \
    const float qA7_ = sA_[224 + j];   const float qB7_ = sB_[224 + j];   \
    { const int mp_ = (G) + 3;                                            \
      const int mpc_ = (mp_ < NC) ? mp_ : NC - 1;                         \
      DMA16(gxA + (size_t)mpc_ * 256 + lane * 4, xrA + (mp_ & 3) * 256)   \
      DMA16(gxB + (size_t)mpc_ * 256 + lane * 4, xrB + (mp_ & 3) * 256) } \
    STEP2(hA, cA, opA, qA0_)  STEP2(hB, cB, opB, qB0_)                    \
    STEP2(hA, cA, opA, qA1_)  STEP2(hB, cB, opB, qB1_)                    \
    STEP2(hA, cA, opA, qA2_)  STEP2(hB, cB, opB, qB2_)                    \
    STEP2(hA, cA, opA, qA3_)  STEP2(hB, cB, opB, qB3_)                    \
    STEP2(hA, cA, opA, qA4_)  STEP2(hB, cB, opB, qB4_)                    \
    STEP2(hA, cA, opA, qA5_)  STEP2(hB, cB, opB, qB5_)                    \
    STEP2(hA, cA, opA, qA6_)  STEP2(hB, cB, opB, qB6_)                    \
    STEP2(hA, cA, opA, qA7_)  STEP2(hB, cB, opB, qB7_)                    \
  }

  GROUP2(4, 0)
  GROUP2(20, 1)
  GROUP2(36, 2)
#pragma unroll 1
  for (int g = 3; g < NC; ++g) {
    GROUP2(52, g)
  }
#undef GROUP2
#undef STEP2
}

// ==================== Fallback (R10, proven): weights in scan ====================
__global__ __launch_bounds__(64, 1) void l1_scan_fb(
    const float* __restrict__ x,
    const float* __restrict__ wih_f, const float* __restrict__ whh_f,
    const float* __restrict__ bih_f, const float* __restrict__ bhh_f,
    const float* __restrict__ wih_b, const float* __restrict__ whh_b,
    const float* __restrict__ bih_b, const float* __restrict__ bhh_b,
    float* __restrict__ out1) {
  constexpr int NC = Tn / 4;
  const int lane = threadIdx.x;
  const int dir  = blockIdx.x & 1;
  const int b    = blockIdx.x >> 1;
  __shared__ float xr[4 * 256];
  const float* xb = x + (size_t)b * (Tn * 64);
  {
    const int m0 = dir ? NC - 1 : 0;
    const int md = dir ? -1 : 1;
#pragma unroll
    for (int q = 0; q < 3; ++q) {
      const int mc = m0 + q * md;
      DMA16(xb + (size_t)mc * 256 + lane * 4, xr + (mc & 3) * 256)
    }
  }
  const float* wih = dir ? wih_b : wih_f;
  const float* whh = dir ? whh_b : whh_f;
  float bias = (dir ? bih_b : bih_f)[lane] + (dir ? bhh_b : bhh_f)[lane];
  const int k = lane & 15, grp = lane >> 4;
  const float gin  = (grp == 2) ? 2.0f : 1.0f;
  const float gout = (grp == 2) ? 2.0f : 1.0f;
  const float gsub = (grp == 2) ? -1.0f : 0.0f;
  const float4* wr = reinterpret_cast<const float4*>(wih + lane * 64);
  float4 w0 = wr[0],  w1 = wr[1],  w2 = wr[2],  w3 = wr[3],
         w4 = wr[4],  w5 = wr[5],  w6 = wr[6],  w7 = wr[7],
         w8 = wr[8],  w9 = wr[9],  w10 = wr[10], w11 = wr[11],
         w12 = wr[12], w13 = wr[13], w14 = wr[14], w15 = wr[15];
  const float* whr = whh + lane * 16;
  float u0 = whr[k], u1 = whr[(k - 1) & 15], u2 = whr[(k - 2) & 15],
        u3 = whr[(k - 3) & 15], u4 = whr[(k - 4) & 15],
        u5 = whr[(k - 5) & 15], u6 = whr[(k - 6) & 15],
        u7 = whr[(k - 7) & 15], u8 = whr[(k - 8) & 15],
        u9 = whr[(k - 9) & 15], u10 = whr[(k - 10) & 15],
        u11 = whr[(k - 11) & 15], u12 = whr[(k - 12) & 15],
        u13 = whr[(k - 13) & 15], u14 = whr[(k - 14) & 15],
        u15 = whr[(k - 15) & 15];
  const int ostep = dir ? -32 : 32;
  float* op = out1 + (size_t)b * (Tn * 32) + dir * 16 +
              (dir ? (size_t)(Tn - 1) * 32 : 0);
  float h = 0.0f, c = 0.0f;
#define STEP1F(XROW) {                                                    \
    const float4* xq_ = reinterpret_cast<const float4*>(XROW);            \
    float a0 = bias, a1 = 0.f, a2 = 0.f, a3 = 0.f;                        \
    FMAQ(a0, 0)  FMAQ(a1, 1)  FMAQ(a2, 2)  FMAQ(a3, 3)                   \
    FMAQ(a0, 4)  FMAQ(a1, 5)  FMAQ(a2, 6)  FMAQ(a3, 7)                   \
    FMAQ(a0, 8)  FMAQ(a1, 9)  FMAQ(a2, 10) FMAQ(a3, 11)                  \
    FMAQ(a0, 12) FMAQ(a1, 13) FMAQ(a2, 14) FMAQ(a3, 15)                  \
    const float gx_ = (a0 + a1) + (a2 + a3);                              \
    float m0 = h * u0, m1 = 0.f, m2 = 0.f, m3 = 0.f;                      \
    m1 = fmaf(rotr16<1>(h),  u1,  m1);  m2 = fmaf(rotr16<2>(h),  u2,  m2); \
    m3 = fmaf(rotr16<3>(h),  u3,  m3);  m0 = fmaf(rotr16<4>(h),  u4,  m0); \
    m1 = fmaf(rotr16<5>(h),  u5,  m1);  m2 = fmaf(rotr16<6>(h),  u6,  m2); \
    m3 = fmaf(rotr16<7>(h),  u7,  m3);  m0 = fmaf(rotr16<8>(h),  u8,  m0); \
    m1 = fmaf(rotr16<9>(h),  u9,  m1);  m2 = fmaf(rotr16<10>(h), u10, m2); \
    m3 = fmaf(rotr16<11>(h), u11, m3);  m0 = fmaf(rotr16<12>(h), u12, m0); \
    m1 = fmaf(rotr16<13>(h), u13, m1);  m2 = fmaf(rotr16<14>(h), u14, m2); \
    m3 = fmaf(rotr16<15>(h), u15, m3);                                    \
    const float g_ = ((m0 + m1) + (m2 + m3)) + gx_;                       \
    const float sg_  = fast_rcp(1.0f + __expf(-gin * g_));                \
    const float val_ = fmaf(gout, sg_, gsub);                             \
    const float e1_ = __shfl_xor(val_, 16, 64);                           \
    const float e2_ = __shfl_xor(val_, 32, 64);                           \
    const float e3_ = __shfl_xor(val_, 48, 64);                           \
    const float iv_ = (grp == 0) ? val_ : (grp == 1) ? e1_ : (grp == 2) ? e2_ : e3_; \
    const float fv_ = (grp == 1) ? val_ : (grp == 0) ? e1_ : (grp == 3) ? e2_ : e3_; \
    const float gv_ = (grp == 2) ? val_ : (grp == 3) ? e1_ : (grp == 0) ? e2_ : e3_; \
    const float ov_ = (grp == 3) ? val_ : (grp == 2) ? e1_ : (grp == 1) ? e2_ : e3_; \
    c = fmaf(fv_, c, iv_ * gv_);                                          \
    h = ov_ * tanh_fast(c);                                               \
    if (lane < 16) { GST(op + lane, h) }                                  \
    op += ostep;                                                          \
  }
#define GROUP1F(NW, G) {                                                  \
    const int mq_ = dir ? (NC - 1 - (G)) : (G);                           \
    const float* sb_ = xr + (mq_ & 3) * 256;                              \
    WAITV(NW);                                                            \
    { const int mp_ = dir ? (mq_ - 3) : (mq_ + 3);                        \
      const int sl_ = mp_ & 3;                                            \
      const int mpc_ = mp_ < 0 ? 0 : (mp_ >= NC ? NC - 1 : mp_);          \
      DMA16(xb + (size_t)mpc_ * 256 + lane * 4, xr + sl_ * 256) }         \
    STEP1F(sb_ + (dir ? 3 : 0) * 64)                                      \
    STEP1F(sb_ + (dir ? 2 : 1) * 64)                                      \
    STEP1F(sb_ + (dir ? 1 : 2) * 64)                                      \
    STEP1F(sb_ + (dir ? 0 : 3) * 64)                                      \
  }
  GROUP1F(2, 0)
  GROUP1F(6, 1)
  GROUP1F(10, 2)
#pragma unroll 1
  for (int g = 3; g < NC; ++g) {
    GROUP1F(14, g)
  }
#undef GROUP1F
#undef STEP1F
}

__global__ __launch_bounds__(64, 1) void l2_scan_fb(
    const float* __restrict__ in,
    const float* __restrict__ wih_f, const float* __restrict__ whh_f,
    const float* __restrict__ bih_f, const float* __restrict__ bhh_f,
    const float* __restrict__ wih_b, const float* __restrict__ whh_b,
    const float* __restrict__ bih_b, const float* __restrict__ bhh_b,
    float* __restrict__ out) {
  constexpr int NC = Tn / 8;
  const int lane = threadIdx.x;
  const int j    = lane & 31;
  const int dir  = blockIdx.x & 1;
  const int b    = blockIdx.x >> 1;
  __shared__ float xr[4 * 256];
  const float* ib = in + (size_t)b * (Tn * 32);
  {
    const int m0 = dir ? NC - 1 : 0;
    const int md = dir ? -1 : 1;
#pragma unroll
    for (int q = 0; q < 3; ++q) {
      const int mc = m0 + q * md;
      DMA16(ib + (size_t)mc * 256 + lane * 4, xr + (mc & 3) * 256)
    }
  }
  const float* wih = dir ? wih_b : wih_f;
  const float* whh = dir ? whh_b : whh_f;
  float bias = (dir ? bih_b : bih_f)[j] + (dir ? bhh_b : bhh_f)[j];
  const int k = j & 7, grp = j >> 3;
  const float gin  = (grp == 2) ? 2.0f : 1.0f;
  const float gout = (grp == 2) ? 2.0f : 1.0f;
  const float gsub = (grp == 2) ? -1.0f : 0.0f;
  const float4* wr = reinterpret_cast<const float4*>(wih + j * 32);
  float4 w0 = wr[0], w1 = wr[1], w2 = wr[2], w3 = wr[3],
         w4 = wr[4], w5 = wr[5], w6 = wr[6], w7 = wr[7];
  const float* whr = whh + j * 8;
  float u0 = whr[k], u1 = whr[(k - 1) & 7], u2 = whr[(k - 2) & 7],
        u3 = whr[(k - 3) & 7], u4 = whr[(k - 4) & 7],
        u5 = whr[(k - 5) & 7], u6 = whr[(k - 6) & 7],
        u7 = whr[(k - 7) & 7];
  const int ostep = dir ? -16 : 16;
  float* op = out + (size_t)b * (Tn * 16) + dir * 8 +
              (dir ? (size_t)(Tn - 1) * 16 : 0);
  float h = 0.0f, c = 0.0f;
#define STEP2F(XROW) {                                                    \
    const float4* xq_ = reinterpret_cast<const float4*>(XROW);            \
    float a0 = bias, a1 = 0.f, a2 = 0.f, a3 = 0.f;                        \
    FMAQ(a0, 0) FMAQ(a1, 1) FMAQ(a2, 2) FMAQ(a3, 3)                      \
    FMAQ(a0, 4) FMAQ(a1, 5) FMAQ(a2, 6) FMAQ(a3, 7)                      \
    const float gx_ = (a0 + a1) + (a2 + a3);                              \
    float m0 = h * u0, m1 = 0.f, m2 = 0.f, m3 = 0.f;                      \
    m1 = fmaf(rotr16<1>(h), u1, m1);  m2 = fmaf(rotr16<2>(h), u2, m2);    \
    m3 = fmaf(rotr16<3>(h), u3, m3);  m0 = fmaf(rotr16<4>(h), u4, m0);    \
    m1 = fmaf(rotr16<5>(h), u5, m1);  m2 = fmaf(rotr16<6>(h), u6, m2);    \
    m3 = fmaf(rotr16<7>(h), u7, m3);                                      \
    const float g_ = ((m0 + m1) + (m2 + m3)) + gx_;                       \
    const float sg_  = fast_rcp(1.0f + __expf(-gin * g_));                \
    const float val_ = fmaf(gout, sg_, gsub);                             \
    const float e1_ = __shfl_xor(val_, 8, 64);                            \
    const float e2_ = __shfl_xor(val_, 16, 64);                           \
    const float e3_ = __shfl_xor(val_, 24, 64);                           \
    const float iv_ = (grp == 0) ? val_ : (grp == 1) ? e1_ : (grp == 2) ? e2_ : e3_; \
    const float fv_ = (grp == 1) ? val_ : (grp == 0) ? e1_ : (grp == 3) ? e2_ : e3_; \
    const float gv_ = (grp == 2) ? val_ : (grp == 3) ? e1_ : (grp == 0) ? e2_ : e3_; \
    const float ov_ = (grp == 3) ? val_ : (grp == 2) ? e1_ : (grp == 1) ? e2_ : e3_; \
    c = fmaf(fv_, c, iv_ * gv_);                                          \
    h = ov_ * tanh_fast(c);                                               \
    if (lane < 8) { GST(op + lane, h) }                                   \
    op += ostep;                                                          \
  }
#define GROUP2F(NW, G) {                                                  \
    const int mq_ = dir ? (NC - 1 - (G)) : (G);                           \
    const float* sb_ = xr + (mq_ & 3) * 256;                              \
    WAITV(NW);                                                            \
    { const int mp_ = dir ? (mq_ - 3) : (mq_ + 3);                        \
      const int sl_ = mp_ & 3;                                            \
      const int mpc_ = mp_ < 0 ? 0 : (mp_ >= NC ? NC - 1 : mp_);          \
      DMA16(ib + (size_t)mpc_ * 256 + lane * 4, xr + sl_ * 256) }         \
    STEP2F(sb_ + (dir ? 7 : 0) * 32)                                      \
    STEP2F(sb_ + (dir ? 6 : 1) * 32)                                      \
    STEP2F(sb_ + (dir ? 5 : 2) * 32)                                      \
    STEP2F(sb_ + (dir ? 4 : 3) * 32)                                      \
    STEP2F(sb_ + (dir ? 3 : 4) * 32)                                      \
    STEP2F(sb_ + (dir ? 2 : 5) * 32)                                      \
    STEP2F(sb_ + (dir ? 1 : 6) * 32)                                      \
    STEP2F(sb_ + (dir ? 0 : 7) * 32)                                      \
  }
  GROUP2F(2, 0)
  GROUP2F(10, 1)
  GROUP2F(18, 2)
#pragma unroll 1
  for (int g = 3; g < NC; ++g) {
    GROUP2F(26, g)
  }
#undef GROUP2F
#undef STEP2F
}

extern "C" void kernel_launch(void* const* d_in, const int* in_sizes, int n_in,
                              void* d_out, int out_size, void* d_ws, size_t ws_size,
                              hipStream_t stream) {
  const float* x     = (const float*)d_in[0];
  const float* wih1f = (const float*)d_in[1];
  const float* whh1f = (const float*)d_in[2];
  const float* bih1f = (const float*)d_in[3];
  const float* bhh1f = (const float*)d_in[4];
  const float* wih1b = (const float*)d_in[5];
  const float* whh1b = (const float*)d_in[6];
  const float* bih1b = (const float*)d_in[7];
  const float* bhh1b = (const float*)d_in[8];
  const float* wih2f = (const float*)d_in[9];
  const float* whh2f = (const float*)d_in[10];
  const float* bih2f = (const float*)d_in[11];
  const float* bhh2f = (const float*)d_in[12];
  const float* wih2b = (const float*)d_in[13];
  const float* whh2b = (const float*)d_in[14];
  const float* bih2b = (const float*)d_in[15];
  const float* bhh2b = (const float*)d_in[16];

  float* out1 = (float*)d_ws;                       // [B][T][32] = 67.1 MB
  float* outp = (float*)d_out;                      // [B][T][16]

  const size_t out1F = (size_t)Bn * Tn * 32;
  const size_t gx1F  = (size_t)Bn * 2 * Tn * 64;    // 268.4 MB
  const size_t needB = (out1F + gx1F) * sizeof(float);

  if (ws_size >= needB) {
    float* gx1 = (float*)d_ws + out1F;              // [2B][T][64]
    float* gx2 = gx1;                               // aliases gx1 (dead after scan1)
    gemm_gx1<<<Bn * 2 * 16, 64, 0, stream>>>(
        x, wih1f, bih1f, bhh1f, wih1b, bih1b, bhh1b, gx1);
    l1_scan_gx2<<<Bn, 64, 0, stream>>>(gx1, whh1f, whh1b, out1);
    gemm_gx2<<<Bn * 16, 64, 0, stream>>>(
        out1, wih2f, bih2f, bhh2f, wih2b, bih2b, bhh2b, gx2);
    l2_scan_gx2<<<Bn, 64, 0, stream>>>(gx2, whh2f, whh2b, outp);
  } else {
    l1_scan_fb<<<Bn * 2, 64, 0, stream>>>(x, wih1f, whh1f, bih1f, bhh1f,
                                          wih1b, whh1b, bih1b, bhh1b, out1);
    l2_scan_fb<<<Bn * 2, 64, 0, stream>>>(out1, wih2f, whh2f, bih2f, bhh2f,
                                          wih2b, whh2b, bih2b, bhh2b, outp);
  }
}

// Round 13
// 1332.916 us; speedup vs baseline: 1.4807x; 1.4807x over previous
//
#include <hip/hip_runtime.h>

// 2-layer bidirectional LSTM, B=256 T=2048 D=64, H1=16/dir, H2=8/dir.
// R13 = R10 (last PASS, 1443us) with ONE change: gate exchange via
// permlane-swap BUILTINS + exact XOR-combine.
//  - R12 post-mortem: raw `asm("v_permlane16_swap_b32 ...")` failed
//    (absmax 0.23). Two suspected causes, both fixed here:
//    (a) hazard wait-states: the compiler cannot insert VALU->permlane
//        hazard NOPs around asm it can't parse; builtins are compiler-
//        generated -> hazards handled.
//    (b) vdst/vsrc polarity of the swap outputs: made IRRELEVANT by the
//        identity {r[0], r[1]} = {val[l], val[l^16]} per lane, so
//        r[0]^r[1]^bits(val[l]) == bits(val[l^16]) EXACTLY (bitwise XOR,
//        no select, no rounding).
//  - l2: xor8 via proven rotr16<8> DPP; xor16 via permlane16_swap+XOR;
//    xor24 = rotr16<8>(xor16).
//  - __has_builtin guards fall back to __shfl_xor (R10-proven) so the
//    kernel cannot fail to compile or pass.
// Everything else (GST stores, counted vmcnt 14/26, DMA ring, gemms,
// fallback kernels) is R10 verbatim.

#ifndef __has_builtin
#define __has_builtin(x) 0
#endif

constexpr int Bn = 256;
constexpr int Tn = 2048;

typedef unsigned int uint2v __attribute__((ext_vector_type(2)));

__device__ __forceinline__ float fast_rcp(float x) { return __builtin_amdgcn_rcpf(x); }
__device__ __forceinline__ float tanh_fast(float x) {
  return fmaf(2.0f, fast_rcp(1.0f + __expf(-2.0f * x)), -1.0f);
}

// DPP rotate-right by R within each 16-lane row: dst[l] = src[(l-R)&15].
template <int R>
__device__ __forceinline__ float rotr16(float v) {
  return __int_as_float(__builtin_amdgcn_mov_dpp(
      __float_as_int(v), 0x120 | R, 0xF, 0xF, true));
}

// val[l^16] / val[l^32], polarity-proof (see header).
__device__ __forceinline__ float xor16_lane(float v) {
#if __has_builtin(__builtin_amdgcn_permlane16_swap)
  const unsigned u = __float_as_uint(v);
  uint2v r = __builtin_amdgcn_permlane16_swap(u, u, false, false);
  return __uint_as_float(r[0] ^ r[1] ^ u);
#else
  return __shfl_xor(v, 16, 64);
#endif
}
__device__ __forceinline__ float xor32_lane(float v) {
#if __has_builtin(__builtin_amdgcn_permlane32_swap)
  const unsigned u = __float_as_uint(v);
  uint2v r = __builtin_amdgcn_permlane32_swap(u, u, false, false);
  return __uint_as_float(r[0] ^ r[1] ^ u);
#else
  return __shfl_xor(v, 32, 64);
#endif
}

#define OPQ4(v) asm("" : "+v"(v.x), "+v"(v.y), "+v"(v.z), "+v"(v.w));
#define OPQ1(v) asm("" : "+v"(v));

#define GST(addr, val) \
  asm volatile("global_store_dword %0, %1, off" :: "v"(addr), "v"(val));

#define WAITV(N)                                              \
  do {                                                        \
    asm volatile("s_waitcnt vmcnt(" #N ")" ::: "memory");     \
    __builtin_amdgcn_sched_barrier(0);                        \
  } while (0)

#define DMA16(gsrc, ldst)                                         \
  __builtin_amdgcn_global_load_lds(                               \
      (const __attribute__((address_space(1))) float*)(gsrc),     \
      (__attribute__((address_space(3))) float*)(ldst), 16, 0, 0);

#define FMAU(ACC, I) { const float4 xv_ = x4[I];                    \
    ACC = fmaf(xv_.x, w##I.x, ACC); ACC = fmaf(xv_.y, w##I.y, ACC); \
    ACC = fmaf(xv_.z, w##I.z, ACC); ACC = fmaf(xv_.w, w##I.w, ACC); }

#define FMAQ(ACC, I) { float4 v_ = xq_[I];                          \
    ACC = fmaf(v_.x, w##I.x, ACC); ACC = fmaf(v_.y, w##I.y, ACC);   \
    ACC = fmaf(v_.z, w##I.z, ACC); ACC = fmaf(v_.w, w##I.w, ACC); }

// ==================== GEMM 1: gx1[bd][s][64] (scan order) ====================
__global__ __launch_bounds__(64, 4) void gemm_gx1(
    const float* __restrict__ x,
    const float* __restrict__ wf, const float* __restrict__ bif,
    const float* __restrict__ bhf,
    const float* __restrict__ wb, const float* __restrict__ bib,
    const float* __restrict__ bhb,
    float* __restrict__ gx1) {
  constexpr int TILES = 16, TT = Tn / TILES;
  const int lane = threadIdx.x;
  const int bd   = blockIdx.x / TILES;
  const int tile = blockIdx.x % TILES;
  const int dir  = bd & 1, b = bd >> 1;

  const float* W = dir ? wb : wf;  // [64][64]
  float bias = (dir ? bib : bif)[lane] + (dir ? bhb : bhf)[lane];

  const float4* wr = reinterpret_cast<const float4*>(W + lane * 64);
  float4 w0 = wr[0],  w1 = wr[1],  w2 = wr[2],  w3 = wr[3],
         w4 = wr[4],  w5 = wr[5],  w6 = wr[6],  w7 = wr[7],
         w8 = wr[8],  w9 = wr[9],  w10 = wr[10], w11 = wr[11],
         w12 = wr[12], w13 = wr[13], w14 = wr[14], w15 = wr[15];
  OPQ4(w0)  OPQ4(w1)  OPQ4(w2)  OPQ4(w3)  OPQ4(w4)  OPQ4(w5)
  OPQ4(w6)  OPQ4(w7)  OPQ4(w8)  OPQ4(w9)  OPQ4(w10) OPQ4(w11)
  OPQ4(w12) OPQ4(w13) OPQ4(w14) OPQ4(w15) OPQ1(bias)

  float* gout = gx1 + (size_t)bd * Tn * 64;
  for (int tt = 0; tt < TT; ++tt) {
    const int t = tile * TT + tt;
    const float4* x4 =
        reinterpret_cast<const float4*>(x + ((size_t)b * Tn + t) * 64);
    float a0 = bias, a1 = 0.f, a2 = 0.f, a3 = 0.f;
    FMAU(a0, 0)  FMAU(a1, 1)  FMAU(a2, 2)  FMAU(a3, 3)
    FMAU(a0, 4)  FMAU(a1, 5)  FMAU(a2, 6)  FMAU(a3, 7)
    FMAU(a0, 8)  FMAU(a1, 9)  FMAU(a2, 10) FMAU(a3, 11)
    FMAU(a0, 12) FMAU(a1, 13) FMAU(a2, 14) FMAU(a3, 15)
    const float acc = (a0 + a1) + (a2 + a3);
    const int s = dir ? (Tn - 1 - t) : t;
    gout[(size_t)s * 64 + lane] = acc;
  }
}

// ==================== GEMM 2: gx2[bd][s][32] (scan order) ====================
__global__ __launch_bounds__(64, 4) void gemm_gx2(
    const float* __restrict__ in,   // out1 [B][T][32]
    const float* __restrict__ wf, const float* __restrict__ bif,
    const float* __restrict__ bhf,
    const float* __restrict__ wb, const float* __restrict__ bib,
    const float* __restrict__ bhb,
    float* __restrict__ gx2) {
  constexpr int TILES = 16, TT = Tn / TILES;
  const int lane = threadIdx.x;
  const int g = lane & 31, half = lane >> 5;
  const int b = blockIdx.x / TILES, tile = blockIdx.x % TILES;

  const float* W = half ? wb : wf;  // [32][32]
  float bias = (half ? bib : bif)[g] + (half ? bhb : bhf)[g];

  const float4* wr = reinterpret_cast<const float4*>(W + g * 32);
  float4 w0 = wr[0], w1 = wr[1], w2 = wr[2], w3 = wr[3],
         w4 = wr[4], w5 = wr[5], w6 = wr[6], w7 = wr[7];
  OPQ4(w0) OPQ4(w1) OPQ4(w2) OPQ4(w3) OPQ4(w4) OPQ4(w5) OPQ4(w6) OPQ4(w7)
  OPQ1(bias)

  for (int tt = 0; tt < TT; ++tt) {
    const int t = tile * TT + tt;
    const float4* x4 =
        reinterpret_cast<const float4*>(in + ((size_t)b * Tn + t) * 32);
    float a0 = bias, a1 = 0.f, a2 = 0.f, a3 = 0.f;
    FMAU(a0, 0) FMAU(a1, 1) FMAU(a2, 2) FMAU(a3, 3)
    FMAU(a0, 4) FMAU(a1, 5) FMAU(a2, 6) FMAU(a3, 7)
    const float acc = (a0 + a1) + (a2 + a3);
    const int s = half ? (Tn - 1 - t) : t;
    gx2[((size_t)(b * 2 + half) * Tn + s) * 32 + g] = acc;
  }
}

// ==================== Scan 1 (gx-fed): H=16 ====================
// grid = 2*B (blockIdx = bd), block = 64. Chunk = 4 s-rows x 64 = 1KB.
__global__ __launch_bounds__(64, 1) void l1_scan_gx(
    const float* __restrict__ gx1,
    const float* __restrict__ whh_f, const float* __restrict__ whh_b,
    float* __restrict__ out1) {
  constexpr int NC = Tn / 4;
  const int lane = threadIdx.x;
  const int dir  = blockIdx.x & 1;
  const int b    = blockIdx.x >> 1;

  __shared__ float xr[4 * 256];
  const float* gxb = gx1 + (size_t)blockIdx.x * Tn * 64;

#pragma unroll
  for (int p = 0; p < 3; ++p)
    DMA16(gxb + (size_t)p * 256 + lane * 4, xr + p * 256)

  const float* whh = dir ? whh_b : whh_f;  // [64][16]
  const int k = lane & 15, grp = lane >> 4;
  const float* whr = whh + lane * 16;
  float u0 = whr[k], u1 = whr[(k - 1) & 15], u2 = whr[(k - 2) & 15],
        u3 = whr[(k - 3) & 15], u4 = whr[(k - 4) & 15],
        u5 = whr[(k - 5) & 15], u6 = whr[(k - 6) & 15],
        u7 = whr[(k - 7) & 15], u8 = whr[(k - 8) & 15],
        u9 = whr[(k - 9) & 15], u10 = whr[(k - 10) & 15],
        u11 = whr[(k - 11) & 15], u12 = whr[(k - 12) & 15],
        u13 = whr[(k - 13) & 15], u14 = whr[(k - 14) & 15],
        u15 = whr[(k - 15) & 15];
  OPQ1(u0)  OPQ1(u1)  OPQ1(u2)  OPQ1(u3)  OPQ1(u4)  OPQ1(u5)
  OPQ1(u6)  OPQ1(u7)  OPQ1(u8)  OPQ1(u9)  OPQ1(u10) OPQ1(u11)
  OPQ1(u12) OPQ1(u13) OPQ1(u14) OPQ1(u15)

  const float gin  = (grp == 2) ? 2.0f : 1.0f;
  const float gout = (grp == 2) ? 2.0f : 1.0f;
  const float gsub = (grp == 2) ? -1.0f : 0.0f;

  const int ostep = dir ? -32 : 32;
  float* op = out1 + (size_t)b * Tn * 32 + dir * 16 +
              (dir ? (size_t)(Tn - 1) * 32 : 0);

  float h = 0.0f, c = 0.0f;

#define STEP1(GX) {                                                       \
    float m0 = fmaf(h, u0, (GX)), m1 = 0.f, m2 = 0.f, m3 = 0.f;           \
    m1 = fmaf(rotr16<1>(h),  u1,  m1);  m2 = fmaf(rotr16<2>(h),  u2,  m2); \
    m3 = fmaf(rotr16<3>(h),  u3,  m3);  m0 = fmaf(rotr16<4>(h),  u4,  m0); \
    m1 = fmaf(rotr16<5>(h),  u5,  m1);  m2 = fmaf(rotr16<6>(h),  u6,  m2); \
    m3 = fmaf(rotr16<7>(h),  u7,  m3);  m0 = fmaf(rotr16<8>(h),  u8,  m0); \
    m1 = fmaf(rotr16<9>(h),  u9,  m1);  m2 = fmaf(rotr16<10>(h), u10, m2); \
    m3 = fmaf(rotr16<11>(h), u11, m3);  m0 = fmaf(rotr16<12>(h), u12, m0); \
    m1 = fmaf(rotr16<13>(h), u13, m1);  m2 = fmaf(rotr16<14>(h), u14, m2); \
    m3 = fmaf(rotr16<15>(h), u15, m3);                                    \
    const float g_ = (m0 + m1) + (m2 + m3);                               \
    const float sg_  = fast_rcp(1.0f + __expf(-gin * g_));                \
    const float val_ = fmaf(gout, sg_, gsub);                             \
    const float e1_ = xor16_lane(val_);                                   \
    const float e2_ = xor32_lane(val_);                                   \
    const float e3_ = xor16_lane(e2_);                                    \
    const float iv_ = (grp == 0) ? val_ : (grp == 1) ? e1_ : (grp == 2) ? e2_ : e3_; \
    const float fv_ = (grp == 1) ? val_ : (grp == 0) ? e1_ : (grp == 3) ? e2_ : e3_; \
    const float gv_ = (grp == 2) ? val_ : (grp == 3) ? e1_ : (grp == 0) ? e2_ : e3_; \
    const float ov_ = (grp == 3) ? val_ : (grp == 2) ? e1_ : (grp == 1) ? e2_ : e3_; \
    c = fmaf(fv_, c, iv_ * gv_);                                          \
    h = ov_ * tanh_fast(c);                                               \
    if (lane < 16) { GST(op + lane, h) }                                  \
    op += ostep;                                                          \
  }

  // Per group: 1 DMA + 4 stores -> counted waits 2/6/10 then 14 (R10-proven).
#define GROUP1(NW, G) {                                                   \
    WAITV(NW);                                                            \
    const float* sb_ = xr + ((G) & 3) * 256;                              \
    const float q0_ = sb_[lane];                                          \
    const float q1_ = sb_[64 + lane];                                     \
    const float q2_ = sb_[128 + lane];                                    \
    const float q3_ = sb_[192 + lane];                                    \
    { const int mp_ = (G) + 3;                                            \
      const int mpc_ = (mp_ < NC) ? mp_ : NC - 1;                         \
      DMA16(gxb + (size_t)mpc_ * 256 + lane * 4, xr + (mp_ & 3) * 256) }  \
    STEP1(q0_) STEP1(q1_) STEP1(q2_) STEP1(q3_)                           \
  }

  GROUP1(2, 0)
  GROUP1(6, 1)
  GROUP1(10, 2)
#pragma unroll 1
  for (int g = 3; g < NC; ++g) {
    GROUP1(14, g)
  }
#undef GROUP1
#undef STEP1
}

// ==================== Scan 2 (gx-fed): H=8 ====================
// grid = 2*B, block = 64; lanes 32-63 replicate (j = lane&31).
// Chunk = 8 s-rows x 32 = 1KB.
__global__ __launch_bounds__(64, 1) void l2_scan_gx(
    const float* __restrict__ gx2,
    const float* __restrict__ whh_f, const float* __restrict__ whh_b,
    float* __restrict__ out) {
  constexpr int NC = Tn / 8;
  const int lane = threadIdx.x;
  const int j    = lane & 31;
  const int dir  = blockIdx.x & 1;
  const int b    = blockIdx.x >> 1;

  __shared__ float xr[4 * 256];
  const float* gxb = gx2 + (size_t)blockIdx.x * Tn * 32;

#pragma unroll
  for (int p = 0; p < 3; ++p)
    DMA16(gxb + (size_t)p * 256 + lane * 4, xr + p * 256)

  const float* whh = dir ? whh_b : whh_f;  // [32][8]
  const int k = j & 7, grp = j >> 3;
  const float* whr = whh + j * 8;
  float u0 = whr[k], u1 = whr[(k - 1) & 7], u2 = whr[(k - 2) & 7],
        u3 = whr[(k - 3) & 7], u4 = whr[(k - 4) & 7],
        u5 = whr[(k - 5) & 7], u6 = whr[(k - 6) & 7],
        u7 = whr[(k - 7) & 7];
  OPQ1(u0) OPQ1(u1) OPQ1(u2) OPQ1(u3) OPQ1(u4) OPQ1(u5) OPQ1(u6) OPQ1(u7)

  const float gin  = (grp == 2) ? 2.0f : 1.0f;
  const float gout = (grp == 2) ? 2.0f : 1.0f;
  const float gsub = (grp == 2) ? -1.0f : 0.0f;

  const int ostep = dir ? -16 : 16;
  float* op = out + (size_t)b * Tn * 16 + dir * 8 +
              (dir ? (size_t)(Tn - 1) * 16 : 0);

  float h = 0.0f, c = 0.0f;

#define STEP2(GX) {                                                       \
    float m0 = fmaf(h, u0, (GX)), m1 = 0.f, m2 = 0.f, m3 = 0.f;           \
    m1 = fmaf(rotr16<1>(h), u1, m1);  m2 = fmaf(rotr16<2>(h), u2, m2);    \
    m3 = fmaf(rotr16<3>(h), u3, m3);  m0 = fmaf(rotr16<4>(h), u4, m0);    \
    m1 = fmaf(rotr16<5>(h), u5, m1);  m2 = fmaf(rotr16<6>(h), u6, m2);    \
    m3 = fmaf(rotr16<7>(h), u7, m3);                                      \
    const float g_ = (m0 + m1) + (m2 + m3);                               \
    const float sg_  = fast_rcp(1.0f + __expf(-gin * g_));                \
    const float val_ = fmaf(gout, sg_, gsub);                             \
    const float e1_ = rotr16<8>(val_);       /* val[l^8], proven DPP */   \
    const float e2_ = xor16_lane(val_);      /* val[l^16] */              \
    const float e3_ = rotr16<8>(e2_);        /* val[l^24] */              \
    const float iv_ = (grp == 0) ? val_ : (grp == 1) ? e1_ : (grp == 2) ? e2_ : e3_; \
    const float fv_ = (grp == 1) ? val_ : (grp == 0) ? e1_ : (grp == 3) ? e2_ : e3_; \
    const float gv_ = (grp == 2) ? val_ : (grp == 3) ? e1_ : (grp == 0) ? e2_ : e3_; \
    const float ov_ = (grp == 3) ? val_ : (grp == 2) ? e1_ : (grp == 1) ? e2_ : e3_; \
    c = fmaf(fv_, c, iv_ * gv_);                                          \
    h = ov_ * tanh_fast(c);                                               \
    if (lane < 8) { GST(op + lane, h) }                                   \
    op += ostep;                                                          \
  }

  // Per group: 1 DMA + 8 stores -> counted waits 2/10/18 then 26 (R10-proven).
#define GROUP2(NW, G) {                                                   \
    WAITV(NW);                                                            \
    const float* sb_ = xr + ((G) & 3) * 256;                              \
    const float q0_ = sb_[j];            const float q1_ = sb_[32 + j];   \
    const float q2_ = sb_[64 + j];       const float q3_ = sb_[96 + j];   \
    const float q4_ = sb_[128 + j];      const float q5_ = sb_[160 + j];  \
    const float q6_ = sb_[192 + j];      const float q7_ = sb_[224 + j];  \
    { const int mp_ = (G) + 3;                                            \
      const int mpc_ = (mp_ < NC) ? mp_ : NC - 1;                         \
      DMA16(gxb + (size_t)mpc_ * 256 + lane * 4, xr + (mp_ & 3) * 256) }  \
    STEP2(q0_) STEP2(q1_) STEP2(q2_) STEP2(q3_)                           \
    STEP2(q4_) STEP2(q5_) STEP2(q6_) STEP2(q7_)                           \
  }

  GROUP2(2, 0)
  GROUP2(10, 1)
  GROUP2(18, 2)
#pragma unroll 1
  for (int g = 3; g < NC; ++g) {
    GROUP2(26, g)
  }
#undef GROUP2
#undef STEP2
}

// ==================== Fallback (R10, proven): weights in scan ====================
__global__ __launch_bounds__(64, 1) void l1_scan_fb(
    const float* __restrict__ x,
    const float* __restrict__ wih_f, const float* __restrict__ whh_f,
    const float* __restrict__ bih_f, const float* __restrict__ bhh_f,
    const float* __restrict__ wih_b, const float* __restrict__ whh_b,
    const float* __restrict__ bih_b, const float* __restrict__ bhh_b,
    float* __restrict__ out1) {
  constexpr int NC = Tn / 4;
  const int lane = threadIdx.x;
  const int dir  = blockIdx.x & 1;
  const int b    = blockIdx.x >> 1;
  __shared__ float xr[4 * 256];
  const float* xb = x + (size_t)b * (Tn * 64);
  {
    const int m0 = dir ? NC - 1 : 0;
    const int md = dir ? -1 : 1;
#pragma unroll
    for (int q = 0; q < 3; ++q) {
      const int mc = m0 + q * md;
      DMA16(xb + (size_t)mc * 256 + lane * 4, xr + (mc & 3) * 256)
    }
  }
  const float* wih = dir ? wih_b : wih_f;
  const float* whh = dir ? whh_b : whh_f;
  float bias = (dir ? bih_b : bih_f)[lane] + (dir ? bhh_b : bhh_f)[lane];
  const int k = lane & 15, grp = lane >> 4;
  const float gin  = (grp == 2) ? 2.0f : 1.0f;
  const float gout = (grp == 2) ? 2.0f : 1.0f;
  const float gsub = (grp == 2) ? -1.0f : 0.0f;
  const float4* wr = reinterpret_cast<const float4*>(wih + lane * 64);
  float4 w0 = wr[0],  w1 = wr[1],  w2 = wr[2],  w3 = wr[3],
         w4 = wr[4],  w5 = wr[5],  w6 = wr[6],  w7 = wr[7],
         w8 = wr[8],  w9 = wr[9],  w10 = wr[10], w11 = wr[11],
         w12 = wr[12], w13 = wr[13], w14 = wr[14], w15 = wr[15];
  const float* whr = whh + lane * 16;
  float u0 = whr[k], u1 = whr[(k - 1) & 15], u2 = whr[(k - 2) & 15],
        u3 = whr[(k - 3) & 15], u4 = whr[(k - 4) & 15],
        u5 = whr[(k - 5) & 15], u6 = whr[(k - 6) & 15],
        u7 = whr[(k - 7) & 15], u8 = whr[(k - 8) & 15],
        u9 = whr[(k - 9) & 15], u10 = whr[(k - 10) & 15],
        u11 = whr[(k - 11) & 15], u12 = whr[(k - 12) & 15],
        u13 = whr[(k - 13) & 15], u14 = whr[(k - 14) & 15],
        u15 = whr[(k - 15) & 15];
  const int ostep = dir ? -32 : 32;
  float* op = out1 + (size_t)b * (Tn * 32) + dir * 16 +
              (dir ? (size_t)(Tn - 1) * 32 : 0);
  float h = 0.0f, c = 0.0f;
#define STEP1F(XROW) {                                                    \
    const float4* xq_ = reinterpret_cast<const float4*>(XROW);            \
    float a0 = bias, a1 = 0.f, a2 = 0.f, a3 = 0.f;                        \
    FMAQ(a0, 0)  FMAQ(a1, 1)  FMAQ(a2, 2)  FMAQ(a3, 3)                   \
    FMAQ(a0, 4)  FMAQ(a1, 5)  FMAQ(a2, 6)  FMAQ(a3, 7)                   \
    FMAQ(a0, 8)  FMAQ(a1, 9)  FMAQ(a2, 10) FMAQ(a3, 11)                  \
    FMAQ(a0, 12) FMAQ(a1, 13) FMAQ(a2, 14) FMAQ(a3, 15)                  \
    const float gx_ = (a0 + a1) + (a2 + a3);                              \
    float m0 = h * u0, m1 = 0.f, m2 = 0.f, m3 = 0.f;                      \
    m1 = fmaf(rotr16<1>(h),  u1,  m1);  m2 = fmaf(rotr16<2>(h),  u2,  m2); \
    m3 = fmaf(rotr16<3>(h),  u3,  m3);  m0 = fmaf(rotr16<4>(h),  u4,  m0); \
    m1 = fmaf(rotr16<5>(h),  u5,  m1);  m2 = fmaf(rotr16<6>(h),  u6,  m2); \
    m3 = fmaf(rotr16<7>(h),  u7,  m3);  m0 = fmaf(rotr16<8>(h),  u8,  m0); \
    m1 = fmaf(rotr16<9>(h),  u9,  m1);  m2 = fmaf(rotr16<10>(h), u10, m2); \
    m3 = fmaf(rotr16<11>(h), u11, m3);  m0 = fmaf(rotr16<12>(h), u12, m0); \
    m1 = fmaf(rotr16<13>(h), u13, m1);  m2 = fmaf(rotr16<14>(h), u14, m2); \
    m3 = fmaf(rotr16<15>(h), u15, m3);                                    \
    const float g_ = ((m0 + m1) + (m2 + m3)) + gx_;                       \
    const float sg_  = fast_rcp(1.0f + __expf(-gin * g_));                \
    const float val_ = fmaf(gout, sg_, gsub);                             \
    const float e1_ = __shfl_xor(val_, 16, 64);                           \
    const float e2_ = __shfl_xor(val_, 32, 64);                           \
    const float e3_ = __shfl_xor(val_, 48, 64);                           \
    const float iv_ = (grp == 0) ? val_ : (grp == 1) ? e1_ : (grp == 2) ? e2_ : e3_; \
    const float fv_ = (grp == 1) ? val_ : (grp == 0) ? e1_ : (grp == 3) ? e2_ : e3_; \
    const float gv_ = (grp == 2) ? val_ : (grp == 3) ? e1_ : (grp == 0) ? e2_ : e3_; \
    const float ov_ = (grp == 3) ? val_ : (grp == 2) ? e1_ : (grp == 1) ? e2_ : e3_; \
    c = fmaf(fv_, c, iv_ * gv_);                                          \
    h = ov_ * tanh_fast(c);                                               \
    if (lane < 16) { GST(op + lane, h) }                                  \
    op += ostep;                                                          \
  }
#define GROUP1F(NW, G) {                                                  \
    const int mq_ = dir ? (NC - 1 - (G)) : (G);                           \
    const float* sb_ = xr + (mq_ & 3) * 256;                              \
    WAITV(NW);                                                            \
    { const int mp_ = dir ? (mq_ - 3) : (mq_ + 3);                        \
      const int sl_ = mp_ & 3;                                            \
      const int mpc_ = mp_ < 0 ? 0 : (mp_ >= NC ? NC - 1 : mp_);          \
      DMA16(xb + (size_t)mpc_ * 256 + lane * 4, xr + sl_ * 256) }         \
    STEP1F(sb_ + (dir ? 3 : 0) * 64)                                      \
    STEP1F(sb_ + (dir ? 2 : 1) * 64)                                      \
    STEP1F(sb_ + (dir ? 1 : 2) * 64)                                      \
    STEP1F(sb_ + (dir ? 0 : 3) * 64)                                      \
  }
  GROUP1F(2, 0)
  GROUP1F(6, 1)
  GROUP1F(10, 2)
#pragma unroll 1
  for (int g = 3; g < NC; ++g) {
    GROUP1F(14, g)
  }
#undef GROUP1F
#undef STEP1F
}

__global__ __launch_bounds__(64, 1) void l2_scan_fb(
    const float* __restrict__ in,
    const float* __restrict__ wih_f, const float* __restrict__ whh_f,
    const float* __restrict__ bih_f, const float* __restrict__ bhh_f,
    const float* __restrict__ wih_b, const float* __restrict__ whh_b,
    const float* __restrict__ bih_b, const float* __restrict__ bhh_b,
    float* __restrict__ out) {
  constexpr int NC = Tn / 8;
  const int lane = threadIdx.x;
  const int j    = lane & 31;
  const int dir  = blockIdx.x & 1;
  const int b    = blockIdx.x >> 1;
  __shared__ float xr[4 * 256];
  const float* ib = in + (size_t)b * (Tn * 32);
  {
    const int m0 = dir ? NC - 1 : 0;
    const int md = dir ? -1 : 1;
#pragma unroll
    for (int q = 0; q < 3; ++q) {
      const int mc = m0 + q * md;
      DMA16(ib + (size_t)mc * 256 + lane * 4, xr + (mc & 3) * 256)
    }
  }
  const float* wih = dir ? wih_b : wih_f;
  const float* whh = dir ? whh_b : whh_f;
  float bias = (dir ? bih_b : bih_f)[j] + (dir ? bhh_b : bhh_f)[j];
  const int k = j & 7, grp = j >> 3;
  const float gin  = (grp == 2) ? 2.0f : 1.0f;
  const float gout = (grp == 2) ? 2.0f : 1.0f;
  const float gsub = (grp == 2) ? -1.0f : 0.0f;
  const float4* wr = reinterpret_cast<const float4*>(wih + j * 32);
  float4 w0 = wr[0], w1 = wr[1], w2 = wr[2], w3 = wr[3],
         w4 = wr[4], w5 = wr[5], w6 = wr[6], w7 = wr[7];
  const float* whr = whh + j * 8;
  float u0 = whr[k], u1 = whr[(k - 1) & 7], u2 = whr[(k - 2) & 7],
        u3 = whr[(k - 3) & 7], u4 = whr[(k - 4) & 7],
        u5 = whr[(k - 5) & 7], u6 = whr[(k - 6) & 7],
        u7 = whr[(k - 7) & 7];
  const int ostep = dir ? -16 : 16;
  float* op = out + (size_t)b * (Tn * 16) + dir * 8 +
              (dir ? (size_t)(Tn - 1) * 16 : 0);
  float h = 0.0f, c = 0.0f;
#define STEP2F(XROW) {                                                    \
    const float4* xq_ = reinterpret_cast<const float4*>(XROW);            \
    float a0 = bias, a1 = 0.f, a2 = 0.f, a3 = 0.f;                        \
    FMAQ(a0, 0) FMAQ(a1, 1) FMAQ(a2, 2) FMAQ(a3, 3)                      \
    FMAQ(a0, 4) FMAQ(a1, 5) FMAQ(a2, 6) FMAQ(a3, 7)                      \
    const float gx_ = (a0 + a1) + (a2 + a3);                              \
    float m0 = h * u0, m1 = 0.f, m2 = 0.f, m3 = 0.f;                      \
    m1 = fmaf(rotr16<1>(h), u1, m1);  m2 = fmaf(rotr16<2>(h), u2, m2);    \
    m3 = fmaf(rotr16<3>(h), u3, m3);  m0 = fmaf(rotr16<4>(h), u4, m0);    \
    m1 = fmaf(rotr16<5>(h), u5, m1);  m2 = fmaf(rotr16<6>(h), u6, m2);    \
    m3 = fmaf(rotr16<7>(h), u7, m3);                                      \
    const float g_ = ((m0 + m1) + (m2 + m3)) + gx_;                       \
    const float sg_  = fast_rcp(1.0f + __expf(-gin * g_));                \
    const float val_ = fmaf(gout, sg_, gsub);                             \
    const float e1_ = __shfl_xor(val_, 8, 64);                            \
    const float e2_ = __shfl_xor(val_, 16, 64);                           \
    const float e3_ = __shfl_xor(val_, 24, 64);                           \
    const float iv_ = (grp == 0) ? val_ : (grp == 1) ? e1_ : (grp == 2) ? e2_ : e3_; \
    const float fv_ = (grp == 1) ? val_ : (grp == 0) ? e1_ : (grp == 3) ? e2_ : e3_; \
    const float gv_ = (grp == 2) ? val_ : (grp == 3) ? e1_ : (grp == 0) ? e2_ : e3_; \
    const float ov_ = (grp == 3) ? val_ : (grp == 2) ? e1_ : (grp == 1) ? e2_ : e3_; \
    c = fmaf(fv_, c, iv_ * gv_);                                          \
    h = ov_ * tanh_fast(c);                                               \
    if (lane < 8) { GST(op + lane, h) }                                   \
    op += ostep;                                                          \
  }
#define GROUP2F(NW, G) {                                                  \
    const int mq_ = dir ? (NC - 1 - (G)) : (G);                           \
    const float* sb_ = xr + (mq_ & 3) * 256;                              \
    WAITV(NW);                                                            \
    { const int mp_ = dir ? (mq_ - 3) : (mq_ + 3);                        \
      const int sl_ = mp_ & 3;                                            \
      const int mpc_ = mp_ < 0 ? 0 : (mp_ >= NC ? NC - 1 : mp_);          \
      DMA16(ib + (size_t)mpc_ * 256 + lane * 4, xr + sl_ * 256) }         \
    STEP2F(sb_ + (dir ? 7 : 0) * 32)                                      \
    STEP2F(sb_ + (dir ? 6 : 1) * 32)                                      \
    STEP2F(sb_ + (dir ? 5 : 2) * 32)                                      \
    STEP2F(sb_ + (dir ? 4 : 3) * 32)                                      \
    STEP2F(sb_ + (dir ? 3 : 4) * 32)                                      \
    STEP2F(sb_ + (dir ? 2 : 5) * 32)                                      \
    STEP2F(sb_ + (dir ? 1 : 6) * 32)                                      \
    STEP2F(sb_ + (dir ? 0 : 7) * 32)                                      \
  }
  GROUP2F(2, 0)
  GROUP2F(10, 1)
  GROUP2F(18, 2)
#pragma unroll 1
  for (int g = 3; g < NC; ++g) {
    GROUP2F(26, g)
  }
#undef GROUP2F
#undef STEP2F
}

extern "C" void kernel_launch(void* const* d_in, const int* in_sizes, int n_in,
                              void* d_out, int out_size, void* d_ws, size_t ws_size,
                              hipStream_t stream) {
  const float* x     = (const float*)d_in[0];
  const float* wih1f = (const float*)d_in[1];
  const float* whh1f = (const float*)d_in[2];
  const float* bih1f = (const float*)d_in[3];
  const float* bhh1f = (const float*)d_in[4];
  const float* wih1b = (const float*)d_in[5];
  const float* whh1b = (const float*)d_in[6];
  const float* bih1b = (const float*)d_in[7];
  const float* bhh1b = (const float*)d_in[8];
  const float* wih2f = (const float*)d_in[9];
  const float* whh2f = (const float*)d_in[10];
  const float* bih2f = (const float*)d_in[11];
  const float* bhh2f = (const float*)d_in[12];
  const float* wih2b = (const float*)d_in[13];
  const float* whh2b = (const float*)d_in[14];
  const float* bih2b = (const float*)d_in[15];
  const float* bhh2b = (const float*)d_in[16];

  float* out1 = (float*)d_ws;                       // [B][T][32] = 67.1 MB
  float* outp = (float*)d_out;                      // [B][T][16]

  const size_t out1F = (size_t)Bn * Tn * 32;
  const size_t gx1F  = (size_t)Bn * 2 * Tn * 64;    // 268.4 MB
  const size_t needB = (out1F + gx1F) * sizeof(float);

  if (ws_size >= needB) {
    float* gx1 = (float*)d_ws + out1F;              // [2B][T][64]
    float* gx2 = gx1;                               // aliases gx1 (dead after scan1)
    gemm_gx1<<<Bn * 2 * 16, 64, 0, stream>>>(
        x, wih1f, bih1f, bhh1f, wih1b, bih1b, bhh1b, gx1);
    l1_scan_gx<<<Bn * 2, 64, 0, stream>>>(gx1, whh1f, whh1b, out1);
    gemm_gx2<<<Bn * 16, 64, 0, stream>>>(
        out1, wih2f, bih2f, bhh2f, wih2b, bih2b, bhh2b, gx2);
    l2_scan_gx<<<Bn * 2, 64, 0, stream>>>(gx2, whh2f, whh2b, outp);
  } else {
    l1_scan_fb<<<Bn * 2, 64, 0, stream>>>(x, wih1f, whh1f, bih1f, bhh1f,
                                          wih1b, whh1b, bih1b, bhh1b, out1);
    l2_scan_fb<<<Bn * 2, 64, 0, stream>>>(out1, wih2f, whh2f, bih2f, bhh2f,
                                          wih2b, whh2b, bih2b, bhh2b, outp);
  }
}

// Round 14
// 1230.664 us; speedup vs baseline: 1.6038x; 1.0831x over previous
//
#include <hip/hip_runtime.h>

// 2-layer bidirectional LSTM, B=256 T=2048 D=64, H1=16/dir, H2=8/dir.
// R14 = R13 (PASS, 1333us) + three exact chain cuts in the scans:
//  1. GX joins at the END of the butterfly tree (R4 pattern): the group's
//     LDS q-read gets ~100cy of butterfly to land instead of stalling the
//     step's first instruction (~120cy/group exposed -> ~20cy).
//  2. Prescale (exact, x-1/x-2): gemms write -gin*gx, scans load -gin*u;
//     sigmoid becomes rcp(1+exp(g)) - one mul+negate off the serial chain.
//  3. Stores batched at group end under ONE exec-mask toggle (h stashed in
//     regs): removes per-step asm-region breaks. vmcnt counts per group
//     unchanged (1 DMA + 4/8 GST) -> proven waits 2/6/10,14 and 2/10/18,26.
// R13 post-mortem: exchange surgery (bpermute->permlane) was a NO-OP on wall
// time (473->469us) => step is latency-bound on the 4 serial transcendentals
// + butterfly dep chain, NOT on exchange or issue count. These cuts target
// the remaining reducible overheads.
// gemm + fallback kernels otherwise unchanged (fallbacks use orig math).

#ifndef __has_builtin
#define __has_builtin(x) 0
#endif

constexpr int Bn = 256;
constexpr int Tn = 2048;

typedef unsigned int uint2v __attribute__((ext_vector_type(2)));

__device__ __forceinline__ float fast_rcp(float x) { return __builtin_amdgcn_rcpf(x); }
__device__ __forceinline__ float tanh_fast(float x) {
  return fmaf(2.0f, fast_rcp(1.0f + __expf(-2.0f * x)), -1.0f);
}

// DPP rotate-right by R within each 16-lane row: dst[l] = src[(l-R)&15].
template <int R>
__device__ __forceinline__ float rotr16(float v) {
  return __int_as_float(__builtin_amdgcn_mov_dpp(
      __float_as_int(v), 0x120 | R, 0xF, 0xF, true));
}

// val[l^16] / val[l^32], polarity-proof XOR-combine (R13-proven).
__device__ __forceinline__ float xor16_lane(float v) {
#if __has_builtin(__builtin_amdgcn_permlane16_swap)
  const unsigned u = __float_as_uint(v);
  uint2v r = __builtin_amdgcn_permlane16_swap(u, u, false, false);
  return __uint_as_float(r[0] ^ r[1] ^ u);
#else
  return __shfl_xor(v, 16, 64);
#endif
}
__device__ __forceinline__ float xor32_lane(float v) {
#if __has_builtin(__builtin_amdgcn_permlane32_swap)
  const unsigned u = __float_as_uint(v);
  uint2v r = __builtin_amdgcn_permlane32_swap(u, u, false, false);
  return __uint_as_float(r[0] ^ r[1] ^ u);
#else
  return __shfl_xor(v, 32, 64);
#endif
}

#define OPQ4(v) asm("" : "+v"(v.x), "+v"(v.y), "+v"(v.z), "+v"(v.w));
#define OPQ1(v) asm("" : "+v"(v));

#define GST(addr, val) \
  asm volatile("global_store_dword %0, %1, off" :: "v"(addr), "v"(val));

#define WAITV(N)                                              \
  do {                                                        \
    asm volatile("s_waitcnt vmcnt(" #N ")" ::: "memory");     \
    __builtin_amdgcn_sched_barrier(0);                        \
  } while (0)

#define DMA16(gsrc, ldst)                                         \
  __builtin_amdgcn_global_load_lds(                               \
      (const __attribute__((address_space(1))) float*)(gsrc),     \
      (__attribute__((address_space(3))) float*)(ldst), 16, 0, 0);

#define FMAU(ACC, I) { const float4 xv_ = x4[I];                    \
    ACC = fmaf(xv_.x, w##I.x, ACC); ACC = fmaf(xv_.y, w##I.y, ACC); \
    ACC = fmaf(xv_.z, w##I.z, ACC); ACC = fmaf(xv_.w, w##I.w, ACC); }

#define FMAQ(ACC, I) { float4 v_ = xq_[I];                          \
    ACC = fmaf(v_.x, w##I.x, ACC); ACC = fmaf(v_.y, w##I.y, ACC);   \
    ACC = fmaf(v_.z, w##I.z, ACC); ACC = fmaf(v_.w, w##I.w, ACC); }

// ==================== GEMM 1: gx1[bd][s][64], PRESCALED by -gin ====================
__global__ __launch_bounds__(64, 4) void gemm_gx1(
    const float* __restrict__ x,
    const float* __restrict__ wf, const float* __restrict__ bif,
    const float* __restrict__ bhf,
    const float* __restrict__ wb, const float* __restrict__ bib,
    const float* __restrict__ bhb,
    float* __restrict__ gx1) {
  constexpr int TILES = 16, TT = Tn / TILES;
  const int lane = threadIdx.x;
  const int bd   = blockIdx.x / TILES;
  const int tile = blockIdx.x % TILES;
  const int dir  = bd & 1, b = bd >> 1;

  const float* W = dir ? wb : wf;  // [64][64]
  float bias = (dir ? bib : bif)[lane] + (dir ? bhb : bhf)[lane];
  const float sc = ((lane >> 4) == 2) ? -2.0f : -1.0f;   // -gin per gate row

  const float4* wr = reinterpret_cast<const float4*>(W + lane * 64);
  float4 w0 = wr[0],  w1 = wr[1],  w2 = wr[2],  w3 = wr[3],
         w4 = wr[4],  w5 = wr[5],  w6 = wr[6],  w7 = wr[7],
         w8 = wr[8],  w9 = wr[9],  w10 = wr[10], w11 = wr[11],
         w12 = wr[12], w13 = wr[13], w14 = wr[14], w15 = wr[15];
  OPQ4(w0)  OPQ4(w1)  OPQ4(w2)  OPQ4(w3)  OPQ4(w4)  OPQ4(w5)
  OPQ4(w6)  OPQ4(w7)  OPQ4(w8)  OPQ4(w9)  OPQ4(w10) OPQ4(w11)
  OPQ4(w12) OPQ4(w13) OPQ4(w14) OPQ4(w15) OPQ1(bias)

  float* gout = gx1 + (size_t)bd * Tn * 64;
  for (int tt = 0; tt < TT; ++tt) {
    const int t = tile * TT + tt;
    const float4* x4 =
        reinterpret_cast<const float4*>(x + ((size_t)b * Tn + t) * 64);
    float a0 = bias, a1 = 0.f, a2 = 0.f, a3 = 0.f;
    FMAU(a0, 0)  FMAU(a1, 1)  FMAU(a2, 2)  FMAU(a3, 3)
    FMAU(a0, 4)  FMAU(a1, 5)  FMAU(a2, 6)  FMAU(a3, 7)
    FMAU(a0, 8)  FMAU(a1, 9)  FMAU(a2, 10) FMAU(a3, 11)
    FMAU(a0, 12) FMAU(a1, 13) FMAU(a2, 14) FMAU(a3, 15)
    const float acc = (a0 + a1) + (a2 + a3);
    const int s = dir ? (Tn - 1 - t) : t;
    gout[(size_t)s * 64 + lane] = sc * acc;
  }
}

// ==================== GEMM 2: gx2[bd][s][32], PRESCALED by -gin ====================
__global__ __launch_bounds__(64, 4) void gemm_gx2(
    const float* __restrict__ in,   // out1 [B][T][32]
    const float* __restrict__ wf, const float* __restrict__ bif,
    const float* __restrict__ bhf,
    const float* __restrict__ wb, const float* __restrict__ bib,
    const float* __restrict__ bhb,
    float* __restrict__ gx2) {
  constexpr int TILES = 16, TT = Tn / TILES;
  const int lane = threadIdx.x;
  const int g = lane & 31, half = lane >> 5;
  const int b = blockIdx.x / TILES, tile = blockIdx.x % TILES;

  const float* W = half ? wb : wf;  // [32][32]
  float bias = (half ? bib : bif)[g] + (half ? bhb : bhf)[g];
  const float sc = ((g >> 3) == 2) ? -2.0f : -1.0f;

  const float4* wr = reinterpret_cast<const float4*>(W + g * 32);
  float4 w0 = wr[0], w1 = wr[1], w2 = wr[2], w3 = wr[3],
         w4 = wr[4], w5 = wr[5], w6 = wr[6], w7 = wr[7];
  OPQ4(w0) OPQ4(w1) OPQ4(w2) OPQ4(w3) OPQ4(w4) OPQ4(w5) OPQ4(w6) OPQ4(w7)
  OPQ1(bias)

  for (int tt = 0; tt < TT; ++tt) {
    const int t = tile * TT + tt;
    const float4* x4 =
        reinterpret_cast<const float4*>(in + ((size_t)b * Tn + t) * 32);
    float a0 = bias, a1 = 0.f, a2 = 0.f, a3 = 0.f;
    FMAU(a0, 0) FMAU(a1, 1) FMAU(a2, 2) FMAU(a3, 3)
    FMAU(a0, 4) FMAU(a1, 5) FMAU(a2, 6) FMAU(a3, 7)
    const float acc = (a0 + a1) + (a2 + a3);
    const int s = half ? (Tn - 1 - t) : t;
    gx2[((size_t)(b * 2 + half) * Tn + s) * 32 + g] = sc * acc;
  }
}

// ==================== Scan 1 (gx-fed, prescaled): H=16 ====================
__global__ __launch_bounds__(64, 1) void l1_scan_gx(
    const float* __restrict__ gx1,
    const float* __restrict__ whh_f, const float* __restrict__ whh_b,
    float* __restrict__ out1) {
  constexpr int NC = Tn / 4;
  const int lane = threadIdx.x;
  const int dir  = blockIdx.x & 1;
  const int b    = blockIdx.x >> 1;

  __shared__ float xr[4 * 256];
  const float* gxb = gx1 + (size_t)blockIdx.x * Tn * 64;

#pragma unroll
  for (int p = 0; p < 3; ++p)
    DMA16(gxb + (size_t)p * 256 + lane * 4, xr + p * 256)

  const float* whh = dir ? whh_b : whh_f;  // [64][16]
  const int k = lane & 15, grp = lane >> 4;
  const float sc = (grp == 2) ? -2.0f : -1.0f;   // -gin (matches gemm prescale)
  const float* whr = whh + lane * 16;
  float u0 = sc * whr[k], u1 = sc * whr[(k - 1) & 15],
        u2 = sc * whr[(k - 2) & 15], u3 = sc * whr[(k - 3) & 15],
        u4 = sc * whr[(k - 4) & 15], u5 = sc * whr[(k - 5) & 15],
        u6 = sc * whr[(k - 6) & 15], u7 = sc * whr[(k - 7) & 15],
        u8 = sc * whr[(k - 8) & 15], u9 = sc * whr[(k - 9) & 15],
        u10 = sc * whr[(k - 10) & 15], u11 = sc * whr[(k - 11) & 15],
        u12 = sc * whr[(k - 12) & 15], u13 = sc * whr[(k - 13) & 15],
        u14 = sc * whr[(k - 14) & 15], u15 = sc * whr[(k - 15) & 15];
  OPQ1(u0)  OPQ1(u1)  OPQ1(u2)  OPQ1(u3)  OPQ1(u4)  OPQ1(u5)
  OPQ1(u6)  OPQ1(u7)  OPQ1(u8)  OPQ1(u9)  OPQ1(u10) OPQ1(u11)
  OPQ1(u12) OPQ1(u13) OPQ1(u14) OPQ1(u15)

  const float gout = (grp == 2) ? 2.0f : 1.0f;
  const float gsub = (grp == 2) ? -1.0f : 0.0f;

  const int ostep = dir ? -32 : 32;
  float* op = out1 + (size_t)b * Tn * 32 + dir * 16 +
              (dir ? (size_t)(Tn - 1) * 32 : 0);

  float h = 0.0f, c = 0.0f;

  // Step: butterfly first; GX (prescaled) joins at the TREE END so the LDS
  // q-read has the whole butterfly to land. sigmoid = rcp(1+exp(g)).
#define STEP1(GX, HS) {                                                   \
    float m0 = h * u0, m1 = 0.f, m2 = 0.f, m3 = 0.f;                      \
    m1 = fmaf(rotr16<1>(h),  u1,  m1);  m2 = fmaf(rotr16<2>(h),  u2,  m2); \
    m3 = fmaf(rotr16<3>(h),  u3,  m3);  m0 = fmaf(rotr16<4>(h),  u4,  m0); \
    m1 = fmaf(rotr16<5>(h),  u5,  m1);  m2 = fmaf(rotr16<6>(h),  u6,  m2); \
    m3 = fmaf(rotr16<7>(h),  u7,  m3);  m0 = fmaf(rotr16<8>(h),  u8,  m0); \
    m1 = fmaf(rotr16<9>(h),  u9,  m1);  m2 = fmaf(rotr16<10>(h), u10, m2); \
    m3 = fmaf(rotr16<11>(h), u11, m3);  m0 = fmaf(rotr16<12>(h), u12, m0); \
    m1 = fmaf(rotr16<13>(h), u13, m1);  m2 = fmaf(rotr16<14>(h), u14, m2); \
    m3 = fmaf(rotr16<15>(h), u15, m3);                                    \
    const float g_ = ((m0 + m1) + (m2 + m3)) + (GX);                      \
    const float sg_  = fast_rcp(1.0f + __expf(g_));                       \
    const float val_ = fmaf(gout, sg_, gsub);                             \
    const float e1_ = xor16_lane(val_);                                   \
    const float e2_ = xor32_lane(val_);                                   \
    const float e3_ = xor16_lane(e2_);                                    \
    const float iv_ = (grp == 0) ? val_ : (grp == 1) ? e1_ : (grp == 2) ? e2_ : e3_; \
    const float fv_ = (grp == 1) ? val_ : (grp == 0) ? e1_ : (grp == 3) ? e2_ : e3_; \
    const float gv_ = (grp == 2) ? val_ : (grp == 3) ? e1_ : (grp == 0) ? e2_ : e3_; \
    const float ov_ = (grp == 3) ? val_ : (grp == 2) ? e1_ : (grp == 1) ? e2_ : e3_; \
    c = fmaf(fv_, c, iv_ * gv_);                                          \
    h = ov_ * tanh_fast(c);                                               \
    HS = h;                                                               \
  }

  // Per group: 1 DMA + 4 GST (batched at end) -> waits 2/6/10 then 14.
#define GROUP1(NW, G) {                                                   \
    WAITV(NW);                                                            \
    const float* sb_ = xr + ((G) & 3) * 256;                              \
    const float q0_ = sb_[lane];                                          \
    const float q1_ = sb_[64 + lane];                                     \
    const float q2_ = sb_[128 + lane];                                    \
    const float q3_ = sb_[192 + lane];                                    \
    { const int mp_ = (G) + 3;                                            \
      const int mpc_ = (mp_ < NC) ? mp_ : NC - 1;                         \
      DMA16(gxb + (size_t)mpc_ * 256 + lane * 4, xr + (mp_ & 3) * 256) }  \
    float h0_, h1_, h2_, h3_;                                             \
    STEP1(q0_, h0_) STEP1(q1_, h1_) STEP1(q2_, h2_) STEP1(q3_, h3_)       \
    if (lane < 16) {                                                      \
      GST(op + lane, h0_)                                                 \
      GST(op + ostep + lane, h1_)                                         \
      GST(op + 2 * ostep + lane, h2_)                                     \
      GST(op + 3 * ostep + lane, h3_)                                     \
    }                                                                     \
    op += 4 * ostep;                                                      \
  }

  GROUP1(2, 0)
  GROUP1(6, 1)
  GROUP1(10, 2)
#pragma unroll 1
  for (int g = 3; g < NC; ++g) {
    GROUP1(14, g)
  }
#undef GROUP1
#undef STEP1
}

// ==================== Scan 2 (gx-fed, prescaled): H=8 ====================
__global__ __launch_bounds__(64, 1) void l2_scan_gx(
    const float* __restrict__ gx2,
    const float* __restrict__ whh_f, const float* __restrict__ whh_b,
    float* __restrict__ out) {
  constexpr int NC = Tn / 8;
  const int lane = threadIdx.x;
  const int j    = lane & 31;
  const int dir  = blockIdx.x & 1;
  const int b    = blockIdx.x >> 1;

  __shared__ float xr[4 * 256];
  const float* gxb = gx2 + (size_t)blockIdx.x * Tn * 32;

#pragma unroll
  for (int p = 0; p < 3; ++p)
    DMA16(gxb + (size_t)p * 256 + lane * 4, xr + p * 256)

  const float* whh = dir ? whh_b : whh_f;  // [32][8]
  const int k = j & 7, grp = j >> 3;
  const float sc = (grp == 2) ? -2.0f : -1.0f;
  const float* whr = whh + j * 8;
  float u0 = sc * whr[k], u1 = sc * whr[(k - 1) & 7],
        u2 = sc * whr[(k - 2) & 7], u3 = sc * whr[(k - 3) & 7],
        u4 = sc * whr[(k - 4) & 7], u5 = sc * whr[(k - 5) & 7],
        u6 = sc * whr[(k - 6) & 7], u7 = sc * whr[(k - 7) & 7];
  OPQ1(u0) OPQ1(u1) OPQ1(u2) OPQ1(u3) OPQ1(u4) OPQ1(u5) OPQ1(u6) OPQ1(u7)

  const float gout = (grp == 2) ? 2.0f : 1.0f;
  const float gsub = (grp == 2) ? -1.0f : 0.0f;

  const int ostep = dir ? -16 : 16;
  float* op = out + (size_t)b * Tn * 16 + dir * 8 +
              (dir ? (size_t)(Tn - 1) * 16 : 0);

  float h = 0.0f, c = 0.0f;

#define STEP2(GX, HS) {                                                   \
    float m0 = h * u0, m1 = 0.f, m2 = 0.f, m3 = 0.f;                      \
    m1 = fmaf(rotr16<1>(h), u1, m1);  m2 = fmaf(rotr16<2>(h), u2, m2);    \
    m3 = fmaf(rotr16<3>(h), u3, m3);  m0 = fmaf(rotr16<4>(h), u4, m0);    \
    m1 = fmaf(rotr16<5>(h), u5, m1);  m2 = fmaf(rotr16<6>(h), u6, m2);    \
    m3 = fmaf(rotr16<7>(h), u7, m3);                                      \
    const float g_ = ((m0 + m1) + (m2 + m3)) + (GX);                      \
    const float sg_  = fast_rcp(1.0f + __expf(g_));                       \
    const float val_ = fmaf(gout, sg_, gsub);                             \
    const float e1_ = rotr16<8>(val_);       /* val[l^8] */               \
    const float e2_ = xor16_lane(val_);      /* val[l^16] */              \
    const float e3_ = rotr16<8>(e2_);        /* val[l^24] */              \
    const float iv_ = (grp == 0) ? val_ : (grp == 1) ? e1_ : (grp == 2) ? e2_ : e3_; \
    const float fv_ = (grp == 1) ? val_ : (grp == 0) ? e1_ : (grp == 3) ? e2_ : e3_; \
    const float gv_ = (grp == 2) ? val_ : (grp == 3) ? e1_ : (grp == 0) ? e2_ : e3_; \
    const float ov_ = (grp == 3) ? val_ : (grp == 2) ? e1_ : (grp == 1) ? e2_ : e3_; \
    c = fmaf(fv_, c, iv_ * gv_);                                          \
    h = ov_ * tanh_fast(c);                                               \
    HS = h;                                                               \
  }

  // Per group: 1 DMA + 8 GST (batched) -> waits 2/10/18 then 26.
#define GROUP2(NW, G) {                                                   \
    WAITV(NW);                                                            \
    const float* sb_ = xr + ((G) & 3) * 256;                              \
    const float q0_ = sb_[j];            const float q1_ = sb_[32 + j];   \
    const float q2_ = sb_[64 + j];       const float q3_ = sb_[96 + j];   \
    const float q4_ = sb_[128 + j];      const float q5_ = sb_[160 + j];  \
    const float q6_ = sb_[192 + j];      const float q7_ = sb_[224 + j];  \
    { const int mp_ = (G) + 3;                                            \
      const int mpc_ = (mp_ < NC) ? mp_ : NC - 1;                         \
      DMA16(gxb + (size_t)mpc_ * 256 + lane * 4, xr + (mp_ & 3) * 256) }  \
    float h0_, h1_, h2_, h3_, h4_, h5_, h6_, h7_;                         \
    STEP2(q0_, h0_) STEP2(q1_, h1_) STEP2(q2_, h2_) STEP2(q3_, h3_)       \
    STEP2(q4_, h4_) STEP2(q5_, h5_) STEP2(q6_, h6_) STEP2(q7_, h7_)       \
    if (lane < 8) {                                                       \
      GST(op + lane, h0_)                                                 \
      GST(op + ostep + lane, h1_)                                         \
      GST(op + 2 * ostep + lane, h2_)                                     \
      GST(op + 3 * ostep + lane, h3_)                                     \
      GST(op + 4 * ostep + lane, h4_)                                     \
      GST(op + 5 * ostep + lane, h5_)                                     \
      GST(op + 6 * ostep + lane, h6_)                                     \
      GST(op + 7 * ostep + lane, h7_)                                     \
    }                                                                     \
    op += 8 * ostep;                                                      \
  }

  GROUP2(2, 0)
  GROUP2(10, 1)
  GROUP2(18, 2)
#pragma unroll 1
  for (int g = 3; g < NC; ++g) {
    GROUP2(26, g)
  }
#undef GROUP2
#undef STEP2
}

// ==================== Fallback (R10, proven): weights in scan ====================
__global__ __launch_bounds__(64, 1) void l1_scan_fb(
    const float* __restrict__ x,
    const float* __restrict__ wih_f, const float* __restrict__ whh_f,
    const float* __restrict__ bih_f, const float* __restrict__ bhh_f,
    const float* __restrict__ wih_b, const float* __restrict__ whh_b,
    const float* __restrict__ bih_b, const float* __restrict__ bhh_b,
    float* __restrict__ out1) {
  constexpr int NC = Tn / 4;
  const int lane = threadIdx.x;
  const int dir  = blockIdx.x & 1;
  const int b    = blockIdx.x >> 1;
  __shared__ float xr[4 * 256];
  const float* xb = x + (size_t)b * (Tn * 64);
  {
    const int m0 = dir ? NC - 1 : 0;
    const int md = dir ? -1 : 1;
#pragma unroll
    for (int q = 0; q < 3; ++q) {
      const int mc = m0 + q * md;
      DMA16(xb + (size_t)mc * 256 + lane * 4, xr + (mc & 3) * 256)
    }
  }
  const float* wih = dir ? wih_b : wih_f;
  const float* whh = dir ? whh_b : whh_f;
  float bias = (dir ? bih_b : bih_f)[lane] + (dir ? bhh_b : bhh_f)[lane];
  const int k = lane & 15, grp = lane >> 4;
  const float gin  = (grp == 2) ? 2.0f : 1.0f;
  const float gout = (grp == 2) ? 2.0f : 1.0f;
  const float gsub = (grp == 2) ? -1.0f : 0.0f;
  const float4* wr = reinterpret_cast<const float4*>(wih + lane * 64);
  float4 w0 = wr[0],  w1 = wr[1],  w2 = wr[2],  w3 = wr[3],
         w4 = wr[4],  w5 = wr[5],  w6 = wr[6],  w7 = wr[7],
         w8 = wr[8],  w9 = wr[9],  w10 = wr[10], w11 = wr[11],
         w12 = wr[12], w13 = wr[13], w14 = wr[14], w15 = wr[15];
  const float* whr = whh + lane * 16;
  float u0 = whr[k], u1 = whr[(k - 1) & 15], u2 = whr[(k - 2) & 15],
        u3 = whr[(k - 3) & 15], u4 = whr[(k - 4) & 15],
        u5 = whr[(k - 5) & 15], u6 = whr[(k - 6) & 15],
        u7 = whr[(k - 7) & 15], u8 = whr[(k - 8) & 15],
        u9 = whr[(k - 9) & 15], u10 = whr[(k - 10) & 15],
        u11 = whr[(k - 11) & 15], u12 = whr[(k - 12) & 15],
        u13 = whr[(k - 13) & 15], u14 = whr[(k - 14) & 15],
        u15 = whr[(k - 15) & 15];
  const int ostep = dir ? -32 : 32;
  float* op = out1 + (size_t)b * (Tn * 32) + dir * 16 +
              (dir ? (size_t)(Tn - 1) * 32 : 0);
  float h = 0.0f, c = 0.0f;
#define STEP1F(XROW) {                                                    \
    const float4* xq_ = reinterpret_cast<const float4*>(XROW);            \
    float a0 = bias, a1 = 0.f, a2 = 0.f, a3 = 0.f;                        \
    FMAQ(a0, 0)  FMAQ(a1, 1)  FMAQ(a2, 2)  FMAQ(a3, 3)                   \
    FMAQ(a0, 4)  FMAQ(a1, 5)  FMAQ(a2, 6)  FMAQ(a3, 7)                   \
    FMAQ(a0, 8)  FMAQ(a1, 9)  FMAQ(a2, 10) FMAQ(a3, 11)                  \
    FMAQ(a0, 12) FMAQ(a1, 13) FMAQ(a2, 14) FMAQ(a3, 15)                  \
    const float gx_ = (a0 + a1) + (a2 + a3);                              \
    float m0 = h * u0, m1 = 0.f, m2 = 0.f, m3 = 0.f;                      \
    m1 = fmaf(rotr16<1>(h),  u1,  m1);  m2 = fmaf(rotr16<2>(h),  u2,  m2); \
    m3 = fmaf(rotr16<3>(h),  u3,  m3);  m0 = fmaf(rotr16<4>(h),  u4,  m0); \
    m1 = fmaf(rotr16<5>(h),  u5,  m1);  m2 = fmaf(rotr16<6>(h),  u6,  m2); \
    m3 = fmaf(rotr16<7>(h),  u7,  m3);  m0 = fmaf(rotr16<8>(h),  u8,  m0); \
    m1 = fmaf(rotr16<9>(h),  u9,  m1);  m2 = fmaf(rotr16<10>(h), u10, m2); \
    m3 = fmaf(rotr16<11>(h), u11, m3);  m0 = fmaf(rotr16<12>(h), u12, m0); \
    m1 = fmaf(rotr16<13>(h), u13, m1);  m2 = fmaf(rotr16<14>(h), u14, m2); \
    m3 = fmaf(rotr16<15>(h), u15, m3);                                    \
    const float g_ = ((m0 + m1) + (m2 + m3)) + gx_;                       \
    const float sg_  = fast_rcp(1.0f + __expf(-gin * g_));                \
    const float val_ = fmaf(gout, sg_, gsub);                             \
    const float e1_ = __shfl_xor(val_, 16, 64);                           \
    const float e2_ = __shfl_xor(val_, 32, 64);                           \
    const float e3_ = __shfl_xor(val_, 48, 64);                           \
    const float iv_ = (grp == 0) ? val_ : (grp == 1) ? e1_ : (grp == 2) ? e2_ : e3_; \
    const float fv_ = (grp == 1) ? val_ : (grp == 0) ? e1_ : (grp == 3) ? e2_ : e3_; \
    const float gv_ = (grp == 2) ? val_ : (grp == 3) ? e1_ : (grp == 0) ? e2_ : e3_; \
    const float ov_ = (grp == 3) ? val_ : (grp == 2) ? e1_ : (grp == 1) ? e2_ : e3_; \
    c = fmaf(fv_, c, iv_ * gv_);                                          \
    h = ov_ * tanh_fast(c);                                               \
    if (lane < 16) { GST(op + lane, h) }                                  \
    op += ostep;                                                          \
  }
#define GROUP1F(NW, G) {                                                  \
    const int mq_ = dir ? (NC - 1 - (G)) : (G);                           \
    const float* sb_ = xr + (mq_ & 3) * 256;                              \
    WAITV(NW);                                                            \
    { const int mp_ = dir ? (mq_ - 3) : (mq_ + 3);                        \
      const int sl_ = mp_ & 3;                                            \
      const int mpc_ = mp_ < 0 ? 0 : (mp_ >= NC ? NC - 1 : mp_);          \
      DMA16(xb + (size_t)mpc_ * 256 + lane * 4, xr + sl_ * 256) }         \
    STEP1F(sb_ + (dir ? 3 : 0) * 64)                                      \
    STEP1F(sb_ + (dir ? 2 : 1) * 64)                                      \
    STEP1F(sb_ + (dir ? 1 : 2) * 64)                                      \
    STEP1F(sb_ + (dir ? 0 : 3) * 64)                                      \
  }
  GROUP1F(2, 0)
  GROUP1F(6, 1)
  GROUP1F(10, 2)
#pragma unroll 1
  for (int g = 3; g < NC; ++g) {
    GROUP1F(14, g)
  }
#undef GROUP1F
#undef STEP1F
}

__global__ __launch_bounds__(64, 1) void l2_scan_fb(
    const float* __restrict__ in,
    const float* __restrict__ wih_f, const float* __restrict__ whh_f,
    const float* __restrict__ bih_f, const float* __restrict__ bhh_f,
    const float* __restrict__ wih_b, const float* __restrict__ whh_b,
    const float* __restrict__ bih_b, const float* __restrict__ bhh_b,
    float* __restrict__ out) {
  constexpr int NC = Tn / 8;
  const int lane = threadIdx.x;
  const int j    = lane & 31;
  const int dir  = blockIdx.x & 1;
  const int b    = blockIdx.x >> 1;
  __shared__ float xr[4 * 256];
  const float* ib = in + (size_t)b * (Tn * 32);
  {
    const int m0 = dir ? NC - 1 : 0;
    const int md = dir ? -1 : 1;
#pragma unroll
    for (int q = 0; q < 3; ++q) {
      const int mc = m0 + q * md;
      DMA16(ib + (size_t)mc * 256 + lane * 4, xr + (mc & 3) * 256)
    }
  }
  const float* wih = dir ? wih_b : wih_f;
  const float* whh = dir ? whh_b : whh_f;
  float bias = (dir ? bih_b : bih_f)[j] + (dir ? bhh_b : bhh_f)[j];
  const int k = j & 7, grp = j >> 3;
  const float gin  = (grp == 2) ? 2.0f : 1.0f;
  const float gout = (grp == 2) ? 2.0f : 1.0f;
  const float gsub = (grp == 2) ? -1.0f : 0.0f;
  const float4* wr = reinterpret_cast<const float4*>(wih + j * 32);
  float4 w0 = wr[0], w1 = wr[1], w2 = wr[2], w3 = wr[3],
         w4 = wr[4], w5 = wr[5], w6 = wr[6], w7 = wr[7];
  const float* whr = whh + j * 8;
  float u0 = whr[k], u1 = whr[(k - 1) & 7], u2 = whr[(k - 2) & 7],
        u3 = whr[(k - 3) & 7], u4 = whr[(k - 4) & 7],
        u5 = whr[(k - 5) & 7], u6 = whr[(k - 6) & 7],
        u7 = whr[(k - 7) & 7];
  const int ostep = dir ? -16 : 16;
  float* op = out + (size_t)b * (Tn * 16) + dir * 8 +
              (dir ? (size_t)(Tn - 1) * 16 : 0);
  float h = 0.0f, c = 0.0f;
#define STEP2F(XROW) {                                                    \
    const float4* xq_ = reinterpret_cast<const float4*>(XROW);            \
    float a0 = bias, a1 = 0.f, a2 = 0.f, a3 = 0.f;                        \
    FMAQ(a0, 0) FMAQ(a1, 1) FMAQ(a2, 2) FMAQ(a3, 3)                      \
    FMAQ(a0, 4) FMAQ(a1, 5) FMAQ(a2, 6) FMAQ(a3, 7)                      \
    const float gx_ = (a0 + a1) + (a2 + a3);                              \
    float m0 = h * u0, m1 = 0.f, m2 = 0.f, m3 = 0.f;                      \
    m1 = fmaf(rotr16<1>(h), u1, m1);  m2 = fmaf(rotr16<2>(h), u2, m2);    \
    m3 = fmaf(rotr16<3>(h), u3, m3);  m0 = fmaf(rotr16<4>(h), u4, m0);    \
    m1 = fmaf(rotr16<5>(h), u5, m1);  m2 = fmaf(rotr16<6>(h), u6, m2);    \
    m3 = fmaf(rotr16<7>(h), u7, m3);                                      \
    const float g_ = ((m0 + m1) + (m2 + m3)) + gx_;                       \
    const float sg_  = fast_rcp(1.0f + __expf(-gin * g_));                \
    const float val_ = fmaf(gout, sg_, gsub);                             \
    const float e1_ = __shfl_xor(val_, 8, 64);                            \
    const float e2_ = __shfl_xor(val_, 16, 64);                           \
    const float e3_ = __shfl_xor(val_, 24, 64);                           \
    const float iv_ = (grp == 0) ? val_ : (grp == 1) ? e1_ : (grp == 2) ? e2_ : e3_; \
    const float fv_ = (grp == 1) ? val_ : (grp == 0) ? e1_ : (grp == 3) ? e2_ : e3_; \
    const float gv_ = (grp == 2) ? val_ : (grp == 3) ? e1_ : (grp == 0) ? e2_ : e3_; \
    const float ov_ = (grp == 3) ? val_ : (grp == 2) ? e1_ : (grp == 1) ? e2_ : e3_; \
    c = fmaf(fv_, c, iv_ * gv_);                                          \
    h = ov_ * tanh_fast(c);                                               \
    if (lane < 8) { GST(op + lane, h) }                                   \
    op += ostep;                                                          \
  }
#define GROUP2F(NW, G) {                                                  \
    const int mq_ = dir ? (NC - 1 - (G)) : (G);                           \
    const float* sb_ = xr + (mq_ & 3) * 256;                              \
    WAITV(NW);                                                            \
    { const int mp_ = dir ? (mq_ - 3) : (mq_ + 3);                        \
      const int sl_ = mp_ & 3;                                            \
      const int mpc_ = mp_ < 0 ? 0 : (mp_ >= NC ? NC - 1 : mp_);          \
      DMA16(ib + (size_t)mpc_ * 256 + lane * 4, xr + sl_ * 256) }         \
    STEP2F(sb_ + (dir ? 7 : 0) * 32)                                      \
    STEP2F(sb_ + (dir ? 6 : 1) * 32)                                      \
    STEP2F(sb_ + (dir ? 5 : 2) * 32)                                      \
    STEP2F(sb_ + (dir ? 4 : 3) * 32)                                      \
    STEP2F(sb_ + (dir ? 3 : 4) * 32)                                      \
    STEP2F(sb_ + (dir ? 2 : 5) * 32)                                      \
    STEP2F(sb_ + (dir ? 1 : 6) * 32)                                      \
    STEP2F(sb_ + (dir ? 0 : 7) * 32)                                      \
  }
  GROUP2F(2, 0)
  GROUP2F(10, 1)
  GROUP2F(18, 2)
#pragma unroll 1
  for (int g = 3; g < NC; ++g) {
    GROUP2F(26, g)
  }
#undef GROUP2F
#undef STEP2F
}

extern "C" void kernel_launch(void* const* d_in, const int* in_sizes, int n_in,
                              void* d_out, int out_size, void* d_ws, size_t ws_size,
                              hipStream_t stream) {
  const float* x     = (const float*)d_in[0];
  const float* wih1f = (const float*)d_in[1];
  const float* whh1f = (const float*)d_in[2];
  const float* bih1f = (const float*)d_in[3];
  const float* bhh1f = (const float*)d_in[4];
  const float* wih1b = (const float*)d_in[5];
  const float* whh1b = (const float*)d_in[6];
  const float* bih1b = (const float*)d_in[7];
  const float* bhh1b = (const float*)d_in[8];
  const float* wih2f = (const float*)d_in[9];
  const float* whh2f = (const float*)d_in[10];
  const float* bih2f = (const float*)d_in[11];
  const float* bhh2f = (const float*)d_in[12];
  const float* wih2b = (const float*)d_in[13];
  const float* whh2b = (const float*)d_in[14];
  const float* bih2b = (const float*)d_in[15];
  const float* bhh2b = (const float*)d_in[16];

  float* out1 = (float*)d_ws;                       // [B][T][32] = 67.1 MB
  float* outp = (float*)d_out;                      // [B][T][16]

  const size_t out1F = (size_t)Bn * Tn * 32;
  const size_t gx1F  = (size_t)Bn * 2 * Tn * 64;    // 268.4 MB
  const size_t needB = (out1F + gx1F) * sizeof(float);

  if (ws_size >= needB) {
    float* gx1 = (float*)d_ws + out1F;              // [2B][T][64]
    float* gx2 = gx1;                               // aliases gx1 (dead after scan1)
    gemm_gx1<<<Bn * 2 * 16, 64, 0, stream>>>(
        x, wih1f, bih1f, bhh1f, wih1b, bih1b, bhh1b, gx1);
    l1_scan_gx<<<Bn * 2, 64, 0, stream>>>(gx1, whh1f, whh1b, out1);
    gemm_gx2<<<Bn * 16, 64, 0, stream>>>(
        out1, wih2f, bih2f, bhh2f, wih2b, bih2b, bhh2b, gx2);
    l2_scan_gx<<<Bn * 2, 64, 0, stream>>>(gx2, whh2f, whh2b, outp);
  } else {
    l1_scan_fb<<<Bn * 2, 64, 0, stream>>>(x, wih1f, whh1f, bih1f, bhh1f,
                                          wih1b, whh1b, bih1b, bhh1b, out1);
    l2_scan_fb<<<Bn * 2, 64, 0, stream>>>(out1, wih2f, whh2f, bih2f, bhh2f,
                                          wih2b, whh2b, bih2b, bhh2b, outp);
  }
}

// Round 15
// 920.233 us; speedup vs baseline: 2.1448x; 1.3373x over previous
//
#include <hip/hip_runtime.h>

// 2-layer bidirectional LSTM, B=256 T=2048 D=64, H1=16/dir, H2=8/dir.
// R15 = R14 (PASS, 1231us) with the gx GEMMs rebuilt on the scan-proven
// DMA16-ring skeleton. R14 profile: gemm_gx1 = 494us @ 1.3TB/s, VALUBusy
// 38% -- per-iteration wave-uniform x loads (scalarized s_load, ~200cy)
// serialize with the FMAs. Fix: 4-slot LDS ring prefetched 3 groups ahead
// (fire-and-forget DMA, counted vmcnt identical to the scans: 1 DMA + 4/8
// stores per group -> waits 2/6/10,14 and 2/10/18,26), x rows consumed as
// LDS broadcasts. TILES 16->32, launch_bounds(64,2) for weight residency.
// Scans (R14: prescaled gx, tree-end GX join, batched stores) + fallbacks
// unchanged.

#ifndef __has_builtin
#define __has_builtin(x) 0
#endif

constexpr int Bn = 256;
constexpr int Tn = 2048;

typedef unsigned int uint2v __attribute__((ext_vector_type(2)));

__device__ __forceinline__ float fast_rcp(float x) { return __builtin_amdgcn_rcpf(x); }
__device__ __forceinline__ float tanh_fast(float x) {
  return fmaf(2.0f, fast_rcp(1.0f + __expf(-2.0f * x)), -1.0f);
}

// DPP rotate-right by R within each 16-lane row: dst[l] = src[(l-R)&15].
template <int R>
__device__ __forceinline__ float rotr16(float v) {
  return __int_as_float(__builtin_amdgcn_mov_dpp(
      __float_as_int(v), 0x120 | R, 0xF, 0xF, true));
}

// val[l^16] / val[l^32], polarity-proof XOR-combine (R13-proven).
__device__ __forceinline__ float xor16_lane(float v) {
#if __has_builtin(__builtin_amdgcn_permlane16_swap)
  const unsigned u = __float_as_uint(v);
  uint2v r = __builtin_amdgcn_permlane16_swap(u, u, false, false);
  return __uint_as_float(r[0] ^ r[1] ^ u);
#else
  return __shfl_xor(v, 16, 64);
#endif
}
__device__ __forceinline__ float xor32_lane(float v) {
#if __has_builtin(__builtin_amdgcn_permlane32_swap)
  const unsigned u = __float_as_uint(v);
  uint2v r = __builtin_amdgcn_permlane32_swap(u, u, false, false);
  return __uint_as_float(r[0] ^ r[1] ^ u);
#else
  return __shfl_xor(v, 32, 64);
#endif
}

#define OPQ4(v) asm("" : "+v"(v.x), "+v"(v.y), "+v"(v.z), "+v"(v.w));
#define OPQ1(v) asm("" : "+v"(v));

#define GST(addr, val) \
  asm volatile("global_store_dword %0, %1, off" :: "v"(addr), "v"(val));

#define WAITV(N)                                              \
  do {                                                        \
    asm volatile("s_waitcnt vmcnt(" #N ")" ::: "memory");     \
    __builtin_amdgcn_sched_barrier(0);                        \
  } while (0)

#define DMA16(gsrc, ldst)                                         \
  __builtin_amdgcn_global_load_lds(                               \
      (const __attribute__((address_space(1))) float*)(gsrc),     \
      (__attribute__((address_space(3))) float*)(ldst), 16, 0, 0);

#define FMAU(ACC, I) { const float4 xv_ = x4[I];                    \
    ACC = fmaf(xv_.x, w##I.x, ACC); ACC = fmaf(xv_.y, w##I.y, ACC); \
    ACC = fmaf(xv_.z, w##I.z, ACC); ACC = fmaf(xv_.w, w##I.w, ACC); }

#define FMAQ(ACC, I) { float4 v_ = xq_[I];                          \
    ACC = fmaf(v_.x, w##I.x, ACC); ACC = fmaf(v_.y, w##I.y, ACC);   \
    ACC = fmaf(v_.z, w##I.z, ACC); ACC = fmaf(v_.w, w##I.w, ACC); }

// ==================== GEMM 1: gx1[bd][s][64], PRESCALED by -gin ====================
// grid = B*2*32; block = 1 wave; TT=64 rows/block; DMA ring, 16 groups of 4.
__global__ __launch_bounds__(64, 2) void gemm_gx1(
    const float* __restrict__ x,
    const float* __restrict__ wf, const float* __restrict__ bif,
    const float* __restrict__ bhf,
    const float* __restrict__ wb, const float* __restrict__ bib,
    const float* __restrict__ bhb,
    float* __restrict__ gx1) {
  constexpr int TILES = 32, TT = Tn / TILES;   // 64 rows per block
  constexpr int NG = TT / 4;                   // 16 groups of 4 rows
  const int lane = threadIdx.x;
  const int bd   = blockIdx.x / TILES;
  const int tile = blockIdx.x % TILES;
  const int dir  = bd & 1, b = bd >> 1;

  __shared__ float xr[4 * 256];                // 4-slot ring, 4KB
  const float* xb = x + ((size_t)b * Tn + tile * TT) * 64;

#pragma unroll
  for (int p = 0; p < 3; ++p)
    DMA16(xb + (size_t)p * 256 + lane * 4, xr + p * 256)

  const float* W = dir ? wb : wf;  // [64][64]
  float bias = (dir ? bib : bif)[lane] + (dir ? bhb : bhf)[lane];
  const float sc = ((lane >> 4) == 2) ? -2.0f : -1.0f;   // -gin per gate row

  const float4* wr = reinterpret_cast<const float4*>(W + lane * 64);
  float4 w0 = wr[0],  w1 = wr[1],  w2 = wr[2],  w3 = wr[3],
         w4 = wr[4],  w5 = wr[5],  w6 = wr[6],  w7 = wr[7],
         w8 = wr[8],  w9 = wr[9],  w10 = wr[10], w11 = wr[11],
         w12 = wr[12], w13 = wr[13], w14 = wr[14], w15 = wr[15];
  OPQ4(w0)  OPQ4(w1)  OPQ4(w2)  OPQ4(w3)  OPQ4(w4)  OPQ4(w5)
  OPQ4(w6)  OPQ4(w7)  OPQ4(w8)  OPQ4(w9)  OPQ4(w10) OPQ4(w11)
  OPQ4(w12) OPQ4(w13) OPQ4(w14) OPQ4(w15) OPQ1(bias)

  const int t0 = tile * TT;
  const int sstep = dir ? -1 : 1;
  float* op = gx1 + (size_t)bd * Tn * 64 +
              (size_t)(dir ? (Tn - 1 - t0) : t0) * 64 + lane;

#define ROWDOT1(RP, RES) {                                               \
    const float4* x4 = reinterpret_cast<const float4*>(RP);              \
    float a0 = bias, a1 = 0.f, a2 = 0.f, a3 = 0.f;                       \
    FMAU(a0, 0)  FMAU(a1, 1)  FMAU(a2, 2)  FMAU(a3, 3)                  \
    FMAU(a0, 4)  FMAU(a1, 5)  FMAU(a2, 6)  FMAU(a3, 7)                  \
    FMAU(a0, 8)  FMAU(a1, 9)  FMAU(a2, 10) FMAU(a3, 11)                 \
    FMAU(a0, 12) FMAU(a1, 13) FMAU(a2, 14) FMAU(a3, 15)                 \
    RES = sc * ((a0 + a1) + (a2 + a3)); }

  // Per group: [DMA, 4 GST] -> waits 2/6/10 then 14 (scan-proven counting).
#define GG1(NW, G) {                                                     \
    WAITV(NW);                                                           \
    { const int mp_ = (G) + 3;                                           \
      const int mpc_ = (mp_ < NG) ? mp_ : NG - 1;                        \
      DMA16(xb + (size_t)mpc_ * 256 + lane * 4, xr + (mp_ & 3) * 256) }  \
    const float* sb_ = xr + ((G) & 3) * 256;                             \
    float h0_, h1_, h2_, h3_;                                            \
    ROWDOT1(sb_, h0_)        ROWDOT1(sb_ + 64, h1_)                      \
    ROWDOT1(sb_ + 128, h2_)  ROWDOT1(sb_ + 192, h3_)                     \
    GST(op, h0_)                 GST(op + sstep * 64, h1_)               \
    GST(op + 2 * sstep * 64, h2_) GST(op + 3 * sstep * 64, h3_)          \
    op += 4 * sstep * 64; }

  GG1(2, 0)
  GG1(6, 1)
  GG1(10, 2)
#pragma unroll 1
  for (int g = 3; g < NG; ++g) {
    GG1(14, g)
  }
#undef GG1
#undef ROWDOT1
}

// ==================== GEMM 2: gx2[bd][s][32], PRESCALED by -gin ====================
// grid = B*32; lanes 0-31 fwd gates, 32-63 bwd gates (x row uniform).
// TT=64 rows/block; DMA ring, 8 groups of 8 rows.
__global__ __launch_bounds__(64, 2) void gemm_gx2(
    const float* __restrict__ in,   // out1 [B][T][32]
    const float* __restrict__ wf, const float* __restrict__ bif,
    const float* __restrict__ bhf,
    const float* __restrict__ wb, const float* __restrict__ bib,
    const float* __restrict__ bhb,
    float* __restrict__ gx2) {
  constexpr int TILES = 32, TT = Tn / TILES;   // 64 rows per block
  constexpr int NG = TT / 8;                   // 8 groups of 8 rows
  const int lane = threadIdx.x;
  const int g = lane & 31, half = lane >> 5;
  const int b = blockIdx.x / TILES, tile = blockIdx.x % TILES;

  __shared__ float xr[4 * 256];
  const float* ib = in + ((size_t)b * Tn + tile * TT) * 32;

#pragma unroll
  for (int p = 0; p < 3; ++p)
    DMA16(ib + (size_t)p * 256 + lane * 4, xr + p * 256)

  const float* W = half ? wb : wf;  // [32][32]
  float bias = (half ? bib : bif)[g] + (half ? bhb : bhf)[g];
  const float sc = ((g >> 3) == 2) ? -2.0f : -1.0f;

  const float4* wr = reinterpret_cast<const float4*>(W + g * 32);
  float4 w0 = wr[0], w1 = wr[1], w2 = wr[2], w3 = wr[3],
         w4 = wr[4], w5 = wr[5], w6 = wr[6], w7 = wr[7];
  OPQ4(w0) OPQ4(w1) OPQ4(w2) OPQ4(w3) OPQ4(w4) OPQ4(w5) OPQ4(w6) OPQ4(w7)
  OPQ1(bias)

  const int t0 = tile * TT;
  const int slstep = half ? -1 : 1;
  float* op = gx2 + ((size_t)(b * 2 + half) * Tn +
              (half ? (Tn - 1 - t0) : t0)) * 32 + g;

#define ROWDOT2(RP, RES) {                                               \
    const float4* x4 = reinterpret_cast<const float4*>(RP);              \
    float a0 = bias, a1 = 0.f, a2 = 0.f, a3 = 0.f;                       \
    FMAU(a0, 0) FMAU(a1, 1) FMAU(a2, 2) FMAU(a3, 3)                     \
    FMAU(a0, 4) FMAU(a1, 5) FMAU(a2, 6) FMAU(a3, 7)                     \
    RES = sc * ((a0 + a1) + (a2 + a3)); }

  // Per group: [DMA, 8 GST] -> waits 2/10/18 then 26.
#define GG2(NW, G) {                                                     \
    WAITV(NW);                                                           \
    { const int mp_ = (G) + 3;                                           \
      const int mpc_ = (mp_ < NG) ? mp_ : NG - 1;                        \
      DMA16(ib + (size_t)mpc_ * 256 + lane * 4, xr + (mp_ & 3) * 256) }  \
    const float* sb_ = xr + ((G) & 3) * 256;                             \
    float h0_, h1_, h2_, h3_, h4_, h5_, h6_, h7_;                        \
    ROWDOT2(sb_, h0_)        ROWDOT2(sb_ + 32, h1_)                      \
    ROWDOT2(sb_ + 64, h2_)   ROWDOT2(sb_ + 96, h3_)                      \
    ROWDOT2(sb_ + 128, h4_)  ROWDOT2(sb_ + 160, h5_)                     \
    ROWDOT2(sb_ + 192, h6_)  ROWDOT2(sb_ + 224, h7_)                     \
    GST(op, h0_)                  GST(op + slstep * 32, h1_)             \
    GST(op + 2 * slstep * 32, h2_) GST(op + 3 * slstep * 32, h3_)        \
    GST(op + 4 * slstep * 32, h4_) GST(op + 5 * slstep * 32, h5_)        \
    GST(op + 6 * slstep * 32, h6_) GST(op + 7 * slstep * 32, h7_)        \
    op += 8 * slstep * 32; }

  GG2(2, 0)
  GG2(10, 1)
  GG2(18, 2)
#pragma unroll 1
  for (int gg = 3; gg < NG; ++gg) {
    GG2(26, gg)
  }
#undef GG2
#undef ROWDOT2
}

// ==================== Scan 1 (gx-fed, prescaled): H=16 ====================
__global__ __launch_bounds__(64, 1) void l1_scan_gx(
    const float* __restrict__ gx1,
    const float* __restrict__ whh_f, const float* __restrict__ whh_b,
    float* __restrict__ out1) {
  constexpr int NC = Tn / 4;
  const int lane = threadIdx.x;
  const int dir  = blockIdx.x & 1;
  const int b    = blockIdx.x >> 1;

  __shared__ float xr[4 * 256];
  const float* gxb = gx1 + (size_t)blockIdx.x * Tn * 64;

#pragma unroll
  for (int p = 0; p < 3; ++p)
    DMA16(gxb + (size_t)p * 256 + lane * 4, xr + p * 256)

  const float* whh = dir ? whh_b : whh_f;  // [64][16]
  const int k = lane & 15, grp = lane >> 4;
  const float sc = (grp == 2) ? -2.0f : -1.0f;   // -gin (matches gemm prescale)
  const float* whr = whh + lane * 16;
  float u0 = sc * whr[k], u1 = sc * whr[(k - 1) & 15],
        u2 = sc * whr[(k - 2) & 15], u3 = sc * whr[(k - 3) & 15],
        u4 = sc * whr[(k - 4) & 15], u5 = sc * whr[(k - 5) & 15],
        u6 = sc * whr[(k - 6) & 15], u7 = sc * whr[(k - 7) & 15],
        u8 = sc * whr[(k - 8) & 15], u9 = sc * whr[(k - 9) & 15],
        u10 = sc * whr[(k - 10) & 15], u11 = sc * whr[(k - 11) & 15],
        u12 = sc * whr[(k - 12) & 15], u13 = sc * whr[(k - 13) & 15],
        u14 = sc * whr[(k - 14) & 15], u15 = sc * whr[(k - 15) & 15];
  OPQ1(u0)  OPQ1(u1)  OPQ1(u2)  OPQ1(u3)  OPQ1(u4)  OPQ1(u5)
  OPQ1(u6)  OPQ1(u7)  OPQ1(u8)  OPQ1(u9)  OPQ1(u10) OPQ1(u11)
  OPQ1(u12) OPQ1(u13) OPQ1(u14) OPQ1(u15)

  const float gout = (grp == 2) ? 2.0f : 1.0f;
  const float gsub = (grp == 2) ? -1.0f : 0.0f;

  const int ostep = dir ? -32 : 32;
  float* op = out1 + (size_t)b * Tn * 32 + dir * 16 +
              (dir ? (size_t)(Tn - 1) * 32 : 0);

  float h = 0.0f, c = 0.0f;

#define STEP1(GX, HS) {                                                   \
    float m0 = h * u0, m1 = 0.f, m2 = 0.f, m3 = 0.f;                      \
    m1 = fmaf(rotr16<1>(h),  u1,  m1);  m2 = fmaf(rotr16<2>(h),  u2,  m2); \
    m3 = fmaf(rotr16<3>(h),  u3,  m3);  m0 = fmaf(rotr16<4>(h),  u4,  m0); \
    m1 = fmaf(rotr16<5>(h),  u5,  m1);  m2 = fmaf(rotr16<6>(h),  u6,  m2); \
    m3 = fmaf(rotr16<7>(h),  u7,  m3);  m0 = fmaf(rotr16<8>(h),  u8,  m0); \
    m1 = fmaf(rotr16<9>(h),  u9,  m1);  m2 = fmaf(rotr16<10>(h), u10, m2); \
    m3 = fmaf(rotr16<11>(h), u11, m3);  m0 = fmaf(rotr16<12>(h), u12, m0); \
    m1 = fmaf(rotr16<13>(h), u13, m1);  m2 = fmaf(rotr16<14>(h), u14, m2); \
    m3 = fmaf(rotr16<15>(h), u15, m3);                                    \
    const float g_ = ((m0 + m1) + (m2 + m3)) + (GX);                      \
    const float sg_  = fast_rcp(1.0f + __expf(g_));                       \
    const float val_ = fmaf(gout, sg_, gsub);                             \
    const float e1_ = xor16_lane(val_);                                   \
    const float e2_ = xor32_lane(val_);                                   \
    const float e3_ = xor16_lane(e2_);                                    \
    const float iv_ = (grp == 0) ? val_ : (grp == 1) ? e1_ : (grp == 2) ? e2_ : e3_; \
    const float fv_ = (grp == 1) ? val_ : (grp == 0) ? e1_ : (grp == 3) ? e2_ : e3_; \
    const float gv_ = (grp == 2) ? val_ : (grp == 3) ? e1_ : (grp == 0) ? e2_ : e3_; \
    const float ov_ = (grp == 3) ? val_ : (grp == 2) ? e1_ : (grp == 1) ? e2_ : e3_; \
    c = fmaf(fv_, c, iv_ * gv_);                                          \
    h = ov_ * tanh_fast(c);                                               \
    HS = h;                                                               \
  }

#define GROUP1(NW, G) {                                                   \
    WAITV(NW);                                                            \
    const float* sb_ = xr + ((G) & 3) * 256;                              \
    const float q0_ = sb_[lane];                                          \
    const float q1_ = sb_[64 + lane];                                     \
    const float q2_ = sb_[128 + lane];                                    \
    const float q3_ = sb_[192 + lane];                                    \
    { const int mp_ = (G) + 3;                                            \
      const int mpc_ = (mp_ < NC) ? mp_ : NC - 1;                         \
      DMA16(gxb + (size_t)mpc_ * 256 + lane * 4, xr + (mp_ & 3) * 256) }  \
    float h0_, h1_, h2_, h3_;                                             \
    STEP1(q0_, h0_) STEP1(q1_, h1_) STEP1(q2_, h2_) STEP1(q3_, h3_)       \
    if (lane < 16) {                                                      \
      GST(op + lane, h0_)                                                 \
      GST(op + ostep + lane, h1_)                                         \
      GST(op + 2 * ostep + lane, h2_)                                     \
      GST(op + 3 * ostep + lane, h3_)                                     \
    }                                                                     \
    op += 4 * ostep;                                                      \
  }

  GROUP1(2, 0)
  GROUP1(6, 1)
  GROUP1(10, 2)
#pragma unroll 1
  for (int g = 3; g < NC; ++g) {
    GROUP1(14, g)
  }
#undef GROUP1
#undef STEP1
}

// ==================== Scan 2 (gx-fed, prescaled): H=8 ====================
__global__ __launch_bounds__(64, 1) void l2_scan_gx(
    const float* __restrict__ gx2,
    const float* __restrict__ whh_f, const float* __restrict__ whh_b,
    float* __restrict__ out) {
  constexpr int NC = Tn / 8;
  const int lane = threadIdx.x;
  const int j    = lane & 31;
  const int dir  = blockIdx.x & 1;
  const int b    = blockIdx.x >> 1;

  __shared__ float xr[4 * 256];
  const float* gxb = gx2 + (size_t)blockIdx.x * Tn * 32;

#pragma unroll
  for (int p = 0; p < 3; ++p)
    DMA16(gxb + (size_t)p * 256 + lane * 4, xr + p * 256)

  const float* whh = dir ? whh_b : whh_f;  // [32][8]
  const int k = j & 7, grp = j >> 3;
  const float sc = (grp == 2) ? -2.0f : -1.0f;
  const float* whr = whh + j * 8;
  float u0 = sc * whr[k], u1 = sc * whr[(k - 1) & 7],
        u2 = sc * whr[(k - 2) & 7], u3 = sc * whr[(k - 3) & 7],
        u4 = sc * whr[(k - 4) & 7], u5 = sc * whr[(k - 5) & 7],
        u6 = sc * whr[(k - 6) & 7], u7 = sc * whr[(k - 7) & 7];
  OPQ1(u0) OPQ1(u1) OPQ1(u2) OPQ1(u3) OPQ1(u4) OPQ1(u5) OPQ1(u6) OPQ1(u7)

  const float gout = (grp == 2) ? 2.0f : 1.0f;
  const float gsub = (grp == 2) ? -1.0f : 0.0f;

  const int ostep = dir ? -16 : 16;
  float* op = out + (size_t)b * Tn * 16 + dir * 8 +
              (dir ? (size_t)(Tn - 1) * 16 : 0);

  float h = 0.0f, c = 0.0f;

#define STEP2(GX, HS) {                                                   \
    float m0 = h * u0, m1 = 0.f, m2 = 0.f, m3 = 0.f;                      \
    m1 = fmaf(rotr16<1>(h), u1, m1);  m2 = fmaf(rotr16<2>(h), u2, m2);    \
    m3 = fmaf(rotr16<3>(h), u3, m3);  m0 = fmaf(rotr16<4>(h), u4, m0);    \
    m1 = fmaf(rotr16<5>(h), u5, m1);  m2 = fmaf(rotr16<6>(h), u6, m2);    \
    m3 = fmaf(rotr16<7>(h), u7, m3);                                      \
    const float g_ = ((m0 + m1) + (m2 + m3)) + (GX);                      \
    const float sg_  = fast_rcp(1.0f + __expf(g_));                       \
    const float val_ = fmaf(gout, sg_, gsub);                             \
    const float e1_ = rotr16<8>(val_);       /* val[l^8] */               \
    const float e2_ = xor16_lane(val_);      /* val[l^16] */              \
    const float e3_ = rotr16<8>(e2_);        /* val[l^24] */              \
    const float iv_ = (grp == 0) ? val_ : (grp == 1) ? e1_ : (grp == 2) ? e2_ : e3_; \
    const float fv_ = (grp == 1) ? val_ : (grp == 0) ? e1_ : (grp == 3) ? e2_ : e3_; \
    const float gv_ = (grp == 2) ? val_ : (grp == 3) ? e1_ : (grp == 0) ? e2_ : e3_; \
    const float ov_ = (grp == 3) ? val_ : (grp == 2) ? e1_ : (grp == 1) ? e2_ : e3_; \
    c = fmaf(fv_, c, iv_ * gv_);                                          \
    h = ov_ * tanh_fast(c);                                               \
    HS = h;                                                               \
  }

#define GROUP2(NW, G) {                                                   \
    WAITV(NW);                                                            \
    const float* sb_ = xr + ((G) & 3) * 256;                              \
    const float q0_ = sb_[j];            const float q1_ = sb_[32 + j];   \
    const float q2_ = sb_[64 + j];       const float q3_ = sb_[96 + j];   \
    const float q4_ = sb_[128 + j];      const float q5_ = sb_[160 + j];  \
    const float q6_ = sb_[192 + j];      const float q7_ = sb_[224 + j];  \
    { const int mp_ = (G) + 3;                                            \
      const int mpc_ = (mp_ < NC) ? mp_ : NC - 1;                         \
      DMA16(gxb + (size_t)mpc_ * 256 + lane * 4, xr + (mp_ & 3) * 256) }  \
    float h0_, h1_, h2_, h3_, h4_, h5_, h6_, h7_;                         \
    STEP2(q0_, h0_) STEP2(q1_, h1_) STEP2(q2_, h2_) STEP2(q3_, h3_)       \
    STEP2(q4_, h4_) STEP2(q5_, h5_) STEP2(q6_, h6_) STEP2(q7_, h7_)       \
    if (lane < 8) {                                                       \
      GST(op + lane, h0_)                                                 \
      GST(op + ostep + lane, h1_)                                         \
      GST(op + 2 * ostep + lane, h2_)                                     \
      GST(op + 3 * ostep + lane, h3_)                                     \
      GST(op + 4 * ostep + lane, h4_)                                     \
      GST(op + 5 * ostep + lane, h5_)                                     \
      GST(op + 6 * ostep + lane, h6_)                                     \
      GST(op + 7 * ostep + lane, h7_)                                     \
    }                                                                     \
    op += 8 * ostep;                                                      \
  }

  GROUP2(2, 0)
  GROUP2(10, 1)
  GROUP2(18, 2)
#pragma unroll 1
  for (int g = 3; g < NC; ++g) {
    GROUP2(26, g)
  }
#undef GROUP2
#undef STEP2
}

// ==================== Fallback (R10, proven): weights in scan ====================
__global__ __launch_bounds__(64, 1) void l1_scan_fb(
    const float* __restrict__ x,
    const float* __restrict__ wih_f, const float* __restrict__ whh_f,
    const float* __restrict__ bih_f, const float* __restrict__ bhh_f,
    const float* __restrict__ wih_b, const float* __restrict__ whh_b,
    const float* __restrict__ bih_b, const float* __restrict__ bhh_b,
    float* __restrict__ out1) {
  constexpr int NC = Tn / 4;
  const int lane = threadIdx.x;
  const int dir  = blockIdx.x & 1;
  const int b    = blockIdx.x >> 1;
  __shared__ float xr[4 * 256];
  const float* xb = x + (size_t)b * (Tn * 64);
  {
    const int m0 = dir ? NC - 1 : 0;
    const int md = dir ? -1 : 1;
#pragma unroll
    for (int q = 0; q < 3; ++q) {
      const int mc = m0 + q * md;
      DMA16(xb + (size_t)mc * 256 + lane * 4, xr + (mc & 3) * 256)
    }
  }
  const float* wih = dir ? wih_b : wih_f;
  const float* whh = dir ? whh_b : whh_f;
  float bias = (dir ? bih_b : bih_f)[lane] + (dir ? bhh_b : bhh_f)[lane];
  const int k = lane & 15, grp = lane >> 4;
  const float gin  = (grp == 2) ? 2.0f : 1.0f;
  const float gout = (grp == 2) ? 2.0f : 1.0f;
  const float gsub = (grp == 2) ? -1.0f : 0.0f;
  const float4* wr = reinterpret_cast<const float4*>(wih + lane * 64);
  float4 w0 = wr[0],  w1 = wr[1],  w2 = wr[2],  w3 = wr[3],
         w4 = wr[4],  w5 = wr[5],  w6 = wr[6],  w7 = wr[7],
         w8 = wr[8],  w9 = wr[9],  w10 = wr[10], w11 = wr[11],
         w12 = wr[12], w13 = wr[13], w14 = wr[14], w15 = wr[15];
  const float* whr = whh + lane * 16;
  float u0 = whr[k], u1 = whr[(k - 1) & 15], u2 = whr[(k - 2) & 15],
        u3 = whr[(k - 3) & 15], u4 = whr[(k - 4) & 15],
        u5 = whr[(k - 5) & 15], u6 = whr[(k - 6) & 15],
        u7 = whr[(k - 7) & 15], u8 = whr[(k - 8) & 15],
        u9 = whr[(k - 9) & 15], u10 = whr[(k - 10) & 15],
        u11 = whr[(k - 11) & 15], u12 = whr[(k - 12) & 15],
        u13 = whr[(k - 13) & 15], u14 = whr[(k - 14) & 15],
        u15 = whr[(k - 15) & 15];
  const int ostep = dir ? -32 : 32;
  float* op = out1 + (size_t)b * (Tn * 32) + dir * 16 +
              (dir ? (size_t)(Tn - 1) * 32 : 0);
  float h = 0.0f, c = 0.0f;
#define STEP1F(XROW) {                                                    \
    const float4* xq_ = reinterpret_cast<const float4*>(XROW);            \
    float a0 = bias, a1 = 0.f, a2 = 0.f, a3 = 0.f;                        \
    FMAQ(a0, 0)  FMAQ(a1, 1)  FMAQ(a2, 2)  FMAQ(a3, 3)                   \
    FMAQ(a0, 4)  FMAQ(a1, 5)  FMAQ(a2, 6)  FMAQ(a3, 7)                   \
    FMAQ(a0, 8)  FMAQ(a1, 9)  FMAQ(a2, 10) FMAQ(a3, 11)                  \
    FMAQ(a0, 12) FMAQ(a1, 13) FMAQ(a2, 14) FMAQ(a3, 15)                  \
    const float gx_ = (a0 + a1) + (a2 + a3);                              \
    float m0 = h * u0, m1 = 0.f, m2 = 0.f, m3 = 0.f;                      \
    m1 = fmaf(rotr16<1>(h),  u1,  m1);  m2 = fmaf(rotr16<2>(h),  u2,  m2); \
    m3 = fmaf(rotr16<3>(h),  u3,  m3);  m0 = fmaf(rotr16<4>(h),  u4,  m0); \
    m1 = fmaf(rotr16<5>(h),  u5,  m1);  m2 = fmaf(rotr16<6>(h),  u6,  m2); \
    m3 = fmaf(rotr16<7>(h),  u7,  m3);  m0 = fmaf(rotr16<8>(h),  u8,  m0); \
    m1 = fmaf(rotr16<9>(h),  u9,  m1);  m2 = fmaf(rotr16<10>(h), u10, m2); \
    m3 = fmaf(rotr16<11>(h), u11, m3);  m0 = fmaf(rotr16<12>(h), u12, m0); \
    m1 = fmaf(rotr16<13>(h), u13, m1);  m2 = fmaf(rotr16<14>(h), u14, m2); \
    m3 = fmaf(rotr16<15>(h), u15, m3);                                    \
    const float g_ = ((m0 + m1) + (m2 + m3)) + gx_;                       \
    const float sg_  = fast_rcp(1.0f + __expf(-gin * g_));                \
    const float val_ = fmaf(gout, sg_, gsub);                             \
    const float e1_ = __shfl_xor(val_, 16, 64);                           \
    const float e2_ = __shfl_xor(val_, 32, 64);                           \
    const float e3_ = __shfl_xor(val_, 48, 64);                           \
    const float iv_ = (grp == 0) ? val_ : (grp == 1) ? e1_ : (grp == 2) ? e2_ : e3_; \
    const float fv_ = (grp == 1) ? val_ : (grp == 0) ? e1_ : (grp == 3) ? e2_ : e3_; \
    const float gv_ = (grp == 2) ? val_ : (grp == 3) ? e1_ : (grp == 0) ? e2_ : e3_; \
    const float ov_ = (grp == 3) ? val_ : (grp == 2) ? e1_ : (grp == 1) ? e2_ : e3_; \
    c = fmaf(fv_, c, iv_ * gv_);                                          \
    h = ov_ * tanh_fast(c);                                               \
    if (lane < 16) { GST(op + lane, h) }                                  \
    op += ostep;                                                          \
  }
#define GROUP1F(NW, G) {                                                  \
    const int mq_ = dir ? (NC - 1 - (G)) : (G);                           \
    const float* sb_ = xr + (mq_ & 3) * 256;                              \
    WAITV(NW);                                                            \
    { const int mp_ = dir ? (mq_ - 3) : (mq_ + 3);                        \
      const int sl_ = mp_ & 3;                                            \
      const int mpc_ = mp_ < 0 ? 0 : (mp_ >= NC ? NC - 1 : mp_);          \
      DMA16(xb + (size_t)mpc_ * 256 + lane * 4, xr + sl_ * 256) }         \
    STEP1F(sb_ + (dir ? 3 : 0) * 64)                                      \
    STEP1F(sb_ + (dir ? 2 : 1) * 64)                                      \
    STEP1F(sb_ + (dir ? 1 : 2) * 64)                                      \
    STEP1F(sb_ + (dir ? 0 : 3) * 64)                                      \
  }
  GROUP1F(2, 0)
  GROUP1F(6, 1)
  GROUP1F(10, 2)
#pragma unroll 1
  for (int g = 3; g < NC; ++g) {
    GROUP1F(14, g)
  }
#undef GROUP1F
#undef STEP1F
}

__global__ __launch_bounds__(64, 1) void l2_scan_fb(
    const float* __restrict__ in,
    const float* __restrict__ wih_f, const float* __restrict__ whh_f,
    const float* __restrict__ bih_f, const float* __restrict__ bhh_f,
    const float* __restrict__ wih_b, const float* __restrict__ whh_b,
    const float* __restrict__ bih_b, const float* __restrict__ bhh_b,
    float* __restrict__ out) {
  constexpr int NC = Tn / 8;
  const int lane = threadIdx.x;
  const int j    = lane & 31;
  const int dir  = blockIdx.x & 1;
  const int b    = blockIdx.x >> 1;
  __shared__ float xr[4 * 256];
  const float* ib = in + (size_t)b * (Tn * 32);
  {
    const int m0 = dir ? NC - 1 : 0;
    const int md = dir ? -1 : 1;
#pragma unroll
    for (int q = 0; q < 3; ++q) {
      const int mc = m0 + q * md;
      DMA16(ib + (size_t)mc * 256 + lane * 4, xr + (mc & 3) * 256)
    }
  }
  const float* wih = dir ? wih_b : wih_f;
  const float* whh = dir ? whh_b : whh_f;
  float bias = (dir ? bih_b : bih_f)[j] + (dir ? bhh_b : bhh_f)[j];
  const int k = j & 7, grp = j >> 3;
  const float gin  = (grp == 2) ? 2.0f : 1.0f;
  const float gout = (grp == 2) ? 2.0f : 1.0f;
  const float gsub = (grp == 2) ? -1.0f : 0.0f;
  const float4* wr = reinterpret_cast<const float4*>(wih + j * 32);
  float4 w0 = wr[0], w1 = wr[1], w2 = wr[2], w3 = wr[3],
         w4 = wr[4], w5 = wr[5], w6 = wr[6], w7 = wr[7];
  const float* whr = whh + j * 8;
  float u0 = whr[k], u1 = whr[(k - 1) & 7], u2 = whr[(k - 2) & 7],
        u3 = whr[(k - 3) & 7], u4 = whr[(k - 4) & 7],
        u5 = whr[(k - 5) & 7], u6 = whr[(k - 6) & 7],
        u7 = whr[(k - 7) & 7];
  const int ostep = dir ? -16 : 16;
  float* op = out + (size_t)b * (Tn * 16) + dir * 8 +
              (dir ? (size_t)(Tn - 1) * 16 : 0);
  float h = 0.0f, c = 0.0f;
#define STEP2F(XROW) {                                                    \
    const float4* xq_ = reinterpret_cast<const float4*>(XROW);            \
    float a0 = bias, a1 = 0.f, a2 = 0.f, a3 = 0.f;                        \
    FMAQ(a0, 0) FMAQ(a1, 1) FMAQ(a2, 2) FMAQ(a3, 3)                      \
    FMAQ(a0, 4) FMAQ(a1, 5) FMAQ(a2, 6) FMAQ(a3, 7)                      \
    const float gx_ = (a0 + a1) + (a2 + a3);                              \
    float m0 = h * u0, m1 = 0.f, m2 = 0.f, m3 = 0.f;                      \
    m1 = fmaf(rotr16<1>(h), u1, m1);  m2 = fmaf(rotr16<2>(h), u2, m2);    \
    m3 = fmaf(rotr16<3>(h), u3, m3);  m0 = fmaf(rotr16<4>(h), u4, m0);    \
    m1 = fmaf(rotr16<5>(h), u5, m1);  m2 = fmaf(rotr16<6>(h), u6, m2);    \
    m3 = fmaf(rotr16<7>(h), u7, m3);                                      \
    const float g_ = ((m0 + m1) + (m2 + m3)) + gx_;                       \
    const float sg_  = fast_rcp(1.0f + __expf(-gin * g_));                \
    const float val_ = fmaf(gout, sg_, gsub);                             \
    const float e1_ = __shfl_xor(val_, 8, 64);                            \
    const float e2_ = __shfl_xor(val_, 16, 64);                           \
    const float e3_ = __shfl_xor(val_, 24, 64);                           \
    const float iv_ = (grp == 0) ? val_ : (grp == 1) ? e1_ : (grp == 2) ? e2_ : e3_; \
    const float fv_ = (grp == 1) ? val_ : (grp == 0) ? e1_ : (grp == 3) ? e2_ : e3_; \
    const float gv_ = (grp == 2) ? val_ : (grp == 3) ? e1_ : (grp == 0) ? e2_ : e3_; \
    const float ov_ = (grp == 3) ? val_ : (grp == 2) ? e1_ : (grp == 1) ? e2_ : e3_; \
    c = fmaf(fv_, c, iv_ * gv_);                                          \
    h = ov_ * tanh_fast(c);                                               \
    if (lane < 8) { GST(op + lane, h) }                                   \
    op += ostep;                                                          \
  }
#define GROUP2F(NW, G) {                                                  \
    const int mq_ = dir ? (NC - 1 - (G)) : (G);                           \
    const float* sb_ = xr + (mq_ & 3) * 256;                              \
    WAITV(NW);                                                            \
    { const int mp_ = dir ? (mq_ - 3) : (mq_ + 3);                        \
      const int sl_ = mp_ & 3;                                            \
      const int mpc_ = mp_ < 0 ? 0 : (mp_ >= NC ? NC - 1 : mp_);          \
      DMA16(ib + (size_t)mpc_ * 256 + lane * 4, xr + sl_ * 256) }         \
    STEP2F(sb_ + (dir ? 7 : 0) * 32)                                      \
    STEP2F(sb_ + (dir ? 6 : 1) * 32)                                      \
    STEP2F(sb_ + (dir ? 5 : 2) * 32)                                      \
    STEP2F(sb_ + (dir ? 4 : 3) * 32)                                      \
    STEP2F(sb_ + (dir ? 3 : 4) * 32)                                      \
    STEP2F(sb_ + (dir ? 2 : 5) * 32)                                      \
    STEP2F(sb_ + (dir ? 1 : 6) * 32)                                      \
    STEP2F(sb_ + (dir ? 0 : 7) * 32)                                      \
  }
  GROUP2F(2, 0)
  GROUP2F(10, 1)
  GROUP2F(18, 2)
#pragma unroll 1
  for (int g = 3; g < NC; ++g) {
    GROUP2F(26, g)
  }
#undef GROUP2F
#undef STEP2F
}

extern "C" void kernel_launch(void* const* d_in, const int* in_sizes, int n_in,
                              void* d_out, int out_size, void* d_ws, size_t ws_size,
                              hipStream_t stream) {
  const float* x     = (const float*)d_in[0];
  const float* wih1f = (const float*)d_in[1];
  const float* whh1f = (const float*)d_in[2];
  const float* bih1f = (const float*)d_in[3];
  const float* bhh1f = (const float*)d_in[4];
  const float* wih1b = (const float*)d_in[5];
  const float* whh1b = (const float*)d_in[6];
  const float* bih1b = (const float*)d_in[7];
  const float* bhh1b = (const float*)d_in[8];
  const float* wih2f = (const float*)d_in[9];
  const float* whh2f = (const float*)d_in[10];
  const float* bih2f = (const float*)d_in[11];
  const float* bhh2f = (const float*)d_in[12];
  const float* wih2b = (const float*)d_in[13];
  const float* whh2b = (const float*)d_in[14];
  const float* bih2b = (const float*)d_in[15];
  const float* bhh2b = (const float*)d_in[16];

  float* out1 = (float*)d_ws;                       // [B][T][32] = 67.1 MB
  float* outp = (float*)d_out;                      // [B][T][16]

  const size_t out1F = (size_t)Bn * Tn * 32;
  const size_t gx1F  = (size_t)Bn * 2 * Tn * 64;    // 268.4 MB
  const size_t needB = (out1F + gx1F) * sizeof(float);

  if (ws_size >= needB) {
    float* gx1 = (float*)d_ws + out1F;              // [2B][T][64]
    float* gx2 = gx1;                               // aliases gx1 (dead after scan1)
    gemm_gx1<<<Bn * 2 * 32, 64, 0, stream>>>(
        x, wih1f, bih1f, bhh1f, wih1b, bih1b, bhh1b, gx1);
    l1_scan_gx<<<Bn * 2, 64, 0, stream>>>(gx1, whh1f, whh1b, out1);
    gemm_gx2<<<Bn * 32, 64, 0, stream>>>(
        out1, wih2f, bih2f, bhh2f, wih2b, bih2b, bhh2b, gx2);
    l2_scan_gx<<<Bn * 2, 64, 0, stream>>>(gx2, whh2f, whh2b, outp);
  } else {
    l1_scan_fb<<<Bn * 2, 64, 0, stream>>>(x, wih1f, whh1f, bih1f, bhh1f,
                                          wih1b, whh1b, bih1b, bhh1b, out1);
    l2_scan_fb<<<Bn * 2, 64, 0, stream>>>(out1, wih2f, whh2f, bih2f, bhh2f,
                                          wih2b, whh2b, bih2b, bhh2b, outp);
  }
}

// Round 16
// 819.345 us; speedup vs baseline: 2.4089x; 1.1231x over previous
//
#include <hip/hip_runtime.h>

// 2-layer bidirectional LSTM, B=256 T=2048 D=64, H1=16/dir, H2=8/dir.
// R16 = R15 (PASS, 920us) + quad-gate layout + exp2 domain in gemms/scans.
//  - Lane = unit*4 + gate (rr = grp*H + u in PyTorch row space). Gate
//    exchange becomes 4 parallel quad_perm broadcasts (ctrl 0x55*q) --
//    no permlane chain, no cndmask cascade (~40-55cy off the serial chain).
//  - Butterfly: h pattern h_{l>>2}; terms via rotr16<4r> (low-2-bit unit
//    rotate) x xor16/32 (high-bit flips); weights precomputed per lane:
//    l1 idx = ((u&12)^(4s)) | (((u&3)-r)&3), l2 idx = ((u&4)^(4s)) | ...
//  - exp2 domain (exact): gemm emits -gin*log2e*gx, u-weights scaled the
//    same; cell state kept as cs = -2*log2e*c. Both nonlinearities are
//    rcp(1+exp2(.)) -- no log2e muls on the chain.
//  - DMA ring + counted vmcnt skeleton unchanged (R15-proven).
// Fallback kernels (R10, original math/layout) unchanged.

#ifndef __has_builtin
#define __has_builtin(x) 0
#endif

constexpr int Bn = 256;
constexpr int Tn = 2048;
#define LOG2E 1.4426950408889634f
#define KNEG2LOG2E -2.8853900817779268f

typedef unsigned int uint2v __attribute__((ext_vector_type(2)));

__device__ __forceinline__ float fast_rcp(float x) { return __builtin_amdgcn_rcpf(x); }
__device__ __forceinline__ float exp2_fast(float x) {
#if __has_builtin(__builtin_amdgcn_exp2f)
  return __builtin_amdgcn_exp2f(x);
#else
  return exp2f(x);
#endif
}
__device__ __forceinline__ float tanh_fast(float x) {   // fallback kernels only
  return fmaf(2.0f, fast_rcp(1.0f + __expf(-2.0f * x)), -1.0f);
}

// DPP rotate-right by R within each 16-lane row: dst[l] = src[(l-R)&15].
template <int R>
__device__ __forceinline__ float rotr16(float v) {
  return __int_as_float(__builtin_amdgcn_mov_dpp(
      __float_as_int(v), 0x120 | R, 0xF, 0xF, true));
}
// Quad broadcast: dst[l] = src[(l&~3) | Q].
template <int Q>
__device__ __forceinline__ float qbcast(float v) {
  return __int_as_float(__builtin_amdgcn_mov_dpp(
      __float_as_int(v), 0x55 * Q, 0xF, 0xF, true));
}

// val[l^16] / val[l^32], polarity-proof XOR-combine (R13-proven).
__device__ __forceinline__ float xor16_lane(float v) {
#if __has_builtin(__builtin_amdgcn_permlane16_swap)
  const unsigned u = __float_as_uint(v);
  uint2v r = __builtin_amdgcn_permlane16_swap(u, u, false, false);
  return __uint_as_float(r[0] ^ r[1] ^ u);
#else
  return __shfl_xor(v, 16, 64);
#endif
}
__device__ __forceinline__ float xor32_lane(float v) {
#if __has_builtin(__builtin_amdgcn_permlane32_swap)
  const unsigned u = __float_as_uint(v);
  uint2v r = __builtin_amdgcn_permlane32_swap(u, u, false, false);
  return __uint_as_float(r[0] ^ r[1] ^ u);
#else
  return __shfl_xor(v, 32, 64);
#endif
}

#define OPQ4(v) asm("" : "+v"(v.x), "+v"(v.y), "+v"(v.z), "+v"(v.w));
#define OPQ1(v) asm("" : "+v"(v));

#define GST(addr, val) \
  asm volatile("global_store_dword %0, %1, off" :: "v"(addr), "v"(val));

#define WAITV(N)                                              \
  do {                                                        \
    asm volatile("s_waitcnt vmcnt(" #N ")" ::: "memory");     \
    __builtin_amdgcn_sched_barrier(0);                        \
  } while (0)

#define DMA16(gsrc, ldst)                                         \
  __builtin_amdgcn_global_load_lds(                               \
      (const __attribute__((address_space(1))) float*)(gsrc),     \
      (__attribute__((address_space(3))) float*)(ldst), 16, 0, 0);

#define FMAU(ACC, I) { const float4 xv_ = x4[I];                    \
    ACC = fmaf(xv_.x, w##I.x, ACC); ACC = fmaf(xv_.y, w##I.y, ACC); \
    ACC = fmaf(xv_.z, w##I.z, ACC); ACC = fmaf(xv_.w, w##I.w, ACC); }

#define FMAQ(ACC, I) { float4 v_ = xq_[I];                          \
    ACC = fmaf(v_.x, w##I.x, ACC); ACC = fmaf(v_.y, w##I.y, ACC);   \
    ACC = fmaf(v_.z, w##I.z, ACC); ACC = fmaf(v_.w, w##I.w, ACC); }

// ============ GEMM 1: gx1[bd][s][64], quad-interleaved, exp2-prescaled ============
__global__ __launch_bounds__(64, 2) void gemm_gx1(
    const float* __restrict__ x,
    const float* __restrict__ wf, const float* __restrict__ bif,
    const float* __restrict__ bhf,
    const float* __restrict__ wb, const float* __restrict__ bib,
    const float* __restrict__ bhb,
    float* __restrict__ gx1) {
  constexpr int TILES = 32, TT = Tn / TILES;
  constexpr int NG = TT / 4;
  const int lane = threadIdx.x;
  const int bd   = blockIdx.x / TILES;
  const int tile = blockIdx.x % TILES;
  const int dir  = bd & 1, b = bd >> 1;

  __shared__ float xr[4 * 256];
  const float* xb = x + ((size_t)b * Tn + tile * TT) * 64;

#pragma unroll
  for (int p = 0; p < 3; ++p)
    DMA16(xb + (size_t)p * 256 + lane * 4, xr + p * 256)

  const int grp = lane & 3, un = lane >> 2;
  const int rr = grp * 16 + un;                 // PyTorch gate row
  const float* W = dir ? wb : wf;               // [64][64]
  float bias = (dir ? bib : bif)[rr] + (dir ? bhb : bhf)[rr];
  const float sc = (grp == 2) ? (-2.0f * LOG2E) : (-LOG2E);

  const float4* wr = reinterpret_cast<const float4*>(W + rr * 64);
  float4 w0 = wr[0],  w1 = wr[1],  w2 = wr[2],  w3 = wr[3],
         w4 = wr[4],  w5 = wr[5],  w6 = wr[6],  w7 = wr[7],
         w8 = wr[8],  w9 = wr[9],  w10 = wr[10], w11 = wr[11],
         w12 = wr[12], w13 = wr[13], w14 = wr[14], w15 = wr[15];
  OPQ4(w0)  OPQ4(w1)  OPQ4(w2)  OPQ4(w3)  OPQ4(w4)  OPQ4(w5)
  OPQ4(w6)  OPQ4(w7)  OPQ4(w8)  OPQ4(w9)  OPQ4(w10) OPQ4(w11)
  OPQ4(w12) OPQ4(w13) OPQ4(w14) OPQ4(w15) OPQ1(bias)

  const int t0 = tile * TT;
  const int sstep = dir ? -1 : 1;
  float* op = gx1 + (size_t)bd * Tn * 64 +
              (size_t)(dir ? (Tn - 1 - t0) : t0) * 64 + lane;

#define ROWDOT1(RP, RES) {                                               \
    const float4* x4 = reinterpret_cast<const float4*>(RP);              \
    float a0 = bias, a1 = 0.f, a2 = 0.f, a3 = 0.f;                       \
    FMAU(a0, 0)  FMAU(a1, 1)  FMAU(a2, 2)  FMAU(a3, 3)                  \
    FMAU(a0, 4)  FMAU(a1, 5)  FMAU(a2, 6)  FMAU(a3, 7)                  \
    FMAU(a0, 8)  FMAU(a1, 9)  FMAU(a2, 10) FMAU(a3, 11)                 \
    FMAU(a0, 12) FMAU(a1, 13) FMAU(a2, 14) FMAU(a3, 15)                 \
    RES = sc * ((a0 + a1) + (a2 + a3)); }

#define GG1(NW, G) {                                                     \
    WAITV(NW);                                                           \
    { const int mp_ = (G) + 3;                                           \
      const int mpc_ = (mp_ < NG) ? mp_ : NG - 1;                        \
      DMA16(xb + (size_t)mpc_ * 256 + lane * 4, xr + (mp_ & 3) * 256) }  \
    const float* sb_ = xr + ((G) & 3) * 256;                             \
    float h0_, h1_, h2_, h3_;                                            \
    ROWDOT1(sb_, h0_)        ROWDOT1(sb_ + 64, h1_)                      \
    ROWDOT1(sb_ + 128, h2_)  ROWDOT1(sb_ + 192, h3_)                     \
    GST(op, h0_)                 GST(op + sstep * 64, h1_)               \
    GST(op + 2 * sstep * 64, h2_) GST(op + 3 * sstep * 64, h3_)          \
    op += 4 * sstep * 64; }

  GG1(2, 0)
  GG1(6, 1)
  GG1(10, 2)
#pragma unroll 1
  for (int g = 3; g < NG; ++g) {
    GG1(14, g)
  }
#undef GG1
#undef ROWDOT1
}

// ============ GEMM 2: gx2[bd][s][32], quad-interleaved, exp2-prescaled ============
__global__ __launch_bounds__(64, 2) void gemm_gx2(
    const float* __restrict__ in,   // out1 [B][T][32]
    const float* __restrict__ wf, const float* __restrict__ bif,
    const float* __restrict__ bhf,
    const float* __restrict__ wb, const float* __restrict__ bib,
    const float* __restrict__ bhb,
    float* __restrict__ gx2) {
  constexpr int TILES = 32, TT = Tn / TILES;
  constexpr int NG = TT / 8;
  const int lane = threadIdx.x;
  const int g = lane & 31, half = lane >> 5;
  const int b = blockIdx.x / TILES, tile = blockIdx.x % TILES;

  __shared__ float xr[4 * 256];
  const float* ib = in + ((size_t)b * Tn + tile * TT) * 32;

#pragma unroll
  for (int p = 0; p < 3; ++p)
    DMA16(ib + (size_t)p * 256 + lane * 4, xr + p * 256)

  const int grp = g & 3, un = g >> 2;
  const int rr = grp * 8 + un;
  const float* W = half ? wb : wf;  // [32][32]
  float bias = (half ? bib : bif)[rr] + (half ? bhb : bhf)[rr];
  const float sc = (grp == 2) ? (-2.0f * LOG2E) : (-LOG2E);

  const float4* wr = reinterpret_cast<const float4*>(W + rr * 32);
  float4 w0 = wr[0], w1 = wr[1], w2 = wr[2], w3 = wr[3],
         w4 = wr[4], w5 = wr[5], w6 = wr[6], w7 = wr[7];
  OPQ4(w0) OPQ4(w1) OPQ4(w2) OPQ4(w3) OPQ4(w4) OPQ4(w5) OPQ4(w6) OPQ4(w7)
  OPQ1(bias)

  const int t0 = tile * TT;
  const int slstep = half ? -1 : 1;
  float* op = gx2 + ((size_t)(b * 2 + half) * Tn +
              (half ? (Tn - 1 - t0) : t0)) * 32 + g;

#define ROWDOT2(RP, RES) {                                               \
    const float4* x4 = reinterpret_cast<const float4*>(RP);              \
    float a0 = bias, a1 = 0.f, a2 = 0.f, a3 = 0.f;                       \
    FMAU(a0, 0) FMAU(a1, 1) FMAU(a2, 2) FMAU(a3, 3)                     \
    FMAU(a0, 4) FMAU(a1, 5) FMAU(a2, 6) FMAU(a3, 7)                     \
    RES = sc * ((a0 + a1) + (a2 + a3)); }

#define GG2(NW, G) {                                                     \
    WAITV(NW);                                                           \
    { const int mp_ = (G) + 3;                                           \
      const int mpc_ = (mp_ < NG) ? mp_ : NG - 1;                        \
      DMA16(ib + (size_t)mpc_ * 256 + lane * 4, xr + (mp_ & 3) * 256) }  \
    const float* sb_ = xr + ((G) & 3) * 256;                             \
    float h0_, h1_, h2_, h3_, h4_, h5_, h6_, h7_;                        \
    ROWDOT2(sb_, h0_)        ROWDOT2(sb_ + 32, h1_)                      \
    ROWDOT2(sb_ + 64, h2_)   ROWDOT2(sb_ + 96, h3_)                      \
    ROWDOT2(sb_ + 128, h4_)  ROWDOT2(sb_ + 160, h5_)                     \
    ROWDOT2(sb_ + 192, h6_)  ROWDOT2(sb_ + 224, h7_)                     \
    GST(op, h0_)                  GST(op + slstep * 32, h1_)             \
    GST(op + 2 * slstep * 32, h2_) GST(op + 3 * slstep * 32, h3_)        \
    GST(op + 4 * slstep * 32, h4_) GST(op + 5 * slstep * 32, h5_)        \
    GST(op + 6 * slstep * 32, h6_) GST(op + 7 * slstep * 32, h7_)        \
    op += 8 * slstep * 32; }

  GG2(2, 0)
  GG2(10, 1)
  GG2(18, 2)
#pragma unroll 1
  for (int gg = 3; gg < NG; ++gg) {
    GG2(26, gg)
  }
#undef GG2
#undef ROWDOT2
}

// ============ Scan 1 (quad layout, exp2 domain): H=16 ============
__global__ __launch_bounds__(64, 1) void l1_scan_gx(
    const float* __restrict__ gx1,
    const float* __restrict__ whh_f, const float* __restrict__ whh_b,
    float* __restrict__ out1) {
  constexpr int NC = Tn / 4;
  const int lane = threadIdx.x;
  const int dir  = blockIdx.x & 1;
  const int b    = blockIdx.x >> 1;

  __shared__ float xr[4 * 256];
  const float* gxb = gx1 + (size_t)blockIdx.x * Tn * 64;

#pragma unroll
  for (int p = 0; p < 3; ++p)
    DMA16(gxb + (size_t)p * 256 + lane * 4, xr + p * 256)

  const float* whh = dir ? whh_b : whh_f;  // [64][16]
  const int grp = lane & 3, un = lane >> 2;
  const int rr = grp * 16 + un;
  const float sc = (grp == 2) ? (-2.0f * LOG2E) : (-LOG2E);
  const float* whr = whh + rr * 16;
  // u[s*4+r] = sc * Whh[rr][ ((un&12)^(4s)) | (((un&3)-r)&3) ]
#define UIDX(S, R) (((un & 12) ^ (4 * (S))) | (((un & 3) - (R)) & 3))
  float u0  = sc * whr[UIDX(0, 0)], u1  = sc * whr[UIDX(0, 1)],
        u2  = sc * whr[UIDX(0, 2)], u3  = sc * whr[UIDX(0, 3)],
        u4  = sc * whr[UIDX(1, 0)], u5  = sc * whr[UIDX(1, 1)],
        u6  = sc * whr[UIDX(1, 2)], u7  = sc * whr[UIDX(1, 3)],
        u8  = sc * whr[UIDX(2, 0)], u9  = sc * whr[UIDX(2, 1)],
        u10 = sc * whr[UIDX(2, 2)], u11 = sc * whr[UIDX(2, 3)],
        u12 = sc * whr[UIDX(3, 0)], u13 = sc * whr[UIDX(3, 1)],
        u14 = sc * whr[UIDX(3, 2)], u15 = sc * whr[UIDX(3, 3)];
#undef UIDX
  OPQ1(u0)  OPQ1(u1)  OPQ1(u2)  OPQ1(u3)  OPQ1(u4)  OPQ1(u5)
  OPQ1(u6)  OPQ1(u7)  OPQ1(u8)  OPQ1(u9)  OPQ1(u10) OPQ1(u11)
  OPQ1(u12) OPQ1(u13) OPQ1(u14) OPQ1(u15)

  const float gout = (grp == 2) ? 2.0f : 1.0f;
  const float gsub = (grp == 2) ? -1.0f : 0.0f;

  const int ostep = dir ? -32 : 32;
  float* op = out1 + (size_t)b * Tn * 32 + dir * 16 +
              (dir ? (size_t)(Tn - 1) * 32 : 0);

  float h = 0.0f, cs = 0.0f;   // cs = -2*log2e*c

#define STEP1(GX, HS) {                                                   \
    const float hb1 = xor16_lane(h);                                      \
    const float hb2 = xor32_lane(h);                                      \
    const float hb3 = xor16_lane(hb2);                                    \
    float m0 = h * u0;                                                    \
    m0 = fmaf(rotr16<4>(h),   u1,  m0);                                   \
    m0 = fmaf(rotr16<8>(h),   u2,  m0);                                   \
    m0 = fmaf(rotr16<12>(h),  u3,  m0);                                   \
    float m1 = hb1 * u4;                                                  \
    m1 = fmaf(rotr16<4>(hb1),  u5,  m1);                                  \
    m1 = fmaf(rotr16<8>(hb1),  u6,  m1);                                  \
    m1 = fmaf(rotr16<12>(hb1), u7,  m1);                                  \
    float m2 = hb2 * u8;                                                  \
    m2 = fmaf(rotr16<4>(hb2),  u9,  m2);                                  \
    m2 = fmaf(rotr16<8>(hb2),  u10, m2);                                  \
    m2 = fmaf(rotr16<12>(hb2), u11, m2);                                  \
    float m3 = hb3 * u12;                                                 \
    m3 = fmaf(rotr16<4>(hb3),  u13, m3);                                  \
    m3 = fmaf(rotr16<8>(hb3),  u14, m3);                                  \
    m3 = fmaf(rotr16<12>(hb3), u15, m3);                                  \
    const float g_ = ((m0 + m1) + (m2 + m3)) + (GX);                      \
    const float t_  = fast_rcp(1.0f + exp2_fast(g_));                     \
    const float val_ = fmaf(gout, t_, gsub);                              \
    const float iv_ = qbcast<0>(val_);                                    \
    const float fv_ = qbcast<1>(val_);                                    \
    const float gv_ = qbcast<2>(val_);                                    \
    const float ov_ = qbcast<3>(val_);                                    \
    cs = fmaf(fv_, cs, KNEG2LOG2E * (iv_ * gv_));                         \
    const float t2_ = fast_rcp(1.0f + exp2_fast(cs));                     \
    h = ov_ * fmaf(2.0f, t2_, -1.0f);                                     \
    HS = h;                                                               \
  }

  // Per group: 1 DMA + 4 GST -> counted waits 2/6/10 then 14 (proven).
#define GROUP1(NW, G) {                                                   \
    WAITV(NW);                                                            \
    const float* sb_ = xr + ((G) & 3) * 256;                              \
    const float q0_ = sb_[lane];                                          \
    const float q1_ = sb_[64 + lane];                                     \
    const float q2_ = sb_[128 + lane];                                    \
    const float q3_ = sb_[192 + lane];                                    \
    { const int mp_ = (G) + 3;                                            \
      const int mpc_ = (mp_ < NC) ? mp_ : NC - 1;                         \
      DMA16(gxb + (size_t)mpc_ * 256 + lane * 4, xr + (mp_ & 3) * 256) }  \
    float h0_, h1_, h2_, h3_;                                             \
    STEP1(q0_, h0_) STEP1(q1_, h1_) STEP1(q2_, h2_) STEP1(q3_, h3_)       \
    if ((lane & 3) == 0) {                                                \
      GST(op + un, h0_)                                                   \
      GST(op + ostep + un, h1_)                                           \
      GST(op + 2 * ostep + un, h2_)                                       \
      GST(op + 3 * ostep + un, h3_)                                       \
    }                                                                     \
    op += 4 * ostep;                                                      \
  }

  GROUP1(2, 0)
  GROUP1(6, 1)
  GROUP1(10, 2)
#pragma unroll 1
  for (int g = 3; g < NC; ++g) {
    GROUP1(14, g)
  }
#undef GROUP1
#undef STEP1
}

// ============ Scan 2 (quad layout, exp2 domain): H=8 ============
__global__ __launch_bounds__(64, 1) void l2_scan_gx(
    const float* __restrict__ gx2,
    const float* __restrict__ whh_f, const float* __restrict__ whh_b,
    float* __restrict__ out) {
  constexpr int NC = Tn / 8;
  const int lane = threadIdx.x;
  const int j    = lane & 31;
  const int dir  = blockIdx.x & 1;
  const int b    = blockIdx.x >> 1;

  __shared__ float xr[4 * 256];
  const float* gxb = gx2 + (size_t)blockIdx.x * Tn * 32;

#pragma unroll
  for (int p = 0; p < 3; ++p)
    DMA16(gxb + (size_t)p * 256 + lane * 4, xr + p * 256)

  const float* whh = dir ? whh_b : whh_f;  // [32][8]
  const int grp = j & 3, un = j >> 2;      // un in 0..7
  const int rr = grp * 8 + un;
  const float sc = (grp == 2) ? (-2.0f * LOG2E) : (-LOG2E);
  const float* whr = whh + rr * 8;
#define UIDX2(S, R) (((un & 4) ^ (4 * (S))) | (((un & 3) - (R)) & 3))
  float u0 = sc * whr[UIDX2(0, 0)], u1 = sc * whr[UIDX2(0, 1)],
        u2 = sc * whr[UIDX2(0, 2)], u3 = sc * whr[UIDX2(0, 3)],
        u4 = sc * whr[UIDX2(1, 0)], u5 = sc * whr[UIDX2(1, 1)],
        u6 = sc * whr[UIDX2(1, 2)], u7 = sc * whr[UIDX2(1, 3)];
#undef UIDX2
  OPQ1(u0) OPQ1(u1) OPQ1(u2) OPQ1(u3) OPQ1(u4) OPQ1(u5) OPQ1(u6) OPQ1(u7)

  const float gout = (grp == 2) ? 2.0f : 1.0f;
  const float gsub = (grp == 2) ? -1.0f : 0.0f;

  const int ostep = dir ? -16 : 16;
  float* op = out + (size_t)b * Tn * 16 + dir * 8 +
              (dir ? (size_t)(Tn - 1) * 16 : 0);

  float h = 0.0f, cs = 0.0f;

#define STEP2(GX, HS) {                                                   \
    const float hb1 = xor16_lane(h);                                      \
    float m0 = h * u0;                                                    \
    m0 = fmaf(rotr16<4>(h),   u1, m0);                                    \
    m0 = fmaf(rotr16<8>(h),   u2, m0);                                    \
    m0 = fmaf(rotr16<12>(h),  u3, m0);                                    \
    float m1 = hb1 * u4;                                                  \
    m1 = fmaf(rotr16<4>(hb1),  u5, m1);                                   \
    m1 = fmaf(rotr16<8>(hb1),  u6, m1);                                   \
    m1 = fmaf(rotr16<12>(hb1), u7, m1);                                   \
    const float g_ = (m0 + m1) + (GX);                                    \
    const float t_  = fast_rcp(1.0f + exp2_fast(g_));                     \
    const float val_ = fmaf(gout, t_, gsub);                              \
    const float iv_ = qbcast<0>(val_);                                    \
    const float fv_ = qbcast<1>(val_);                                    \
    const float gv_ = qbcast<2>(val_);                                    \
    const float ov_ = qbcast<3>(val_);                                    \
    cs = fmaf(fv_, cs, KNEG2LOG2E * (iv_ * gv_));                         \
    const float t2_ = fast_rcp(1.0f + exp2_fast(cs));                     \
    h = ov_ * fmaf(2.0f, t2_, -1.0f);                                     \
    HS = h;                                                               \
  }

  // Per group: 1 DMA + 8 GST -> counted waits 2/10/18 then 26 (proven).
#define GROUP2(NW, G) {                                                   \
    WAITV(NW);                                                            \
    const float* sb_ = xr + ((G) & 3) * 256;                              \
    const float q0_ = sb_[j];            const float q1_ = sb_[32 + j];   \
    const float q2_ = sb_[64 + j];       const float q3_ = sb_[96 + j];   \
    const float q4_ = sb_[128 + j];      const float q5_ = sb_[160 + j];  \
    const float q6_ = sb_[192 + j];      const float q7_ = sb_[224 + j];  \
    { const int mp_ = (G) + 3;                                            \
      const int mpc_ = (mp_ < NC) ? mp_ : NC - 1;                         \
      DMA16(gxb + (size_t)mpc_ * 256 + lane * 4, xr + (mp_ & 3) * 256) }  \
    float h0_, h1_, h2_, h3_, h4_, h5_, h6_, h7_;                         \
    STEP2(q0_, h0_) STEP2(q1_, h1_) STEP2(q2_, h2_) STEP2(q3_, h3_)       \
    STEP2(q4_, h4_) STEP2(q5_, h5_) STEP2(q6_, h6_) STEP2(q7_, h7_)       \
    if ((lane & 3) == 0 && lane < 32) {                                   \
      GST(op + un, h0_)                                                   \
      GST(op + ostep + un, h1_)                                           \
      GST(op + 2 * ostep + un, h2_)                                       \
      GST(op + 3 * ostep + un, h3_)                                       \
      GST(op + 4 * ostep + un, h4_)                                       \
      GST(op + 5 * ostep + un, h5_)                                       \
      GST(op + 6 * ostep + un, h6_)                                       \
      GST(op + 7 * ostep + un, h7_)                                       \
    }                                                                     \
    op += 8 * ostep;                                                      \
  }

  GROUP2(2, 0)
  GROUP2(10, 1)
  GROUP2(18, 2)
#pragma unroll 1
  for (int g = 3; g < NC; ++g) {
    GROUP2(26, g)
  }
#undef GROUP2
#undef STEP2
}

// ==================== Fallback (R10, proven): weights in scan ====================
__global__ __launch_bounds__(64, 1) void l1_scan_fb(
    const float* __restrict__ x,
    const float* __restrict__ wih_f, const float* __restrict__ whh_f,
    const float* __restrict__ bih_f, const float* __restrict__ bhh_f,
    const float* __restrict__ wih_b, const float* __restrict__ whh_b,
    const float* __restrict__ bih_b, const float* __restrict__ bhh_b,
    float* __restrict__ out1) {
  constexpr int NC = Tn / 4;
  const int lane = threadIdx.x;
  const int dir  = blockIdx.x & 1;
  const int b    = blockIdx.x >> 1;
  __shared__ float xr[4 * 256];
  const float* xb = x + (size_t)b * (Tn * 64);
  {
    const int m0 = dir ? NC - 1 : 0;
    const int md = dir ? -1 : 1;
#pragma unroll
    for (int q = 0; q < 3; ++q) {
      const int mc = m0 + q * md;
      DMA16(xb + (size_t)mc * 256 + lane * 4, xr + (mc & 3) * 256)
    }
  }
  const float* wih = dir ? wih_b : wih_f;
  const float* whh = dir ? whh_b : whh_f;
  float bias = (dir ? bih_b : bih_f)[lane] + (dir ? bhh_b : bhh_f)[lane];
  const int k = lane & 15, grp = lane >> 4;
  const float gin  = (grp == 2) ? 2.0f : 1.0f;
  const float gout = (grp == 2) ? 2.0f : 1.0f;
  const float gsub = (grp == 2) ? -1.0f : 0.0f;
  const float4* wr = reinterpret_cast<const float4*>(wih + lane * 64);
  float4 w0 = wr[0],  w1 = wr[1],  w2 = wr[2],  w3 = wr[3],
         w4 = wr[4],  w5 = wr[5],  w6 = wr[6],  w7 = wr[7],
         w8 = wr[8],  w9 = wr[9],  w10 = wr[10], w11 = wr[11],
         w12 = wr[12], w13 = wr[13], w14 = wr[14], w15 = wr[15];
  const float* whr = whh + lane * 16;
  float u0 = whr[k], u1 = whr[(k - 1) & 15], u2 = whr[(k - 2) & 15],
        u3 = whr[(k - 3) & 15], u4 = whr[(k - 4) & 15],
        u5 = whr[(k - 5) & 15], u6 = whr[(k - 6) & 15],
        u7 = whr[(k - 7) & 15], u8 = whr[(k - 8) & 15],
        u9 = whr[(k - 9) & 15], u10 = whr[(k - 10) & 15],
        u11 = whr[(k - 11) & 15], u12 = whr[(k - 12) & 15],
        u13 = whr[(k - 13) & 15], u14 = whr[(k - 14) & 15],
        u15 = whr[(k - 15) & 15];
  const int ostep = dir ? -32 : 32;
  float* op = out1 + (size_t)b * (Tn * 32) + dir * 16 +
              (dir ? (size_t)(Tn - 1) * 32 : 0);
  float h = 0.0f, c = 0.0f;
#define STEP1F(XROW) {                                                    \
    const float4* xq_ = reinterpret_cast<const float4*>(XROW);            \
    float a0 = bias, a1 = 0.f, a2 = 0.f, a3 = 0.f;                        \
    FMAQ(a0, 0)  FMAQ(a1, 1)  FMAQ(a2, 2)  FMAQ(a3, 3)                   \
    FMAQ(a0, 4)  FMAQ(a1, 5)  FMAQ(a2, 6)  FMAQ(a3, 7)                   \
    FMAQ(a0, 8)  FMAQ(a1, 9)  FMAQ(a2, 10) FMAQ(a3, 11)                  \
    FMAQ(a0, 12) FMAQ(a1, 13) FMAQ(a2, 14) FMAQ(a3, 15)                  \
    const float gx_ = (a0 + a1) + (a2 + a3);                              \
    float m0 = h * u0, m1 = 0.f, m2 = 0.f, m3 = 0.f;                      \
    m1 = fmaf(rotr16<1>(h),  u1,  m1);  m2 = fmaf(rotr16<2>(h),  u2,  m2); \
    m3 = fmaf(rotr16<3>(h),  u3,  m3);  m0 = fmaf(rotr16<4>(h),  u4,  m0); \
    m1 = fmaf(rotr16<5>(h),  u5,  m1);  m2 = fmaf(rotr16<6>(h),  u6,  m2); \
    m3 = fmaf(rotr16<7>(h),  u7,  m3);  m0 = fmaf(rotr16<8>(h),  u8,  m0); \
    m1 = fmaf(rotr16<9>(h),  u9,  m1);  m2 = fmaf(rotr16<10>(h), u10, m2); \
    m3 = fmaf(rotr16<11>(h), u11, m3);  m0 = fmaf(rotr16<12>(h), u12, m0); \
    m1 = fmaf(rotr16<13>(h), u13, m1);  m2 = fmaf(rotr16<14>(h), u14, m2); \
    m3 = fmaf(rotr16<15>(h), u15, m3);                                    \
    const float g_ = ((m0 + m1) + (m2 + m3)) + gx_;                       \
    const float sg_  = fast_rcp(1.0f + __expf(-gin * g_));                \
    const float val_ = fmaf(gout, sg_, gsub);                             \
    const float e1_ = __shfl_xor(val_, 16, 64);                           \
    const float e2_ = __shfl_xor(val_, 32, 64);                           \
    const float e3_ = __shfl_xor(val_, 48, 64);                           \
    const float iv_ = (grp == 0) ? val_ : (grp == 1) ? e1_ : (grp == 2) ? e2_ : e3_; \
    const float fv_ = (grp == 1) ? val_ : (grp == 0) ? e1_ : (grp == 3) ? e2_ : e3_; \
    const float gv_ = (grp == 2) ? val_ : (grp == 3) ? e1_ : (grp == 0) ? e2_ : e3_; \
    const float ov_ = (grp == 3) ? val_ : (grp == 2) ? e1_ : (grp == 1) ? e2_ : e3_; \
    c = fmaf(fv_, c, iv_ * gv_);                                          \
    h = ov_ * tanh_fast(c);                                               \
    if (lane < 16) { GST(op + lane, h) }                                  \
    op += ostep;                                                          \
  }
#define GROUP1F(NW, G) {                                                  \
    const int mq_ = dir ? (NC - 1 - (G)) : (G);                           \
    const float* sb_ = xr + (mq_ & 3) * 256;                              \
    WAITV(NW);                                                            \
    { const int mp_ = dir ? (mq_ - 3) : (mq_ + 3);                        \
      const int sl_ = mp_ & 3;                                            \
      const int mpc_ = mp_ < 0 ? 0 : (mp_ >= NC ? NC - 1 : mp_);          \
      DMA16(xb + (size_t)mpc_ * 256 + lane * 4, xr + sl_ * 256) }         \
    STEP1F(sb_ + (dir ? 3 : 0) * 64)                                      \
    STEP1F(sb_ + (dir ? 2 : 1) * 64)                                      \
    STEP1F(sb_ + (dir ? 1 : 2) * 64)                                      \
    STEP1F(sb_ + (dir ? 0 : 3) * 64)                                      \
  }
  GROUP1F(2, 0)
  GROUP1F(6, 1)
  GROUP1F(10, 2)
#pragma unroll 1
  for (int g = 3; g < NC; ++g) {
    GROUP1F(14, g)
  }
#undef GROUP1F
#undef STEP1F
}

__global__ __launch_bounds__(64, 1) void l2_scan_fb(
    const float* __restrict__ in,
    const float* __restrict__ wih_f, const float* __restrict__ whh_f,
    const float* __restrict__ bih_f, const float* __restrict__ bhh_f,
    const float* __restrict__ wih_b, const float* __restrict__ whh_b,
    const float* __restrict__ bih_b, const float* __restrict__ bhh_b,
    float* __restrict__ out) {
  constexpr int NC = Tn / 8;
  const int lane = threadIdx.x;
  const int j    = lane & 31;
  const int dir  = blockIdx.x & 1;
  const int b    = blockIdx.x >> 1;
  __shared__ float xr[4 * 256];
  const float* ib = in + (size_t)b * (Tn * 32);
  {
    const int m0 = dir ? NC - 1 : 0;
    const int md = dir ? -1 : 1;
#pragma unroll
    for (int q = 0; q < 3; ++q) {
      const int mc = m0 + q * md;
      DMA16(ib + (size_t)mc * 256 + lane * 4, xr + (mc & 3) * 256)
    }
  }
  const float* wih = dir ? wih_b : wih_f;
  const float* whh = dir ? whh_b : whh_f;
  float bias = (dir ? bih_b : bih_f)[j] + (dir ? bhh_b : bhh_f)[j];
  const int k = j & 7, grp = j >> 3;
  const float gin  = (grp == 2) ? 2.0f : 1.0f;
  const float gout = (grp == 2) ? 2.0f : 1.0f;
  const float gsub = (grp == 2) ? -1.0f : 0.0f;
  const float4* wr = reinterpret_cast<const float4*>(wih + j * 32);
  float4 w0 = wr[0], w1 = wr[1], w2 = wr[2], w3 = wr[3],
         w4 = wr[4], w5 = wr[5], w6 = wr[6], w7 = wr[7];
  const float* whr = whh + j * 8;
  float u0 = whr[k], u1 = whr[(k - 1) & 7], u2 = whr[(k - 2) & 7],
        u3 = whr[(k - 3) & 7], u4 = whr[(k - 4) & 7],
        u5 = whr[(k - 5) & 7], u6 = whr[(k - 6) & 7],
        u7 = whr[(k - 7) & 7];
  const int ostep = dir ? -16 : 16;
  float* op = out + (size_t)b * (Tn * 16) + dir * 8 +
              (dir ? (size_t)(Tn - 1) * 16 : 0);
  float h = 0.0f, c = 0.0f;
#define STEP2F(XROW) {                                                    \
    const float4* xq_ = reinterpret_cast<const float4*>(XROW);            \
    float a0 = bias, a1 = 0.f, a2 = 0.f, a3 = 0.f;                        \
    FMAQ(a0, 0) FMAQ(a1, 1) FMAQ(a2, 2) FMAQ(a3, 3)                      \
    FMAQ(a0, 4) FMAQ(a1, 5) FMAQ(a2, 6) FMAQ(a3, 7)                      \
    const float gx_ = (a0 + a1) + (a2 + a3);                              \
    float m0 = h * u0, m1 = 0.f, m2 = 0.f, m3 = 0.f;                      \
    m1 = fmaf(rotr16<1>(h), u1, m1);  m2 = fmaf(rotr16<2>(h), u2, m2);    \
    m3 = fmaf(rotr16<3>(h), u3, m3);  m0 = fmaf(rotr16<4>(h), u4, m0);    \
    m1 = fmaf(rotr16<5>(h), u5, m1);  m2 = fmaf(rotr16<6>(h), u6, m2);    \
    m3 = fmaf(rotr16<7>(h), u7, m3);                                      \
    const float g_ = ((m0 + m1) + (m2 + m3)) + gx_;                       \
    const float sg_  = fast_rcp(1.0f + __expf(-gin * g_));                \
    const float val_ = fmaf(gout, sg_, gsub);                             \
    const float e1_ = __shfl_xor(val_, 8, 64);                            \
    const float e2_ = __shfl_xor(val_, 16, 64);                           \
    const float e3_ = __shfl_xor(val_, 24, 64);                           \
    const float iv_ = (grp == 0) ? val_ : (grp == 1) ? e1_ : (grp == 2) ? e2_ : e3_; \
    const float fv_ = (grp == 1) ? val_ : (grp == 0) ? e1_ : (grp == 3) ? e2_ : e3_; \
    const float gv_ = (grp == 2) ? val_ : (grp == 3) ? e1_ : (grp == 0) ? e2_ : e3_; \
    const float ov_ = (grp == 3) ? val_ : (grp == 2) ? e1_ : (grp == 1) ? e2_ : e3_; \
    c = fmaf(fv_, c, iv_ * gv_);                                          \
    h = ov_ * tanh_fast(c);                                               \
    if (lane < 8) { GST(op + lane, h) }                                   \
    op += ostep;                                                          \
  }
#define GROUP2F(NW, G) {                                                  \
    const int mq_ = dir ? (NC - 1 - (G)) : (G);                           \
    const float* sb_ = xr + (mq_ & 3) * 256;                              \
    WAITV(NW);                                                            \
    { const int mp_ = dir ? (mq_ - 3) : (mq_ + 3);                        \
      const int sl_ = mp_ & 3;                                            \
      const int mpc_ = mp_ < 0 ? 0 : (mp_ >= NC ? NC - 1 : mp_);          \
      DMA16(ib + (size_t)mpc_ * 256 + lane * 4, xr + sl_ * 256) }         \
    STEP2F(sb_ + (dir ? 7 : 0) * 32)                                      \
    STEP2F(sb_ + (dir ? 6 : 1) * 32)                                      \
    STEP2F(sb_ + (dir ? 5 : 2) * 32)                                      \
    STEP2F(sb_ + (dir ? 4 : 3) * 32)                                      \
    STEP2F(sb_ + (dir ? 3 : 4) * 32)                                      \
    STEP2F(sb_ + (dir ? 2 : 5) * 32)                                      \
    STEP2F(sb_ + (dir ? 1 : 6) * 32)                                      \
    STEP2F(sb_ + (dir ? 0 : 7) * 32)                                      \
  }
  GROUP2F(2, 0)
  GROUP2F(10, 1)
  GROUP2F(18, 2)
#pragma unroll 1
  for (int g = 3; g < NC; ++g) {
    GROUP2F(26, g)
  }
#undef GROUP2F
#undef STEP2F
}

extern "C" void kernel_launch(void* const* d_in, const int* in_sizes, int n_in,
                              void* d_out, int out_size, void* d_ws, size_t ws_size,
                              hipStream_t stream) {
  const float* x     = (const float*)d_in[0];
  const float* wih1f = (const float*)d_in[1];
  const float* whh1f = (const float*)d_in[2];
  const float* bih1f = (const float*)d_in[3];
  const float* bhh1f = (const float*)d_in[4];
  const float* wih1b = (const float*)d_in[5];
  const float* whh1b = (const float*)d_in[6];
  const float* bih1b = (const float*)d_in[7];
  const float* bhh1b = (const float*)d_in[8];
  const float* wih2f = (const float*)d_in[9];
  const float* whh2f = (const float*)d_in[10];
  const float* bih2f = (const float*)d_in[11];
  const float* bhh2f = (const float*)d_in[12];
  const float* wih2b = (const float*)d_in[13];
  const float* whh2b = (const float*)d_in[14];
  const float* bih2b = (const float*)d_in[15];
  const float* bhh2b = (const float*)d_in[16];

  float* out1 = (float*)d_ws;                       // [B][T][32] = 67.1 MB
  float* outp = (float*)d_out;                      // [B][T][16]

  const size_t out1F = (size_t)Bn * Tn * 32;
  const size_t gx1F  = (size_t)Bn * 2 * Tn * 64;    // 268.4 MB
  const size_t needB = (out1F + gx1F) * sizeof(float);

  if (ws_size >= needB) {
    float* gx1 = (float*)d_ws + out1F;              // [2B][T][64]
    float* gx2 = gx1;                               // aliases gx1 (dead after scan1)
    gemm_gx1<<<Bn * 2 * 32, 64, 0, stream>>>(
        x, wih1f, bih1f, bhh1f, wih1b, bih1b, bhh1b, gx1);
    l1_scan_gx<<<Bn * 2, 64, 0, stream>>>(gx1, whh1f, whh1b, out1);
    gemm_gx2<<<Bn * 32, 64, 0, stream>>>(
        out1, wih2f, bih2f, bhh2f, wih2b, bih2b, bhh2b, gx2);
    l2_scan_gx<<<Bn * 2, 64, 0, stream>>>(gx2, whh2f, whh2b, outp);
  } else {
    l1_scan_fb<<<Bn * 2, 64, 0, stream>>>(x, wih1f, whh1f, bih1f, bhh1f,
                                          wih1b, whh1b, bih1b, bhh1b, out1);
    l2_scan_fb<<<Bn * 2, 64, 0, stream>>>(out1, wih2f, whh2f, bih2f, bhh2f,
                                          wih2b, whh2b, bih2b, bhh2b, outp);
  }
}

// Round 17
// 814.284 us; speedup vs baseline: 2.4239x; 1.0062x over previous
//
#include <hip/hip_runtime.h>

// 2-layer bidirectional LSTM, B=256 T=2048 D=64, H1=16/dir, H2=8/dir.
// R17 = R16 (PASS, 819us) + group-overhead halving in the scans:
//  - l1: 8 steps/group (2 DMAs, 2KB slots); l2: 16 steps/group. Per-group
//    WAITV/exec-toggle/branch overhead (~60-80cy) amortized over 2x steps.
//    vmcnt re-derived (2 DMA + 8/16 GST per body): l1 4/12/20 -> 28;
//    l2 4/20/36 -> 52.
//  - WAITV loses sched_barrier(0): consumers are LDS reads / asm stores
//    (memory ops, ordered by the "memory" clobber); rule #18's hazard is
//    register-only consumers, not applicable.
//  - KNEG2LOG2E folded into gate-0 gout: cs = fmaf(fv, cs, iv*gv), one
//    mul off the serial chain (exact reassociation, same rounding count).
// gemms (R16 quad/exp2) + fallbacks (R10) unchanged.

#ifndef __has_builtin
#define __has_builtin(x) 0
#endif

constexpr int Bn = 256;
constexpr int Tn = 2048;
#define LOG2E 1.4426950408889634f
#define KNEG2LOG2E -2.8853900817779268f

typedef unsigned int uint2v __attribute__((ext_vector_type(2)));

__device__ __forceinline__ float fast_rcp(float x) { return __builtin_amdgcn_rcpf(x); }
__device__ __forceinline__ float exp2_fast(float x) {
#if __has_builtin(__builtin_amdgcn_exp2f)
  return __builtin_amdgcn_exp2f(x);
#else
  return exp2f(x);
#endif
}
__device__ __forceinline__ float tanh_fast(float x) {   // fallback kernels only
  return fmaf(2.0f, fast_rcp(1.0f + __expf(-2.0f * x)), -1.0f);
}

// DPP rotate-right by R within each 16-lane row: dst[l] = src[(l-R)&15].
template <int R>
__device__ __forceinline__ float rotr16(float v) {
  return __int_as_float(__builtin_amdgcn_mov_dpp(
      __float_as_int(v), 0x120 | R, 0xF, 0xF, true));
}
// Quad broadcast: dst[l] = src[(l&~3) | Q].
template <int Q>
__device__ __forceinline__ float qbcast(float v) {
  return __int_as_float(__builtin_amdgcn_mov_dpp(
      __float_as_int(v), 0x55 * Q, 0xF, 0xF, true));
}

// val[l^16] / val[l^32], polarity-proof XOR-combine (R13-proven).
__device__ __forceinline__ float xor16_lane(float v) {
#if __has_builtin(__builtin_amdgcn_permlane16_swap)
  const unsigned u = __float_as_uint(v);
  uint2v r = __builtin_amdgcn_permlane16_swap(u, u, false, false);
  return __uint_as_float(r[0] ^ r[1] ^ u);
#else
  return __shfl_xor(v, 16, 64);
#endif
}
__device__ __forceinline__ float xor32_lane(float v) {
#if __has_builtin(__builtin_amdgcn_permlane32_swap)
  const unsigned u = __float_as_uint(v);
  uint2v r = __builtin_amdgcn_permlane32_swap(u, u, false, false);
  return __uint_as_float(r[0] ^ r[1] ^ u);
#else
  return __shfl_xor(v, 32, 64);
#endif
}

#define OPQ4(v) asm("" : "+v"(v.x), "+v"(v.y), "+v"(v.z), "+v"(v.w));
#define OPQ1(v) asm("" : "+v"(v));

#define GST(addr, val) \
  asm volatile("global_store_dword %0, %1, off" :: "v"(addr), "v"(val));

#define WAITV(N) \
  asm volatile("s_waitcnt vmcnt(" #N ")" ::: "memory");

#define DMA16(gsrc, ldst)                                         \
  __builtin_amdgcn_global_load_lds(                               \
      (const __attribute__((address_space(1))) float*)(gsrc),     \
      (__attribute__((address_space(3))) float*)(ldst), 16, 0, 0);

#define FMAU(ACC, I) { const float4 xv_ = x4[I];                    \
    ACC = fmaf(xv_.x, w##I.x, ACC); ACC = fmaf(xv_.y, w##I.y, ACC); \
    ACC = fmaf(xv_.z, w##I.z, ACC); ACC = fmaf(xv_.w, w##I.w, ACC); }

#define FMAQ(ACC, I) { float4 v_ = xq_[I];                          \
    ACC = fmaf(v_.x, w##I.x, ACC); ACC = fmaf(v_.y, w##I.y, ACC);   \
    ACC = fmaf(v_.z, w##I.z, ACC); ACC = fmaf(v_.w, w##I.w, ACC); }

// ============ GEMM 1: gx1[bd][s][64], quad-interleaved, exp2-prescaled ============
__global__ __launch_bounds__(64, 2) void gemm_gx1(
    const float* __restrict__ x,
    const float* __restrict__ wf, const float* __restrict__ bif,
    const float* __restrict__ bhf,
    const float* __restrict__ wb, const float* __restrict__ bib,
    const float* __restrict__ bhb,
    float* __restrict__ gx1) {
  constexpr int TILES = 32, TT = Tn / TILES;
  constexpr int NG = TT / 4;
  const int lane = threadIdx.x;
  const int bd   = blockIdx.x / TILES;
  const int tile = blockIdx.x % TILES;
  const int dir  = bd & 1, b = bd >> 1;

  __shared__ float xr[4 * 256];
  const float* xb = x + ((size_t)b * Tn + tile * TT) * 64;

#pragma unroll
  for (int p = 0; p < 3; ++p)
    DMA16(xb + (size_t)p * 256 + lane * 4, xr + p * 256)

  const int grp = lane & 3, un = lane >> 2;
  const int rr = grp * 16 + un;
  const float* W = dir ? wb : wf;
  float bias = (dir ? bib : bif)[rr] + (dir ? bhb : bhf)[rr];
  const float sc = (grp == 2) ? (-2.0f * LOG2E) : (-LOG2E);

  const float4* wr = reinterpret_cast<const float4*>(W + rr * 64);
  float4 w0 = wr[0],  w1 = wr[1],  w2 = wr[2],  w3 = wr[3],
         w4 = wr[4],  w5 = wr[5],  w6 = wr[6],  w7 = wr[7],
         w8 = wr[8],  w9 = wr[9],  w10 = wr[10], w11 = wr[11],
         w12 = wr[12], w13 = wr[13], w14 = wr[14], w15 = wr[15];
  OPQ4(w0)  OPQ4(w1)  OPQ4(w2)  OPQ4(w3)  OPQ4(w4)  OPQ4(w5)
  OPQ4(w6)  OPQ4(w7)  OPQ4(w8)  OPQ4(w9)  OPQ4(w10) OPQ4(w11)
  OPQ4(w12) OPQ4(w13) OPQ4(w14) OPQ4(w15) OPQ1(bias)

  const int t0 = tile * TT;
  const int sstep = dir ? -1 : 1;
  float* op = gx1 + (size_t)bd * Tn * 64 +
              (size_t)(dir ? (Tn - 1 - t0) : t0) * 64 + lane;

#define ROWDOT1(RP, RES) {                                               \
    const float4* x4 = reinterpret_cast<const float4*>(RP);              \
    float a0 = bias, a1 = 0.f, a2 = 0.f, a3 = 0.f;                       \
    FMAU(a0, 0)  FMAU(a1, 1)  FMAU(a2, 2)  FMAU(a3, 3)                  \
    FMAU(a0, 4)  FMAU(a1, 5)  FMAU(a2, 6)  FMAU(a3, 7)                  \
    FMAU(a0, 8)  FMAU(a1, 9)  FMAU(a2, 10) FMAU(a3, 11)                 \
    FMAU(a0, 12) FMAU(a1, 13) FMAU(a2, 14) FMAU(a3, 15)                 \
    RES = sc * ((a0 + a1) + (a2 + a3)); }

#define GG1(NW, G) {                                                     \
    WAITV(NW);                                                           \
    { const int mp_ = (G) + 3;                                           \
      const int mpc_ = (mp_ < NG) ? mp_ : NG - 1;                        \
      DMA16(xb + (size_t)mpc_ * 256 + lane * 4, xr + (mp_ & 3) * 256) }  \
    const float* sb_ = xr + ((G) & 3) * 256;                             \
    float h0_, h1_, h2_, h3_;                                            \
    ROWDOT1(sb_, h0_)        ROWDOT1(sb_ + 64, h1_)                      \
    ROWDOT1(sb_ + 128, h2_)  ROWDOT1(sb_ + 192, h3_)                     \
    GST(op, h0_)                 GST(op + sstep * 64, h1_)               \
    GST(op + 2 * sstep * 64, h2_) GST(op + 3 * sstep * 64, h3_)          \
    op += 4 * sstep * 64; }

  GG1(2, 0)
  GG1(6, 1)
  GG1(10, 2)
#pragma unroll 1
  for (int g = 3; g < NG; ++g) {
    GG1(14, g)
  }
#undef GG1
#undef ROWDOT1
}

// ============ GEMM 2: gx2[bd][s][32], quad-interleaved, exp2-prescaled ============
__global__ __launch_bounds__(64, 2) void gemm_gx2(
    const float* __restrict__ in,   // out1 [B][T][32]
    const float* __restrict__ wf, const float* __restrict__ bif,
    const float* __restrict__ bhf,
    const float* __restrict__ wb, const float* __restrict__ bib,
    const float* __restrict__ bhb,
    float* __restrict__ gx2) {
  constexpr int TILES = 32, TT = Tn / TILES;
  constexpr int NG = TT / 8;
  const int lane = threadIdx.x;
  const int g = lane & 31, half = lane >> 5;
  const int b = blockIdx.x / TILES, tile = blockIdx.x % TILES;

  __shared__ float xr[4 * 256];
  const float* ib = in + ((size_t)b * Tn + tile * TT) * 32;

#pragma unroll
  for (int p = 0; p < 3; ++p)
    DMA16(ib + (size_t)p * 256 + lane * 4, xr + p * 256)

  const int grp = g & 3, un = g >> 2;
  const int rr = grp * 8 + un;
  const float* W = half ? wb : wf;
  float bias = (half ? bib : bif)[rr] + (half ? bhb : bhf)[rr];
  const float sc = (grp == 2) ? (-2.0f * LOG2E) : (-LOG2E);

  const float4* wr = reinterpret_cast<const float4*>(W + rr * 32);
  float4 w0 = wr[0], w1 = wr[1], w2 = wr[2], w3 = wr[3],
         w4 = wr[4], w5 = wr[5], w6 = wr[6], w7 = wr[7];
  OPQ4(w0) OPQ4(w1) OPQ4(w2) OPQ4(w3) OPQ4(w4) OPQ4(w5) OPQ4(w6) OPQ4(w7)
  OPQ1(bias)

  const int t0 = tile * TT;
  const int slstep = half ? -1 : 1;
  float* op = gx2 + ((size_t)(b * 2 + half) * Tn +
              (half ? (Tn - 1 - t0) : t0)) * 32 + g;

#define ROWDOT2(RP, RES) {                                               \
    const float4* x4 = reinterpret_cast<const float4*>(RP);              \
    float a0 = bias, a1 = 0.f, a2 = 0.f, a3 = 0.f;                       \
    FMAU(a0, 0) FMAU(a1, 1) FMAU(a2, 2) FMAU(a3, 3)                     \
    FMAU(a0, 4) FMAU(a1, 5) FMAU(a2, 6) FMAU(a3, 7)                     \
    RES = sc * ((a0 + a1) + (a2 + a3)); }

#define GG2(NW, G) {                                                     \
    WAITV(NW);                                                           \
    { const int mp_ = (G) + 3;                                           \
      const int mpc_ = (mp_ < NG) ? mp_ : NG - 1;                        \
      DMA16(ib + (size_t)mpc_ * 256 + lane * 4, xr + (mp_ & 3) * 256) }  \
    const float* sb_ = xr + ((G) & 3) * 256;                             \
    float h0_, h1_, h2_, h3_, h4_, h5_, h6_, h7_;                        \
    ROWDOT2(sb_, h0_)        ROWDOT2(sb_ + 32, h1_)                      \
    ROWDOT2(sb_ + 64, h2_)   ROWDOT2(sb_ + 96, h3_)                      \
    ROWDOT2(sb_ + 128, h4_)  ROWDOT2(sb_ + 160, h5_)                     \
    ROWDOT2(sb_ + 192, h6_)  ROWDOT2(sb_ + 224, h7_)                     \
    GST(op, h0_)                  GST(op + slstep * 32, h1_)             \
    GST(op + 2 * slstep * 32, h2_) GST(op + 3 * slstep * 32, h3_)        \
    GST(op + 4 * slstep * 32, h4_) GST(op + 5 * slstep * 32, h5_)        \
    GST(op + 6 * slstep * 32, h6_) GST(op + 7 * slstep * 32, h7_)        \
    op += 8 * slstep * 32; }

  GG2(2, 0)
  GG2(10, 1)
  GG2(18, 2)
#pragma unroll 1
  for (int gg = 3; gg < NG; ++gg) {
    GG2(26, gg)
  }
#undef GG2
#undef ROWDOT2
}

// ============ Scan 1 (quad layout, exp2 domain): H=16, 8-step groups ============
__global__ __launch_bounds__(64, 1) void l1_scan_gx(
    const float* __restrict__ gx1,
    const float* __restrict__ whh_f, const float* __restrict__ whh_b,
    float* __restrict__ out1) {
  constexpr int NC = Tn / 8;          // 256 groups of 8 rows (2KB chunks)
  const int lane = threadIdx.x;
  const int dir  = blockIdx.x & 1;
  const int b    = blockIdx.x >> 1;

  __shared__ float xr[4 * 512];       // 4 slots x 2KB = 8KB
  const float* gxb = gx1 + (size_t)blockIdx.x * Tn * 64;

#pragma unroll
  for (int p = 0; p < 3; ++p) {
    DMA16(gxb + (size_t)p * 512 + lane * 4, xr + p * 512)
    DMA16(gxb + (size_t)p * 512 + 256 + lane * 4, xr + p * 512 + 256)
  }

  const float* whh = dir ? whh_b : whh_f;  // [64][16]
  const int grp = lane & 3, un = lane >> 2;
  const int rr = grp * 16 + un;
  const float sc = (grp == 2) ? (-2.0f * LOG2E) : (-LOG2E);
  const float* whr = whh + rr * 16;
#define UIDX(S, R) (((un & 12) ^ (4 * (S))) | (((un & 3) - (R)) & 3))
  float u0  = sc * whr[UIDX(0, 0)], u1  = sc * whr[UIDX(0, 1)],
        u2  = sc * whr[UIDX(0, 2)], u3  = sc * whr[UIDX(0, 3)],
        u4  = sc * whr[UIDX(1, 0)], u5  = sc * whr[UIDX(1, 1)],
        u6  = sc * whr[UIDX(1, 2)], u7  = sc * whr[UIDX(1, 3)],
        u8  = sc * whr[UIDX(2, 0)], u9  = sc * whr[UIDX(2, 1)],
        u10 = sc * whr[UIDX(2, 2)], u11 = sc * whr[UIDX(2, 3)],
        u12 = sc * whr[UIDX(3, 0)], u13 = sc * whr[UIDX(3, 1)],
        u14 = sc * whr[UIDX(3, 2)], u15 = sc * whr[UIDX(3, 3)];
#undef UIDX
  OPQ1(u0)  OPQ1(u1)  OPQ1(u2)  OPQ1(u3)  OPQ1(u4)  OPQ1(u5)
  OPQ1(u6)  OPQ1(u7)  OPQ1(u8)  OPQ1(u9)  OPQ1(u10) OPQ1(u11)
  OPQ1(u12) OPQ1(u13) OPQ1(u14) OPQ1(u15)

  // KNEG folded into gate-0 output constant (cs fma needs no extra mul).
  const float gout = (grp == 0) ? KNEG2LOG2E : ((grp == 2) ? 2.0f : 1.0f);
  const float gsub = (grp == 2) ? -1.0f : 0.0f;

  const int ostep = dir ? -32 : 32;
  float* op = out1 + (size_t)b * Tn * 32 + dir * 16 +
              (dir ? (size_t)(Tn - 1) * 32 : 0);

  float h = 0.0f, cs = 0.0f;   // cs = -2*log2e*c

#define STEP1(GX, HS) {                                                   \
    const float hb1 = xor16_lane(h);                                      \
    const float hb2 = xor32_lane(h);                                      \
    const float hb3 = xor16_lane(hb2);                                    \
    float m0 = h * u0;                                                    \
    m0 = fmaf(rotr16<4>(h),   u1,  m0);                                   \
    m0 = fmaf(rotr16<8>(h),   u2,  m0);                                   \
    m0 = fmaf(rotr16<12>(h),  u3,  m0);                                   \
    float m1 = hb1 * u4;                                                  \
    m1 = fmaf(rotr16<4>(hb1),  u5,  m1);                                  \
    m1 = fmaf(rotr16<8>(hb1),  u6,  m1);                                  \
    m1 = fmaf(rotr16<12>(hb1), u7,  m1);                                  \
    float m2 = hb2 * u8;                                                  \
    m2 = fmaf(rotr16<4>(hb2),  u9,  m2);                                  \
    m2 = fmaf(rotr16<8>(hb2),  u10, m2);                                  \
    m2 = fmaf(rotr16<12>(hb2), u11, m2);                                  \
    float m3 = hb3 * u12;                                                 \
    m3 = fmaf(rotr16<4>(hb3),  u13, m3);                                  \
    m3 = fmaf(rotr16<8>(hb3),  u14, m3);                                  \
    m3 = fmaf(rotr16<12>(hb3), u15, m3);                                  \
    const float g_ = ((m0 + m1) + (m2 + m3)) + (GX);                      \
    const float t_  = fast_rcp(1.0f + exp2_fast(g_));                     \
    const float val_ = fmaf(gout, t_, gsub);                              \
    const float iv_ = qbcast<0>(val_);                                    \
    const float fv_ = qbcast<1>(val_);                                    \
    const float gv_ = qbcast<2>(val_);                                    \
    const float ov_ = qbcast<3>(val_);                                    \
    cs = fmaf(fv_, cs, iv_ * gv_);                                        \
    const float t2_ = fast_rcp(1.0f + exp2_fast(cs));                     \
    h = ov_ * fmaf(2.0f, t2_, -1.0f);                                     \
    HS = h;                                                               \
  }

  // Per group: 2 DMA + 8 GST -> counted waits 4/12/20 then 28.
#define GROUP1(NW, G) {                                                   \
    WAITV(NW);                                                            \
    const float* sb_ = xr + ((G) & 3) * 512;                              \
    const float q0_ = sb_[lane];         const float q1_ = sb_[64 + lane];  \
    const float q2_ = sb_[128 + lane];   const float q3_ = sb_[192 + lane]; \
    const float q4_ = sb_[256 + lane];   const float q5_ = sb_[320 + lane]; \
    const float q6_ = sb_[384 + lane];   const float q7_ = sb_[448 + lane]; \
    { const int mp_ = (G) + 3;                                            \
      const int mpc_ = (mp_ < NC) ? mp_ : NC - 1;                         \
      DMA16(gxb + (size_t)mpc_ * 512 + lane * 4, xr + (mp_ & 3) * 512)    \
      DMA16(gxb + (size_t)mpc_ * 512 + 256 + lane * 4,                    \
            xr + (mp_ & 3) * 512 + 256) }                                 \
    float h0_, h1_, h2_, h3_, h4_, h5_, h6_, h7_;                         \
    STEP1(q0_, h0_) STEP1(q1_, h1_) STEP1(q2_, h2_) STEP1(q3_, h3_)       \
    STEP1(q4_, h4_) STEP1(q5_, h5_) STEP1(q6_, h6_) STEP1(q7_, h7_)       \
    if ((lane & 3) == 0) {                                                \
      GST(op + un, h0_)                                                   \
      GST(op + ostep + un, h1_)                                           \
      GST(op + 2 * ostep + un, h2_)                                       \
      GST(op + 3 * ostep + un, h3_)                                       \
      GST(op + 4 * ostep + un, h4_)                                       \
      GST(op + 5 * ostep + un, h5_)                                       \
      GST(op + 6 * ostep + un, h6_)                                       \
      GST(op + 7 * ostep + un, h7_)                                       \
    }                                                                     \
    op += 8 * ostep;                                                      \
  }

  GROUP1(4, 0)
  GROUP1(12, 1)
  GROUP1(20, 2)
#pragma unroll 1
  for (int g = 3; g < NC; ++g) {
    GROUP1(28, g)
  }
#undef GROUP1
#undef STEP1
}

// ============ Scan 2 (quad layout, exp2 domain): H=8, 16-step groups ============
__global__ __launch_bounds__(64, 1) void l2_scan_gx(
    const float* __restrict__ gx2,
    const float* __restrict__ whh_f, const float* __restrict__ whh_b,
    float* __restrict__ out) {
  constexpr int NC = Tn / 16;         // 128 groups of 16 rows (2KB chunks)
  const int lane = threadIdx.x;
  const int j    = lane & 31;
  const int dir  = blockIdx.x & 1;
  const int b    = blockIdx.x >> 1;

  __shared__ float xr[4 * 512];
  const float* gxb = gx2 + (size_t)blockIdx.x * Tn * 32;

#pragma unroll
  for (int p = 0; p < 3; ++p) {
    DMA16(gxb + (size_t)p * 512 + lane * 4, xr + p * 512)
    DMA16(gxb + (size_t)p * 512 + 256 + lane * 4, xr + p * 512 + 256)
  }

  const float* whh = dir ? whh_b : whh_f;  // [32][8]
  const int grp = j & 3, un = j >> 2;
  const int rr = grp * 8 + un;
  const float sc = (grp == 2) ? (-2.0f * LOG2E) : (-LOG2E);
  const float* whr = whh + rr * 8;
#define UIDX2(S, R) (((un & 4) ^ (4 * (S))) | (((un & 3) - (R)) & 3))
  float u0 = sc * whr[UIDX2(0, 0)], u1 = sc * whr[UIDX2(0, 1)],
        u2 = sc * whr[UIDX2(0, 2)], u3 = sc * whr[UIDX2(0, 3)],
        u4 = sc * whr[UIDX2(1, 0)], u5 = sc * whr[UIDX2(1, 1)],
        u6 = sc * whr[UIDX2(1, 2)], u7 = sc * whr[UIDX2(1, 3)];
#undef UIDX2
  OPQ1(u0) OPQ1(u1) OPQ1(u2) OPQ1(u3) OPQ1(u4) OPQ1(u5) OPQ1(u6) OPQ1(u7)

  const float gout = (grp == 0) ? KNEG2LOG2E : ((grp == 2) ? 2.0f : 1.0f);
  const float gsub = (grp == 2) ? -1.0f : 0.0f;

  const int ostep = dir ? -16 : 16;
  float* op = out + (size_t)b * Tn * 16 + dir * 8 +
              (dir ? (size_t)(Tn - 1) * 16 : 0);

  float h = 0.0f, cs = 0.0f;

#define STEP2(GX, HS) {                                                   \
    const float hb1 = xor16_lane(h);                                      \
    float m0 = h * u0;                                                    \
    m0 = fmaf(rotr16<4>(h),   u1, m0);                                    \
    m0 = fmaf(rotr16<8>(h),   u2, m0);                                    \
    m0 = fmaf(rotr16<12>(h),  u3, m0);                                    \
    float m1 = hb1 * u4;                                                  \
    m1 = fmaf(rotr16<4>(hb1),  u5, m1);                                   \
    m1 = fmaf(rotr16<8>(hb1),  u6, m1);                                   \
    m1 = fmaf(rotr16<12>(hb1), u7, m1);                                   \
    const float g_ = (m0 + m1) + (GX);                                    \
    const float t_  = fast_rcp(1.0f + exp2_fast(g_));                     \
    const float val_ = fmaf(gout, t_, gsub);                              \
    const float iv_ = qbcast<0>(val_);                                    \
    const float fv_ = qbcast<1>(val_);                                    \
    const float gv_ = qbcast<2>(val_);                                    \
    const float ov_ = qbcast<3>(val_);                                    \
    cs = fmaf(fv_, cs, iv_ * gv_);                                        \
    const float t2_ = fast_rcp(1.0f + exp2_fast(cs));                     \
    h = ov_ * fmaf(2.0f, t2_, -1.0f);                                     \
    HS = h;                                                               \
  }

  // Per group: 2 DMA + 16 GST -> counted waits 4/20/36 then 52.
#define GROUP2(NW, G) {                                                   \
    WAITV(NW);                                                            \
    const float* sb_ = xr + ((G) & 3) * 512;                              \
    const float q0_  = sb_[j];           const float q1_  = sb_[32 + j];  \
    const float q2_  = sb_[64 + j];      const float q3_  = sb_[96 + j];  \
    const float q4_  = sb_[128 + j];     const float q5_  = sb_[160 + j]; \
    const float q6_  = sb_[192 + j];     const float q7_  = sb_[224 + j]; \
    const float q8_  = sb_[256 + j];     const float q9_  = sb_[288 + j]; \
    const float q10_ = sb_[320 + j];     const float q11_ = sb_[352 + j]; \
    const float q12_ = sb_[384 + j];     const float q13_ = sb_[416 + j]; \
    const float q14_ = sb_[448 + j];     const float q15_ = sb_[480 + j]; \
    { const int mp_ = (G) + 3;                                            \
      const int mpc_ = (mp_ < NC) ? mp_ : NC - 1;                         \
      DMA16(gxb + (size_t)mpc_ * 512 + lane * 4, xr + (mp_ & 3) * 512)    \
      DMA16(gxb + (size_t)mpc_ * 512 + 256 + lane * 4,                    \
            xr + (mp_ & 3) * 512 + 256) }                                 \
    float h0_, h1_, h2_, h3_, h4_, h5_, h6_, h7_;                         \
    float h8_, h9_, h10_, h11_, h12_, h13_, h14_, h15_;                   \
    STEP2(q0_,  h0_)  STEP2(q1_,  h1_)  STEP2(q2_,  h2_)  STEP2(q3_,  h3_)  \
    STEP2(q4_,  h4_)  STEP2(q5_,  h5_)  STEP2(q6_,  h6_)  STEP2(q7_,  h7_)  \
    STEP2(q8_,  h8_)  STEP2(q9_,  h9_)  STEP2(q10_, h10_) STEP2(q11_, h11_) \
    STEP2(q12_, h12_) STEP2(q13_, h13_) STEP2(q14_, h14_) STEP2(q15_, h15_) \
    if ((lane & 3) == 0 && lane < 32) {                                   \
      GST(op + un, h0_)                                                   \
      GST(op + ostep + un, h1_)                                           \
      GST(op + 2 * ostep + un, h2_)                                       \
      GST(op + 3 * ostep + un, h3_)                                       \
      GST(op + 4 * ostep + un, h4_)                                       \
      GST(op + 5 * ostep + un, h5_)                                       \
      GST(op + 6 * ostep + un, h6_)                                       \
      GST(op + 7 * ostep + un, h7_)                                       \
      GST(op + 8 * ostep + un, h8_)                                       \
      GST(op + 9 * ostep + un, h9_)                                       \
      GST(op + 10 * ostep + un, h10_)                                     \
      GST(op + 11 * ostep + un, h11_)                                     \
      GST(op + 12 * ostep + un, h12_)                                     \
      GST(op + 13 * ostep + un, h13_)                                     \
      GST(op + 14 * ostep + un, h14_)                                     \
      GST(op + 15 * ostep + un, h15_)                                     \
    }                                                                     \
    op += 16 * ostep;                                                     \
  }

  GROUP2(4, 0)
  GROUP2(20, 1)
  GROUP2(36, 2)
#pragma unroll 1
  for (int g = 3; g < NC; ++g) {
    GROUP2(52, g)
  }
#undef GROUP2
#undef STEP2
}

// ==================== Fallback (R10, proven): weights in scan ====================
__global__ __launch_bounds__(64, 1) void l1_scan_fb(
    const float* __restrict__ x,
    const float* __restrict__ wih_f, const float* __restrict__ whh_f,
    const float* __restrict__ bih_f, const float* __restrict__ bhh_f,
    const float* __restrict__ wih_b, const float* __restrict__ whh_b,
    const float* __restrict__ bih_b, const float* __restrict__ bhh_b,
    float* __restrict__ out1) {
  constexpr int NC = Tn / 4;
  const int lane = threadIdx.x;
  const int dir  = blockIdx.x & 1;
  const int b    = blockIdx.x >> 1;
  __shared__ float xr[4 * 256];
  const float* xb = x + (size_t)b * (Tn * 64);
  {
    const int m0 = dir ? NC - 1 : 0;
    const int md = dir ? -1 : 1;
#pragma unroll
    for (int q = 0; q < 3; ++q) {
      const int mc = m0 + q * md;
      DMA16(xb + (size_t)mc * 256 + lane * 4, xr + (mc & 3) * 256)
    }
  }
  const float* wih = dir ? wih_b : wih_f;
  const float* whh = dir ? whh_b : whh_f;
  float bias = (dir ? bih_b : bih_f)[lane] + (dir ? bhh_b : bhh_f)[lane];
  const int k = lane & 15, grp = lane >> 4;
  const float gin  = (grp == 2) ? 2.0f : 1.0f;
  const float gout = (grp == 2) ? 2.0f : 1.0f;
  const float gsub = (grp == 2) ? -1.0f : 0.0f;
  const float4* wr = reinterpret_cast<const float4*>(wih + lane * 64);
  float4 w0 = wr[0],  w1 = wr[1],  w2 = wr[2],  w3 = wr[3],
         w4 = wr[4],  w5 = wr[5],  w6 = wr[6],  w7 = wr[7],
         w8 = wr[8],  w9 = wr[9],  w10 = wr[10], w11 = wr[11],
         w12 = wr[12], w13 = wr[13], w14 = wr[14], w15 = wr[15];
  const float* whr = whh + lane * 16;
  float u0 = whr[k], u1 = whr[(k - 1) & 15], u2 = whr[(k - 2) & 15],
        u3 = whr[(k - 3) & 15], u4 = whr[(k - 4) & 15],
        u5 = whr[(k - 5) & 15], u6 = whr[(k - 6) & 15],
        u7 = whr[(k - 7) & 15], u8 = whr[(k - 8) & 15],
        u9 = whr[(k - 9) & 15], u10 = whr[(k - 10) & 15],
        u11 = whr[(k - 11) & 15], u12 = whr[(k - 12) & 15],
        u13 = whr[(k - 13) & 15], u14 = whr[(k - 14) & 15],
        u15 = whr[(k - 15) & 15];
  const int ostep = dir ? -32 : 32;
  float* op = out1 + (size_t)b * (Tn * 32) + dir * 16 +
              (dir ? (size_t)(Tn - 1) * 32 : 0);
  float h = 0.0f, c = 0.0f;
#define STEP1F(XROW) {                                                    \
    const float4* xq_ = reinterpret_cast<const float4*>(XROW);            \
    float a0 = bias, a1 = 0.f, a2 = 0.f, a3 = 0.f;                        \
    FMAQ(a0, 0)  FMAQ(a1, 1)  FMAQ(a2, 2)  FMAQ(a3, 3)                   \
    FMAQ(a0, 4)  FMAQ(a1, 5)  FMAQ(a2, 6)  FMAQ(a3, 7)                   \
    FMAQ(a0, 8)  FMAQ(a1, 9)  FMAQ(a2, 10) FMAQ(a3, 11)                  \
    FMAQ(a0, 12) FMAQ(a1, 13) FMAQ(a2, 14) FMAQ(a3, 15)                  \
    const float gx_ = (a0 + a1) + (a2 + a3);                              \
    float m0 = h * u0, m1 = 0.f, m2 = 0.f, m3 = 0.f;                      \
    m1 = fmaf(rotr16<1>(h),  u1,  m1);  m2 = fmaf(rotr16<2>(h),  u2,  m2); \
    m3 = fmaf(rotr16<3>(h),  u3,  m3);  m0 = fmaf(rotr16<4>(h),  u4,  m0); \
    m1 = fmaf(rotr16<5>(h),  u5,  m1);  m2 = fmaf(rotr16<6>(h),  u6,  m2); \
    m3 = fmaf(rotr16<7>(h),  u7,  m3);  m0 = fmaf(rotr16<8>(h),  u8,  m0); \
    m1 = fmaf(rotr16<9>(h),  u9,  m1);  m2 = fmaf(rotr16<10>(h), u10, m2); \
    m3 = fmaf(rotr16<11>(h), u11, m3);  m0 = fmaf(rotr16<12>(h), u12, m0); \
    m1 = fmaf(rotr16<13>(h), u13, m1);  m2 = fmaf(rotr16<14>(h), u14, m2); \
    m3 = fmaf(rotr16<15>(h), u15, m3);                                    \
    const float g_ = ((m0 + m1) + (m2 + m3)) + gx_;                       \
    const float sg_  = fast_rcp(1.0f + __expf(-gin * g_));                \
    const float val_ = fmaf(gout, sg_, gsub);                             \
    const float e1_ = __shfl_xor(val_, 16, 64);                           \
    const float e2_ = __shfl_xor(val_, 32, 64);                           \
    const float e3_ = __shfl_xor(val_, 48, 64);                           \
    const float iv_ = (grp == 0) ? val_ : (grp == 1) ? e1_ : (grp == 2) ? e2_ : e3_; \
    const float fv_ = (grp == 1) ? val_ : (grp == 0) ? e1_ : (grp == 3) ? e2_ : e3_; \
    const float gv_ = (grp == 2) ? val_ : (grp == 3) ? e1_ : (grp == 0) ? e2_ : e3_; \
    const float ov_ = (grp == 3) ? val_ : (grp == 2) ? e1_ : (grp == 1) ? e2_ : e3_; \
    c = fmaf(fv_, c, iv_ * gv_);                                          \
    h = ov_ * tanh_fast(c);                                               \
    if (lane < 16) { GST(op + lane, h) }                                  \
    op += ostep;                                                          \
  }
#define GROUP1F(NW, G) {                                                  \
    const int mq_ = dir ? (NC - 1 - (G)) : (G);                           \
    const float* sb_ = xr + (mq_ & 3) * 256;                              \
    WAITV(NW);                                                            \
    __builtin_amdgcn_sched_barrier(0);                                    \
    { const int mp_ = dir ? (mq_ - 3) : (mq_ + 3);                        \
      const int sl_ = mp_ & 3;                                            \
      const int mpc_ = mp_ < 0 ? 0 : (mp_ >= NC ? NC - 1 : mp_);          \
      DMA16(xb + (size_t)mpc_ * 256 + lane * 4, xr + sl_ * 256) }         \
    STEP1F(sb_ + (dir ? 3 : 0) * 64)                                      \
    STEP1F(sb_ + (dir ? 2 : 1) * 64)                                      \
    STEP1F(sb_ + (dir ? 1 : 2) * 64)                                      \
    STEP1F(sb_ + (dir ? 0 : 3) * 64)                                      \
  }
  GROUP1F(2, 0)
  GROUP1F(6, 1)
  GROUP1F(10, 2)
#pragma unroll 1
  for (int g = 3; g < NC; ++g) {
    GROUP1F(14, g)
  }
#undef GROUP1F
#undef STEP1F
}

__global__ __launch_bounds__(64, 1) void l2_scan_fb(
    const float* __restrict__ in,
    const float* __restrict__ wih_f, const float* __restrict__ whh_f,
    const float* __restrict__ bih_f, const float* __restrict__ bhh_f,
    const float* __restrict__ wih_b, const float* __restrict__ whh_b,
    const float* __restrict__ bih_b, const float* __restrict__ bhh_b,
    float* __restrict__ out) {
  constexpr int NC = Tn / 8;
  const int lane = threadIdx.x;
  const int j    = lane & 31;
  const int dir  = blockIdx.x & 1;
  const int b    = blockIdx.x >> 1;
  __shared__ float xr[4 * 256];
  const float* ib = in + (size_t)b * (Tn * 32);
  {
    const int m0 = dir ? NC - 1 : 0;
    const int md = dir ? -1 : 1;
#pragma unroll
    for (int q = 0; q < 3; ++q) {
      const int mc = m0 + q * md;
      DMA16(ib + (size_t)mc * 256 + lane * 4, xr + (mc & 3) * 256)
    }
  }
  const float* wih = dir ? wih_b : wih_f;
  const float* whh = dir ? whh_b : whh_f;
  float bias = (dir ? bih_b : bih_f)[j] + (dir ? bhh_b : bhh_f)[j];
  const int k = j & 7, grp = j >> 3;
  const float gin  = (grp == 2) ? 2.0f : 1.0f;
  const float gout = (grp == 2) ? 2.0f : 1.0f;
  const float gsub = (grp == 2) ? -1.0f : 0.0f;
  const float4* wr = reinterpret_cast<const float4*>(wih + j * 32);
  float4 w0 = wr[0], w1 = wr[1], w2 = wr[2], w3 = wr[3],
         w4 = wr[4], w5 = wr[5], w6 = wr[6], w7 = wr[7];
  const float* whr = whh + j * 8;
  float u0 = whr[k], u1 = whr[(k - 1) & 7], u2 = whr[(k - 2) & 7],
        u3 = whr[(k - 3) & 7], u4 = whr[(k - 4) & 7],
        u5 = whr[(k - 5) & 7], u6 = whr[(k - 6) & 7],
        u7 = whr[(k - 7) & 7];
  const int ostep = dir ? -16 : 16;
  float* op = out + (size_t)b * (Tn * 16) + dir * 8 +
              (dir ? (size_t)(Tn - 1) * 16 : 0);
  float h = 0.0f, c = 0.0f;
#define STEP2F(XROW) {                                                    \
    const float4* xq_ = reinterpret_cast<const float4*>(XROW);            \
    float a0 = bias, a1 = 0.f, a2 = 0.f, a3 = 0.f;                        \
    FMAQ(a0, 0) FMAQ(a1, 1) FMAQ(a2, 2) FMAQ(a3, 3)                      \
    FMAQ(a0, 4) FMAQ(a1, 5) FMAQ(a2, 6) FMAQ(a3, 7)                      \
    const float gx_ = (a0 + a1) + (a2 + a3);                              \
    float m0 = h * u0, m1 = 0.f, m2 = 0.f, m3 = 0.f;                      \
    m1 = fmaf(rotr16<1>(h), u1, m1);  m2 = fmaf(rotr16<2>(h), u2, m2);    \
    m3 = fmaf(rotr16<3>(h), u3, m3);  m0 = fmaf(rotr16<4>(h), u4, m0);    \
    m1 = fmaf(rotr16<5>(h), u5, m1);  m2 = fmaf(rotr16<6>(h), u6, m2);    \
    m3 = fmaf(rotr16<7>(h), u7, m3);                                      \
    const float g_ = ((m0 + m1) + (m2 + m3)) + gx_;                       \
    const float sg_  = fast_rcp(1.0f + __expf(-gin * g_));                \
    const float val_ = fmaf(gout, sg_, gsub);                             \
    const float e1_ = __shfl_xor(val_, 8, 64);                            \
    const float e2_ = __shfl_xor(val_, 16, 64);                           \
    const float e3_ = __shfl_xor(val_, 24, 64);                           \
    const float iv_ = (grp == 0) ? val_ : (grp == 1) ? e1_ : (grp == 2) ? e2_ : e3_; \
    const float fv_ = (grp == 1) ? val_ : (grp == 0) ? e1_ : (grp == 3) ? e2_ : e3_; \
    const float gv_ = (grp == 2) ? val_ : (grp == 3) ? e1_ : (grp == 0) ? e2_ : e3_; \
    const float ov_ = (grp == 3) ? val_ : (grp == 2) ? e1_ : (grp == 1) ? e2_ : e3_; \
    c = fmaf(fv_, c, iv_ * gv_);                                          \
    h = ov_ * tanh_fast(c);                                               \
    if (lane < 8) { GST(op + lane, h) }                                   \
    op += ostep;                                                          \
  }
#define GROUP2F(NW, G) {                                                  \
    const int mq_ = dir ? (NC - 1 - (G)) : (G);                           \
    const float* sb_ = xr + (mq_ & 3) * 256;                              \
    WAITV(NW);                                                            \
    __builtin_amdgcn_sched_barrier(0);                                    \
    { const int mp_ = dir ? (mq_ - 3) : (mq_ + 3);                        \
      const int sl_ = mp_ & 3;                                            \
      const int mpc_ = mp_ < 0 ? 0 : (mp_ >= NC ? NC - 1 : mp_);          \
      DMA16(ib + (size_t)mpc_ * 256 + lane * 4, xr + sl_ * 256) }         \
    STEP2F(sb_ + (dir ? 7 : 0) * 32)                                      \
    STEP2F(sb_ + (dir ? 6 : 1) * 32)                                      \
    STEP2F(sb_ + (dir ? 5 : 2) * 32)                                      \
    STEP2F(sb_ + (dir ? 4 : 3) * 32)                                      \
    STEP2F(sb_ + (dir ? 3 : 4) * 32)                                      \
    STEP2F(sb_ + (dir ? 2 : 5) * 32)                                      \
    STEP2F(sb_ + (dir ? 1 : 6) * 32)                                      \
    STEP2F(sb_ + (dir ? 0 : 7) * 32)                                      \
  }
  GROUP2F(2, 0)
  GROUP2F(10, 1)
  GROUP2F(18, 2)
#pragma unroll 1
  for (int g = 3; g < NC; ++g) {
    GROUP2F(26, g)
  }
#undef GROUP2F
#undef STEP2F
}

extern "C" void kernel_launch(void* const* d_in, const int* in_sizes, int n_in,
                              void* d_out, int out_size, void* d_ws, size_t ws_size,
                              hipStream_t stream) {
  const float* x     = (const float*)d_in[0];
  const float* wih1f = (const float*)d_in[1];
  const float* whh1f = (const float*)d_in[2];
  const float* bih1f = (const float*)d_in[3];
  const float* bhh1f = (const float*)d_in[4];
  const float* wih1b = (const float*)d_in[5];
  const float* whh1b = (const float*)d_in[6];
  const float* bih1b = (const float*)d_in[7];
  const float* bhh1b = (const float*)d_in[8];
  const float* wih2f = (const float*)d_in[9];
  const float* whh2f = (const float*)d_in[10];
  const float* bih2f = (const float*)d_in[11];
  const float* bhh2f = (const float*)d_in[12];
  const float* wih2b = (const float*)d_in[13];
  const float* whh2b = (const float*)d_in[14];
  const float* bih2b = (const float*)d_in[15];
  const float* bhh2b = (const float*)d_in[16];

  float* out1 = (float*)d_ws;                       // [B][T][32] = 67.1 MB
  float* outp = (float*)d_out;                      // [B][T][16]

  const size_t out1F = (size_t)Bn * Tn * 32;
  const size_t gx1F  = (size_t)Bn * 2 * Tn * 64;    // 268.4 MB
  const size_t needB = (out1F + gx1F) * sizeof(float);

  if (ws_size >= needB) {
    float* gx1 = (float*)d_ws + out1F;              // [2B][T][64]
    float* gx2 = gx1;                               // aliases gx1 (dead after scan1)
    gemm_gx1<<<Bn * 2 * 32, 64, 0, stream>>>(
        x, wih1f, bih1f, bhh1f, wih1b, bih1b, bhh1b, gx1);
    l1_scan_gx<<<Bn * 2, 64, 0, stream>>>(gx1, whh1f, whh1b, out1);
    gemm_gx2<<<Bn * 32, 64, 0, stream>>>(
        out1, wih2f, bih2f, bhh2f, wih2b, bih2b, bhh2b, gx2);
    l2_scan_gx<<<Bn * 2, 64, 0, stream>>>(gx2, whh2f, whh2b, outp);
  } else {
    l1_scan_fb<<<Bn * 2, 64, 0, stream>>>(x, wih1f, whh1f, bih1f, bhh1f,
                                          wih1b, whh1b, bih1b, bhh1b, out1);
    l2_scan_fb<<<Bn * 2, 64, 0, stream>>>(out1, wih2f, whh2f, bih2f, bhh2f,
                                          wih2b, whh2b, bih2b, bhh2b, outp);
  }
}